// Round 5
// baseline (1308.665 us; speedup 1.0000x reference)
//
#include <hip/hip_runtime.h>
#include <cstdint>
#include <cmath>

// v5: Plan B/C as v4, GEMM inner loop rewritten as 2-phase software pipeline:
//     double-buffered LDS + register prefetch, one barrier per K-step.

typedef __bf16 bf16_t;
typedef __bf16 bf16x8 __attribute__((ext_vector_type(8)));
typedef __bf16 bf16x4 __attribute__((ext_vector_type(4)));
typedef float floatx4 __attribute__((ext_vector_type(4)));

#define DMODEL 768
#define NHEAD  12
#define SEQ    1024
#define NBATCH 4
#define ROWS   (NBATCH*SEQ)   // 4096
#define DH     (DMODEL*NHEAD) // 9216
#define DFF    (4*DMODEL)     // 3072

// ---------------------------------------------------------------------------
// GEMM: C = alpha*(A @ B^T) [+bias[col]] [relu] [+res]   (fp32 bias/res/out)
// A: M x K (lda) bf16, BT: N x K (ldb) bf16, C: M x N (ldc). fp32 accum.
// OMODE: 0 = bf16 store, 1 = f32 store, 2 = f32 accumulate
// Batched via blockIdx.z: off = (z/bdiv)*hi + (z%bdiv)*lo  (element offsets)
// 128x128 tile, BK=32, 4 waves x (4x4) 16x16x32 MFMA. LDS frag-ordered.
// 2-phase pipeline: prefetch k+32 into regs || MFMA on buf || write buf^1 || 1 barrier.
// ---------------------------------------------------------------------------
template<bool BIAS, bool RES, bool RELU, int OMODE>
__global__ __launch_bounds__(256)
void gemm_v5(const bf16_t* __restrict__ A, const bf16_t* __restrict__ BT,
             void* __restrict__ Cv, int K, int lda, int ldb, int ldc,
             int bdiv, long sa_hi, long sa_lo, long sb_hi, long sb_lo,
             long sc_hi, long sc_lo,
             const float* __restrict__ bias, const float* __restrict__ res,
             int ldres, float alpha)
{
  __shared__ __align__(16) bf16_t As[2][128*32];
  __shared__ __align__(16) bf16_t Bs[2][128*32];

  const int tid  = threadIdx.x;
  const int wave = tid >> 6;
  const int lane = tid & 63;
  const int r    = lane & 15;   // row within 16-tile
  const int q    = lane >> 4;   // k-chunk (8 elems each)

  const int z = blockIdx.z;
  A  += (long)(z / bdiv) * sa_hi + (long)(z % bdiv) * sa_lo;
  BT += (long)(z / bdiv) * sb_hi + (long)(z % bdiv) * sb_lo;
  const long coff = (long)(z / bdiv) * sc_hi + (long)(z % bdiv) * sc_lo;

  const int bm = blockIdx.y * 128;
  const int bn = blockIdx.x * 128;
  const int wm = (wave & 1) * 64;
  const int wn = (wave >> 1) * 64;

  const int blk0 = 2*wave, blk1 = 2*wave + 1;
  const bf16_t* a_src0 = A  + (long)(bm + blk0*16 + r) * lda + q*8;
  const bf16_t* a_src1 = A  + (long)(bm + blk1*16 + r) * lda + q*8;
  const bf16_t* b_src0 = BT + (long)(bn + blk0*16 + r) * ldb + q*8;
  const bf16_t* b_src1 = BT + (long)(bn + blk1*16 + r) * ldb + q*8;
  const int da0 = blk0*512 + lane*8;
  const int da1 = blk1*512 + lane*8;

  const int am = (wave & 1) * 4;
  const int bb = (wave >> 1) * 4;

  floatx4 acc[4][4] = {};

  // prologue: stage tile 0 into buffer 0
  bf16x8 av0 = *(const bf16x8*)(a_src0);
  bf16x8 av1 = *(const bf16x8*)(a_src1);
  bf16x8 bv0 = *(const bf16x8*)(b_src0);
  bf16x8 bv1 = *(const bf16x8*)(b_src1);
  *(bf16x8*)(&As[0][da0]) = av0;
  *(bf16x8*)(&As[0][da1]) = av1;
  *(bf16x8*)(&Bs[0][da0]) = bv0;
  *(bf16x8*)(&Bs[0][da1]) = bv1;
  __syncthreads();

  int buf = 0;
  for (int k0 = 0; k0 < K; k0 += 32) {
    const int nk = k0 + 32;
    // issue next tile's global loads (in flight across the compute phase)
    if (nk < K) {
      av0 = *(const bf16x8*)(a_src0 + nk);
      av1 = *(const bf16x8*)(a_src1 + nk);
      bv0 = *(const bf16x8*)(b_src0 + nk);
      bv1 = *(const bf16x8*)(b_src1 + nk);
    }
    // compute on current buffer
    bf16x8 afrag[4], bfrag[4];
#pragma unroll
    for (int t = 0; t < 4; ++t) {
      afrag[t] = *(const bf16x8*)(&As[buf][(am + t)*512 + lane*8]);
      bfrag[t] = *(const bf16x8*)(&Bs[buf][(bb + t)*512 + lane*8]);
    }
#pragma unroll
    for (int mt = 0; mt < 4; ++mt)
#pragma unroll
      for (int nt = 0; nt < 4; ++nt)
        acc[mt][nt] = __builtin_amdgcn_mfma_f32_16x16x32_bf16(
            afrag[mt], bfrag[nt], acc[mt][nt], 0, 0, 0);
    // write next tile into the other buffer (prev reads of buf^1 were fenced
    // by the barrier at the end of the previous iteration)
    if (nk < K) {
      *(bf16x8*)(&As[buf^1][da0]) = av0;
      *(bf16x8*)(&As[buf^1][da1]) = av1;
      *(bf16x8*)(&Bs[buf^1][da0]) = bv0;
      *(bf16x8*)(&Bs[buf^1][da1]) = bv1;
      __syncthreads();
    }
    buf ^= 1;
  }

  // epilogue: C/D layout col=lane&15, row=(lane>>4)*4+e
  const int row0 = bm + wm + q*4;
  const int col0 = bn + wn + r;
#pragma unroll
  for (int nt = 0; nt < 4; ++nt) {
    const int col = col0 + nt*16;
    float bv = 0.f;
    if (BIAS) bv = bias[col];
#pragma unroll
    for (int mt = 0; mt < 4; ++mt) {
#pragma unroll
      for (int e = 0; e < 4; ++e) {
        const int rowi = row0 + mt*16 + e;
        float v = acc[mt][nt][e] * alpha;
        if (BIAS) v += bv;
        if (RELU) v = fmaxf(v, 0.f);
        if (RES)  v += res[(long)rowi * ldres + col];
        const long idx = coff + (long)rowi * ldc + col;
        if (OMODE == 0)      ((bf16_t*)Cv)[idx] = (bf16_t)v;
        else if (OMODE == 1) ((float*)Cv)[idx] = v;
        else                 ((float*)Cv)[idx] += v;
      }
    }
  }
}

// -------- 32x32 tiled transpose, fp32 in -> bf16 out: out[c][r] = bf16(in[r][c]) --------
__global__ void tr_f2b_v5(const float* __restrict__ in, bf16_t* __restrict__ out,
                          int ldi, int ldo)
{
  __shared__ bf16_t tile[32][34];
  const int c0 = blockIdx.x * 32, r0 = blockIdx.y * 32;
  const int tx = threadIdx.x, ty = threadIdx.y;
#pragma unroll
  for (int i = 0; i < 4; ++i)
    tile[ty + 8*i][tx] = (bf16_t)in[(long)(r0 + ty + 8*i) * ldi + c0 + tx];
  __syncthreads();
#pragma unroll
  for (int i = 0; i < 4; ++i)
    out[(long)(c0 + ty + 8*i) * ldo + r0 + tx] = tile[tx][ty + 8*i];
}

// -------- batched 32x32 tiled transpose, bf16 -> bf16 (small plan) --------
__global__ void tr_b_v5(const bf16_t* __restrict__ in, bf16_t* __restrict__ out,
                        int ldi, int ldo, int bdiv,
                        long si_hi, long si_lo, long so_hi, long so_lo)
{
  __shared__ bf16_t tile[32][34];
  const int z = blockIdx.z;
  in  += (long)(z / bdiv) * si_hi + (long)(z % bdiv) * si_lo;
  out += (long)(z / bdiv) * so_hi + (long)(z % bdiv) * so_lo;
  const int c0 = blockIdx.x * 32, r0 = blockIdx.y * 32;
  const int tx = threadIdx.x, ty = threadIdx.y;
#pragma unroll
  for (int i = 0; i < 4; ++i)
    tile[ty + 8*i][tx] = in[(long)(r0 + ty + 8*i) * ldi + c0 + tx];
  __syncthreads();
#pragma unroll
  for (int i = 0; i < 4; ++i)
    out[(long)(c0 + ty + 8*i) * ldo + r0 + tx] = tile[tx][ty + 8*i];
}

// -------- per-head weight transposes (small plan): z=0..2 WhT slices, z=3 WuTh --------
__global__ void tr_wh_v5(const float* __restrict__ Wq, const float* __restrict__ Wk,
                         const float* __restrict__ Wv, const float* __restrict__ Wu,
                         bf16_t* __restrict__ WhT, bf16_t* __restrict__ WuTh, int h)
{
  __shared__ bf16_t tile[32][34];
  const int z = blockIdx.z;
  const float* in; bf16_t* out; int ldi;
  if (z < 3) {
    const float* W = (z == 0) ? Wq : (z == 1) ? Wk : Wv;
    in  = W + (long)h * DMODEL;
    ldi = DH;
    out = WhT + (long)z * DMODEL * DMODEL;
  } else {
    in  = Wu + (long)h * DMODEL * DMODEL;
    ldi = DMODEL;
    out = WuTh;
  }
  const int c0 = blockIdx.x * 32, r0 = blockIdx.y * 32;
  const int tx = threadIdx.x, ty = threadIdx.y;
#pragma unroll
  for (int i = 0; i < 4; ++i)
    tile[ty + 8*i][tx] = (bf16_t)in[(long)(r0 + ty + 8*i) * ldi + c0 + tx];
  __syncthreads();
#pragma unroll
  for (int i = 0; i < 4; ++i)
    out[(long)(c0 + ty + 8*i) * DMODEL + r0 + tx] = tile[tx][ty + 8*i];
}

// -------- cast-only fp32 -> bf16, 3 matrices of DMODEL*DH (z selects) --------
__global__ void cast3_v5(const float* __restrict__ a, const float* __restrict__ b,
                         const float* __restrict__ c,
                         bf16_t* __restrict__ oa, bf16_t* __restrict__ ob,
                         bf16_t* __restrict__ oc)
{
  const float* src = (blockIdx.z == 0) ? a : (blockIdx.z == 1) ? b : c;
  bf16_t* dst      = (blockIdx.z == 0) ? oa : (blockIdx.z == 1) ? ob : oc;
  const long i = ((long)blockIdx.x * 256 + threadIdx.x) * 4;
  float4 v = *(const float4*)(src + i);
  bf16x4 o;
  o[0] = (bf16_t)v.x; o[1] = (bf16_t)v.y; o[2] = (bf16_t)v.z; o[3] = (bf16_t)v.w;
  *(bf16x4*)(dst + i) = o;
}

// -------- cast-only fp32 -> bf16, one DMODEL*DH matrix --------
__global__ void cast1_v5(const float* __restrict__ src, bf16_t* __restrict__ dst)
{
  const long i = ((long)blockIdx.x * 256 + threadIdx.x) * 4;
  float4 v = *(const float4*)(src + i);
  bf16x4 o;
  o[0] = (bf16_t)v.x; o[1] = (bf16_t)v.y; o[2] = (bf16_t)v.z; o[3] = (bf16_t)v.w;
  *(bf16x4*)(dst + i) = o;
}

// ---------------- LayerNorm over last dim (768): fp32 in -> bf16 out ----------------
__global__ void ln_v5(const float* __restrict__ x, const float* __restrict__ g,
                      const float* __restrict__ b, bf16_t* __restrict__ y)
{
  const long row = blockIdx.x;
  const int tid = threadIdx.x;
  const float* xr = x + row * DMODEL;
  float v0 = xr[tid], v1 = xr[tid + 256], v2 = xr[tid + 512];
  float s  = v0 + v1 + v2;
  float ss = v0*v0 + v1*v1 + v2*v2;
  for (int o = 32; o; o >>= 1) { s += __shfl_down(s, o); ss += __shfl_down(ss, o); }
  __shared__ float rs[4], rss[4];
  const int wave = tid >> 6, lane = tid & 63;
  if (lane == 0) { rs[wave] = s; rss[wave] = ss; }
  __syncthreads();
  s  = rs[0] + rs[1] + rs[2] + rs[3];
  ss = rss[0] + rss[1] + rss[2] + rss[3];
  const float inv = 1.0f / (float)DMODEL;
  const float mean = s * inv;
  const float var  = ss * inv - mean * mean;
  const float rstd = rsqrtf(var + 1e-5f);
  bf16_t* yr = y + row * DMODEL;
  yr[tid]       = (bf16_t)(((v0 - mean) * rstd) * g[tid]       + b[tid]);
  yr[tid + 256] = (bf16_t)(((v1 - mean) * rstd) * g[tid + 256] + b[tid + 256]);
  yr[tid + 512] = (bf16_t)(((v2 - mean) * rstd) * g[tid + 512] + b[tid + 512]);
}

// ---------------- softmax over rows of 1024, in place, bf16 ----------------
__global__ void softmax_v5(bf16_t* __restrict__ S)
{
  const long row = blockIdx.x;
  const int tid = threadIdx.x;
  bf16_t* p = S + row * SEQ + tid * 4;
  bf16x4 v = *(const bf16x4*)p;
  float f0 = (float)v[0], f1 = (float)v[1], f2 = (float)v[2], f3 = (float)v[3];
  float m = fmaxf(fmaxf(f0, f1), fmaxf(f2, f3));
  for (int o = 32; o; o >>= 1) m = fmaxf(m, __shfl_down(m, o));
  __shared__ float rm[4], rsum[4];
  const int wave = tid >> 6, lane = tid & 63;
  if (lane == 0) rm[wave] = m;
  __syncthreads();
  m = fmaxf(fmaxf(rm[0], rm[1]), fmaxf(rm[2], rm[3]));
  float e0 = __expf(f0 - m), e1 = __expf(f1 - m), e2 = __expf(f2 - m), e3 = __expf(f3 - m);
  float s = e0 + e1 + e2 + e3;
  for (int o = 32; o; o >>= 1) s += __shfl_down(s, o);
  if (lane == 0) rsum[wave] = s;
  __syncthreads();
  s = rsum[0] + rsum[1] + rsum[2] + rsum[3];
  const float invs = 1.0f / s;
  bf16x4 o4;
  o4[0] = (bf16_t)(e0 * invs); o4[1] = (bf16_t)(e1 * invs);
  o4[2] = (bf16_t)(e2 * invs); o4[3] = (bf16_t)(e3 * invs);
  *(bf16x4*)p = o4;
}

// ---------------- finalize: o = acc + bias[col] + add ----------------
__global__ void finalize_v5(const float* __restrict__ acc, const float* __restrict__ add,
                            const float* __restrict__ bias, float* __restrict__ o)
{
  const long i = (long)blockIdx.x * 256 + threadIdx.x;
  const int c = (int)(i % DMODEL);
  o[i] = acc[i] + bias[c] + add[i];
}

// ------- split-K reduce: o = sum_{n<NP} p[n*plane] + bias[col] + add (float4) -------
template<int NP>
__global__ void reduce_v5(const float* __restrict__ p, const float* __restrict__ add,
                          const float* __restrict__ bias, float* __restrict__ o,
                          long plane)
{
  const long i = ((long)blockIdx.x * 256 + threadIdx.x) * 4;
  float4 s = *(const float4*)(p + i);
#pragma unroll
  for (int n = 1; n < NP; ++n) {
    float4 v = *(const float4*)(p + i + (long)n * plane);
    s.x += v.x; s.y += v.y; s.z += v.z; s.w += v.w;
  }
  const int c = (int)(i % DMODEL);
  float4 bv = *(const float4*)(bias + c);
  float4 av = *(const float4*)(add + i);
  float4 r;
  r.x = s.x + bv.x + av.x; r.y = s.y + bv.y + av.y;
  r.z = s.z + bv.z + av.z; r.w = s.w + bv.w + av.w;
  *(float4*)(o + i) = r;
}

// ---------------------------------------------------------------------------
extern "C" void kernel_launch(void* const* d_in, const int* in_sizes, int n_in,
                              void* d_out, int out_size, void* d_ws, size_t ws_size,
                              hipStream_t stream)
{
  (void)in_sizes; (void)n_in; (void)out_size;
  const float* x    = (const float*)d_in[0];
  const float* Wq   = (const float*)d_in[1];
  const float* Wk   = (const float*)d_in[2];
  const float* Wv   = (const float*)d_in[3];
  const float* Wu   = (const float*)d_in[4];
  const float* bu   = (const float*)d_in[5];
  const float* ln1g = (const float*)d_in[6];
  const float* ln1b = (const float*)d_in[7];
  const float* ln2g = (const float*)d_in[8];
  const float* ln2b = (const float*)d_in[9];
  const float* W1   = (const float*)d_in[10];
  const float* b1   = (const float*)d_in[11];
  const float* W2   = (const float*)d_in[12];
  const float* b2   = (const float*)d_in[13];
  float* out = (float*)d_out;

  char* ws = (char*)d_ws;
  size_t off = 0;
  auto alloc = [&](size_t bytes) -> void* {
    void* p = (void*)(ws + off);
    off += (bytes + 255) & ~(size_t)255;
    return p;
  };

  const float qk_alpha = 1.0f / sqrtf((float)DMODEL);
  dim3 tb(32, 8);

  const size_t SZ_W   = (size_t)DMODEL * DH * 2;         // 14,155,776
  const size_t SZ_MT  = (size_t)NHEAD * DMODEL * DMODEL * 2;
  const size_t SZ_Y   = (size_t)ROWS * DMODEL * 2;       // 6,291,456
  const size_t SZ_X2  = (size_t)ROWS * DMODEL * 4;       // 12,582,912

  if (ws_size >= (size_t)112e6) {
    // ===== PLAN B: batch-looped folded (~110.1 MB) =====
    bf16_t* MT  = (bf16_t*)alloc(SZ_MT);   // [h][g][f] = sum_d Wk[g,hd] Wq[f,hd]
    bf16_t* PhT = (bf16_t*)alloc(SZ_MT);   // [h][d][g] = sum_m Wu[hm,d] Wv[g,hm]
    bf16_t* y   = (bf16_t*)alloc(SZ_Y);
    float*  x2f = (float* )alloc(SZ_X2);
    char*   BIG = (char*  )alloc((size_t)62914560);
    // attention-phase BIG layout (per batch):
    bf16_t* T_b  = (bf16_t*)(BIG);                 // [h][i][g]  18,874,368
    bf16_t* S_b  = (bf16_t*)(BIG + 18874368);      // [i][h*1024+j] 25,165,824
    bf16_t* Zt_b = (bf16_t*)(BIG + 44040192);      // [d][h*1024+j] 18,874,368
    float*  part = (float* )(BIG);                 // 6 x 3,145,728 (alias T_b)
    // staging layout:
    bf16_t* Wqb = (bf16_t*)(BIG);
    bf16_t* Wkb = (bf16_t*)(BIG + SZ_W);
    bf16_t* Wvb = (bf16_t*)(BIG + 2*SZ_W);
    bf16_t* WuT = (bf16_t*)(BIG + 3*SZ_W);
    // MLP layout:
    bf16_t* W1T   = (bf16_t*)(BIG);
    bf16_t* W2T   = (bf16_t*)(BIG + 4718592);
    bf16_t* t     = (bf16_t*)(BIG + 9437184);      // 25,165,824
    float*  partM = (float* )(BIG + 34603008);     // 2 x 12,582,912
    bf16_t* y2    = y;

    // ---- weight folds ----
    cast3_v5<<<dim3(6912, 1, 3), 256, 0, stream>>>(Wq, Wk, Wv, Wqb, Wkb, Wvb);
    tr_f2b_v5<<<dim3(DMODEL/32, DH/32), tb, 0, stream>>>(Wu, WuT, DMODEL, DH);
    gemm_v5<false,false,false,0><<<dim3(6, 6, NHEAD), 256, 0, stream>>>(
        Wkb, Wqb, MT, DMODEL, DH, DH, DMODEL, NHEAD,
        0, DMODEL, 0, DMODEL, 0, (long)DMODEL*DMODEL, nullptr, nullptr, 0, 1.0f);
    gemm_v5<false,false,false,0><<<dim3(6, 6, NHEAD), 256, 0, stream>>>(
        WuT, Wvb, PhT, DMODEL, DH, DH, DMODEL, NHEAD,
        0, DMODEL, 0, DMODEL, 0, (long)DMODEL*DMODEL, nullptr, nullptr, 0, 1.0f);

    // ---- attention, per batch ----
    ln_v5<<<ROWS, 256, 0, stream>>>(x, ln1g, ln1b, y);
    for (int b = 0; b < NBATCH; ++b) {
      const bf16_t* yb = y + (long)b * SEQ * DMODEL;
      // T_b[h][i][g] = y_b @ M_h
      gemm_v5<false,false,false,0><<<dim3(6, 8, NHEAD), 256, 0, stream>>>(
          yb, MT, T_b, DMODEL, DMODEL, DMODEL, DMODEL, NHEAD,
          0, 0, 0, (long)DMODEL*DMODEL, 0, (long)SEQ*DMODEL,
          nullptr, nullptr, 0, 1.0f);
      // S_b[i][h*1024+j] = (T_bh @ y_b^T) * alpha
      gemm_v5<false,false,false,0><<<dim3(8, 8, NHEAD), 256, 0, stream>>>(
          T_b, yb, S_b, DMODEL, DMODEL, DMODEL, NHEAD*SEQ, NHEAD,
          0, (long)SEQ*DMODEL, 0, 0, 0, (long)SEQ,
          nullptr, nullptr, 0, qk_alpha);
      softmax_v5<<<NHEAD*SEQ, 256, 0, stream>>>(S_b);
      // Zt_b[d][h*1024+j] = PhT_h @ y_b^T
      gemm_v5<false,false,false,0><<<dim3(8, 6, NHEAD), 256, 0, stream>>>(
          PhT, yb, Zt_b, DMODEL, DMODEL, DMODEL, NHEAD*SEQ, NHEAD,
          0, (long)DMODEL*DMODEL, 0, 0, 0, (long)SEQ,
          nullptr, nullptr, 0, 1.0f);
      // out_b = S_b(1024x12288) @ Zt_b^T, split-K 6
      gemm_v5<false,false,false,1><<<dim3(6, 8, 6), 256, 0, stream>>>(
          S_b, Zt_b, part, NHEAD*SEQ/6, NHEAD*SEQ, NHEAD*SEQ, DMODEL, 6,
          0, (long)(NHEAD*SEQ/6), 0, (long)(NHEAD*SEQ/6), 0, (long)SEQ*DMODEL,
          nullptr, nullptr, 0, 1.0f);
      reduce_v5<6><<<(SEQ*DMODEL)/1024, 256, 0, stream>>>(
          part, x + (long)b*SEQ*DMODEL, bu, x2f + (long)b*SEQ*DMODEL,
          (long)SEQ*DMODEL);
    }

    // ---- MLP ----
    tr_f2b_v5<<<dim3(DFF/32, DMODEL/32), tb, 0, stream>>>(W1, W1T, DFF, DMODEL);
    tr_f2b_v5<<<dim3(DMODEL/32, DFF/32), tb, 0, stream>>>(W2, W2T, DMODEL, DFF);
    ln_v5<<<ROWS, 256, 0, stream>>>(x2f, ln2g, ln2b, y2);
    gemm_v5<true,false,true,0><<<dim3(DFF/128, ROWS/128, 1), 256, 0, stream>>>(
        y2, W1T, t, DMODEL, DMODEL, DMODEL, DFF, 1, 0,0,0,0,0,0, b1, nullptr, 0, 1.0f);
    gemm_v5<false,false,false,1><<<dim3(6, ROWS/128, 2), 256, 0, stream>>>(
        t, W2T, partM, DFF/2, DFF, DFF, DMODEL, 2,
        0, (long)(DFF/2), 0, (long)(DFF/2), 0, (long)ROWS*DMODEL,
        nullptr, nullptr, 0, 1.0f);
    reduce_v5<2><<<(ROWS*DMODEL)/1024, 256, 0, stream>>>(
        partM, x2f, b2, out, (long)ROWS*DMODEL);
  } else if (ws_size >= (size_t)70e6) {
    // ===== PLAN C: head-looped folded (~68.2 MB) =====
    bf16_t* MT  = (bf16_t*)alloc(SZ_MT);
    bf16_t* PhT = (bf16_t*)alloc(SZ_MT);
    bf16_t* y   = (bf16_t*)alloc(SZ_Y);
    char*   R   = (char*  )alloc((size_t)33554432);
    bf16_t* WAb = (bf16_t*)(R);
    bf16_t* WBb = (bf16_t*)(R + SZ_W);
    float*  x2f = (float* )(R);
    bf16_t* T_h = (bf16_t*)(R + 12582912);
    bf16_t* S_h = (bf16_t*)(R + 18874368);
    bf16_t* Z_h = (bf16_t*)(R + 27262976);
    bf16_t* W1T = (bf16_t*)(R + 12582912);
    bf16_t* W2T = (bf16_t*)(R + 17301504);
    bf16_t* t   = (bf16_t*)MT;
    bf16_t* y2  = y;

    cast1_v5<<<6912, 256, 0, stream>>>(Wq, WAb);
    cast1_v5<<<6912, 256, 0, stream>>>(Wk, WBb);
    gemm_v5<false,false,false,0><<<dim3(6, 6, NHEAD), 256, 0, stream>>>(
        WBb, WAb, MT, DMODEL, DH, DH, DMODEL, NHEAD,
        0, DMODEL, 0, DMODEL, 0, (long)DMODEL*DMODEL, nullptr, nullptr, 0, 1.0f);
    cast1_v5<<<6912, 256, 0, stream>>>(Wv, WAb);
    tr_f2b_v5<<<dim3(DMODEL/32, DH/32), tb, 0, stream>>>(Wu, WBb, DMODEL, DH);
    gemm_v5<false,false,false,0><<<dim3(6, 6, NHEAD), 256, 0, stream>>>(
        WBb, WAb, PhT, DMODEL, DH, DH, DMODEL, NHEAD,
        0, DMODEL, 0, DMODEL, 0, (long)DMODEL*DMODEL, nullptr, nullptr, 0, 1.0f);

    ln_v5<<<ROWS, 256, 0, stream>>>(x, ln1g, ln1b, y);
    for (int h = 0; h < NHEAD; ++h) {
      const bf16_t* MTh  = MT  + (long)h * DMODEL * DMODEL;
      const bf16_t* PhTh = PhT + (long)h * DMODEL * DMODEL;
      gemm_v5<false,false,false,0><<<dim3(6, ROWS/128, 1), 256, 0, stream>>>(
          y, MTh, T_h, DMODEL, DMODEL, DMODEL, DMODEL, 1,
          0,0,0,0,0,0, nullptr, nullptr, 0, 1.0f);
      gemm_v5<false,false,false,0><<<dim3(8, 8, NBATCH), 256, 0, stream>>>(
          T_h, y, S_h, DMODEL, DMODEL, DMODEL, SEQ, NBATCH,
          0, (long)SEQ*DMODEL, 0, (long)SEQ*DMODEL, 0, (long)SEQ*SEQ,
          nullptr, nullptr, 0, qk_alpha);
      softmax_v5<<<ROWS, 256, 0, stream>>>(S_h);
      gemm_v5<false,false,false,0><<<dim3(8, 6, NBATCH), 256, 0, stream>>>(
          PhTh, y, Z_h, DMODEL, DMODEL, DMODEL, SEQ, NBATCH,
          0, 0, 0, (long)SEQ*DMODEL, 0, (long)DMODEL*SEQ,
          nullptr, nullptr, 0, 1.0f);
      if (h == 0)
        gemm_v5<false,false,false,1><<<dim3(6, 8, NBATCH), 256, 0, stream>>>(
            S_h, Z_h, x2f, SEQ, SEQ, SEQ, DMODEL, NBATCH,
            0, (long)SEQ*SEQ, 0, (long)DMODEL*SEQ, 0, (long)SEQ*DMODEL,
            nullptr, nullptr, 0, 1.0f);
      else
        gemm_v5<false,false,false,2><<<dim3(6, 8, NBATCH), 256, 0, stream>>>(
            S_h, Z_h, x2f, SEQ, SEQ, SEQ, DMODEL, NBATCH,
            0, (long)SEQ*SEQ, 0, (long)DMODEL*SEQ, 0, (long)SEQ*DMODEL,
            nullptr, nullptr, 0, 1.0f);
    }
    finalize_v5<<<(ROWS*DMODEL)/256, 256, 0, stream>>>(x2f, x, bu, x2f);

    tr_f2b_v5<<<dim3(DFF/32, DMODEL/32), tb, 0, stream>>>(W1, W1T, DFF, DMODEL);
    tr_f2b_v5<<<dim3(DMODEL/32, DFF/32), tb, 0, stream>>>(W2, W2T, DMODEL, DFF);
    ln_v5<<<ROWS, 256, 0, stream>>>(x2f, ln2g, ln2b, y2);
    gemm_v5<true,false,true,0><<<dim3(DFF/128, ROWS/128, 1), 256, 0, stream>>>(
        y2, W1T, t, DMODEL, DMODEL, DMODEL, DFF, 1, 0,0,0,0,0,0, b1, nullptr, 0, 1.0f);
    gemm_v5<true,true,false,1><<<dim3(6, ROWS/128, 1), 256, 0, stream>>>(
        t, W2T, out, DFF/2, DFF, DFF, DMODEL, 1, 0,0,0,0,0,0,
        b2, x2f, DMODEL, 1.0f);
    gemm_v5<false,false,false,2><<<dim3(6, ROWS/128, 1), 256, 0, stream>>>(
        t + DFF/2, W2T + DFF/2, out, DFF/2, DFF, DFF, DMODEL, 1, 0,0,0,0,0,0,
        nullptr, nullptr, 0, 1.0f);
  } else {
    // ===== legacy SMALL PLAN (~43 MB) =====
    bf16_t* W1T   = (bf16_t*)alloc((size_t)DMODEL * DFF * 2);
    bf16_t* W2T   = (bf16_t*)alloc((size_t)DMODEL * DFF * 2);
    bf16_t* y     = (bf16_t*)alloc(SZ_Y);
    float*  x2f   = (float* )alloc(SZ_X2);
    char*   reg1  = (char*)alloc((size_t)3*DMODEL*DMODEL*2 + (size_t)DMODEL*DMODEL*2 + (size_t)SEQ*DMODEL*2);
    bf16_t* WhT   = (bf16_t*)reg1;
    bf16_t* WuTh  = (bf16_t*)(reg1 + (size_t)3*DMODEL*DMODEL*2);
    bf16_t* attb  = (bf16_t*)(reg1 + (size_t)4*DMODEL*DMODEL*2);
    bf16_t* y2    = (bf16_t*)reg1;
    char*   reg2  = (char*)alloc((size_t)SEQ*3*DMODEL*2 + (size_t)DMODEL*SEQ*2 + (size_t)SEQ*SEQ*2);
    bf16_t* QKVb  = (bf16_t*)reg2;
    bf16_t* Vtb   = (bf16_t*)(reg2 + (size_t)SEQ*3*DMODEL*2);
    bf16_t* Sb    = (bf16_t*)(reg2 + (size_t)SEQ*3*DMODEL*2 + (size_t)DMODEL*SEQ*2);
    bf16_t* tslab = (bf16_t*)reg2;

    tr_f2b_v5<<<dim3(DFF/32, DMODEL/32), tb, 0, stream>>>(W1, W1T, DFF, DMODEL);
    tr_f2b_v5<<<dim3(DMODEL/32, DFF/32), tb, 0, stream>>>(W2, W2T, DMODEL, DFF);
    ln_v5<<<ROWS, 256, 0, stream>>>(x, ln1g, ln1b, y);

    const int N3 = 3 * DMODEL;
    for (int h = 0; h < NHEAD; ++h) {
      tr_wh_v5<<<dim3(24, 24, 4), tb, 0, stream>>>(Wq, Wk, Wv, Wu, WhT, WuTh, h);
      for (int b = 0; b < NBATCH; ++b) {
        const bf16_t* yb = y + (size_t)b * SEQ * DMODEL;
        gemm_v5<false,false,false,0><<<dim3(N3/128, SEQ/128, 1), 256, 0, stream>>>(
            yb, WhT, QKVb, DMODEL, DMODEL, DMODEL, N3, 1, 0,0,0,0,0,0,
            nullptr, nullptr, 0, 1.0f);
        tr_b_v5<<<dim3(DMODEL/32, SEQ/32, 1), tb, 0, stream>>>(
            QKVb + 2*DMODEL, Vtb, N3, SEQ, 1, 0,0,0,0);
        gemm_v5<false,false,false,0><<<dim3(SEQ/128, SEQ/128, 1), 256, 0, stream>>>(
            QKVb, QKVb + DMODEL, Sb, DMODEL, N3, N3, SEQ, 1, 0,0,0,0,0,0,
            nullptr, nullptr, 0, qk_alpha);
        softmax_v5<<<SEQ, 256, 0, stream>>>(Sb);
        gemm_v5<false,false,false,0><<<dim3(DMODEL/128, SEQ/128, 1), 256, 0, stream>>>(
            Sb, Vtb, attb, SEQ, SEQ, SEQ, DMODEL, 1, 0,0,0,0,0,0,
            nullptr, nullptr, 0, 1.0f);
        float* x2b = x2f + (size_t)b * SEQ * DMODEL;
        if (h == 0)
          gemm_v5<false,false,false,1><<<dim3(DMODEL/128, SEQ/128, 1), 256, 0, stream>>>(
              attb, WuTh, x2b, DMODEL, DMODEL, DMODEL, DMODEL, 1, 0,0,0,0,0,0,
              nullptr, nullptr, 0, 1.0f);
        else
          gemm_v5<false,false,false,2><<<dim3(DMODEL/128, SEQ/128, 1), 256, 0, stream>>>(
              attb, WuTh, x2b, DMODEL, DMODEL, DMODEL, DMODEL, 1, 0,0,0,0,0,0,
              nullptr, nullptr, 0, 1.0f);
      }
    }
    finalize_v5<<<(ROWS*DMODEL)/256, 256, 0, stream>>>(x2f, x, bu, x2f);
    ln_v5<<<ROWS, 256, 0, stream>>>(x2f, ln2g, ln2b, y2);
    for (int kb = 0; kb < 4; ++kb) {
      gemm_v5<true,false,true,0><<<dim3(DMODEL/128, ROWS/128, 1), 256, 0, stream>>>(
          y2, W1T + (size_t)kb*DMODEL*DMODEL, tslab, DMODEL, DMODEL, DMODEL, DMODEL, 1,
          0,0,0,0,0,0, b1 + kb*DMODEL, nullptr, 0, 1.0f);
      if (kb == 0)
        gemm_v5<true,true,false,1><<<dim3(DMODEL/128, ROWS/128, 1), 256, 0, stream>>>(
            tslab, W2T + (size_t)kb*DMODEL, out, DMODEL, DMODEL, DFF, DMODEL, 1,
            0,0,0,0,0,0, b2, x2f, DMODEL, 1.0f);
      else
        gemm_v5<false,false,false,2><<<dim3(DMODEL/128, ROWS/128, 1), 256, 0, stream>>>(
            tslab, W2T + (size_t)kb*DMODEL, out, DMODEL, DMODEL, DFF, DMODEL, 1,
            0,0,0,0,0,0, nullptr, nullptr, 0, 1.0f);
    }
  }
}

// Round 6
// 1169.739 us; speedup vs baseline: 1.1188x; 1.1188x over previous
//
#include <hip/hip_runtime.h>
#include <cstdint>
#include <cmath>

// v6: BK=64 simple-loop GEMM (pipeline reverted). Plan A (>=299e6): full-batch
//     folded plan, attention = 6 big dispatches. Plan B (>=112e6): batch-looped.
//     Plan C (>=70e6): head-looped. All use gemm_v6 (K%64==0 at every call).

typedef __bf16 bf16_t;
typedef __bf16 bf16x8 __attribute__((ext_vector_type(8)));
typedef __bf16 bf16x4 __attribute__((ext_vector_type(4)));
typedef float floatx4 __attribute__((ext_vector_type(4)));

#define DMODEL 768
#define NHEAD  12
#define SEQ    1024
#define NBATCH 4
#define ROWS   (NBATCH*SEQ)   // 4096
#define DH     (DMODEL*NHEAD) // 9216
#define DFF    (4*DMODEL)     // 3072

// ---------------------------------------------------------------------------
// GEMM: C = alpha*(A @ B^T) [+bias[col]] [relu] [+res]   (fp32 bias/res/out)
// A: M x K (lda) bf16, BT: N x K (ldb) bf16, C: M x N (ldc). fp32 accum.
// OMODE: 0 = bf16 store, 1 = f32 store, 2 = f32 accumulate
// Batched via blockIdx.z: off = (z/bdiv)*hi + (z%bdiv)*lo  (element offsets)
// 128x128 tile, BK=64 (two frag-ordered 128x32 panels), 4 waves x (4x4) MFMA.
// Requires K % 64 == 0.
// ---------------------------------------------------------------------------
template<bool BIAS, bool RES, bool RELU, int OMODE>
__global__ __launch_bounds__(256)
void gemm_v6(const bf16_t* __restrict__ A, const bf16_t* __restrict__ BT,
             void* __restrict__ Cv, int K, int lda, int ldb, int ldc,
             int bdiv, long sa_hi, long sa_lo, long sb_hi, long sb_lo,
             long sc_hi, long sc_lo,
             const float* __restrict__ bias, const float* __restrict__ res,
             int ldres, float alpha)
{
  __shared__ __align__(16) bf16_t As[128*64];   // panel p at p*4096 elems
  __shared__ __align__(16) bf16_t Bs[128*64];

  const int tid  = threadIdx.x;
  const int wave = tid >> 6;
  const int lane = tid & 63;
  const int r    = lane & 15;   // row within 16-tile
  const int q    = lane >> 4;   // k-chunk (8 elems each)

  const int z = blockIdx.z;
  A  += (long)(z / bdiv) * sa_hi + (long)(z % bdiv) * sa_lo;
  BT += (long)(z / bdiv) * sb_hi + (long)(z % bdiv) * sb_lo;
  const long coff = (long)(z / bdiv) * sc_hi + (long)(z % bdiv) * sc_lo;

  const int bm = blockIdx.y * 128;
  const int bn = blockIdx.x * 128;
  const int wm = (wave & 1) * 64;
  const int wn = (wave >> 1) * 64;

  const int blk0 = 2*wave, blk1 = 2*wave + 1;
  const bf16_t* a_src0 = A  + (long)(bm + blk0*16 + r) * lda + q*8;
  const bf16_t* a_src1 = A  + (long)(bm + blk1*16 + r) * lda + q*8;
  const bf16_t* b_src0 = BT + (long)(bn + blk0*16 + r) * ldb + q*8;
  const bf16_t* b_src1 = BT + (long)(bn + blk1*16 + r) * ldb + q*8;
  const int da0 = blk0*512 + lane*8;
  const int da1 = blk1*512 + lane*8;

  const int am = (wave & 1) * 4;
  const int bb = (wave >> 1) * 4;

  floatx4 acc[4][4] = {};

  for (int k0 = 0; k0 < K; k0 += 64) {
    // stage both 32-wide panels: 8 x b128 loads in flight together
    bf16x8 a00 = *(const bf16x8*)(a_src0 + k0);
    bf16x8 a01 = *(const bf16x8*)(a_src0 + k0 + 32);
    bf16x8 a10 = *(const bf16x8*)(a_src1 + k0);
    bf16x8 a11 = *(const bf16x8*)(a_src1 + k0 + 32);
    bf16x8 b00 = *(const bf16x8*)(b_src0 + k0);
    bf16x8 b01 = *(const bf16x8*)(b_src0 + k0 + 32);
    bf16x8 b10 = *(const bf16x8*)(b_src1 + k0);
    bf16x8 b11 = *(const bf16x8*)(b_src1 + k0 + 32);
    *(bf16x8*)(As + da0)        = a00;
    *(bf16x8*)(As + 4096 + da0) = a01;
    *(bf16x8*)(As + da1)        = a10;
    *(bf16x8*)(As + 4096 + da1) = a11;
    *(bf16x8*)(Bs + da0)        = b00;
    *(bf16x8*)(Bs + 4096 + da0) = b01;
    *(bf16x8*)(Bs + da1)        = b10;
    *(bf16x8*)(Bs + 4096 + da1) = b11;
    __syncthreads();
#pragma unroll
    for (int p = 0; p < 2; ++p) {
      bf16x8 afrag[4], bfrag[4];
#pragma unroll
      for (int t = 0; t < 4; ++t) {
        afrag[t] = *(const bf16x8*)(As + p*4096 + (am + t)*512 + lane*8);
        bfrag[t] = *(const bf16x8*)(Bs + p*4096 + (bb + t)*512 + lane*8);
      }
#pragma unroll
      for (int mt = 0; mt < 4; ++mt)
#pragma unroll
        for (int nt = 0; nt < 4; ++nt)
          acc[mt][nt] = __builtin_amdgcn_mfma_f32_16x16x32_bf16(
              afrag[mt], bfrag[nt], acc[mt][nt], 0, 0, 0);
    }
    __syncthreads();
  }

  // epilogue: C/D layout col=lane&15, row=(lane>>4)*4+e
  const int row0 = bm + wm + q*4;
  const int col0 = bn + wn + r;
#pragma unroll
  for (int nt = 0; nt < 4; ++nt) {
    const int col = col0 + nt*16;
    float bv = 0.f;
    if (BIAS) bv = bias[col];
#pragma unroll
    for (int mt = 0; mt < 4; ++mt) {
#pragma unroll
      for (int e = 0; e < 4; ++e) {
        const int rowi = row0 + mt*16 + e;
        float v = acc[mt][nt][e] * alpha;
        if (BIAS) v += bv;
        if (RELU) v = fmaxf(v, 0.f);
        if (RES)  v += res[(long)rowi * ldres + col];
        const long idx = coff + (long)rowi * ldc + col;
        if (OMODE == 0)      ((bf16_t*)Cv)[idx] = (bf16_t)v;
        else if (OMODE == 1) ((float*)Cv)[idx] = v;
        else                 ((float*)Cv)[idx] += v;
      }
    }
  }
}

// -------- 32x32 tiled transpose, fp32 in -> bf16 out --------
__global__ void tr_f2b_v6(const float* __restrict__ in, bf16_t* __restrict__ out,
                          int ldi, int ldo)
{
  __shared__ bf16_t tile[32][34];
  const int c0 = blockIdx.x * 32, r0 = blockIdx.y * 32;
  const int tx = threadIdx.x, ty = threadIdx.y;
#pragma unroll
  for (int i = 0; i < 4; ++i)
    tile[ty + 8*i][tx] = (bf16_t)in[(long)(r0 + ty + 8*i) * ldi + c0 + tx];
  __syncthreads();
#pragma unroll
  for (int i = 0; i < 4; ++i)
    out[(long)(c0 + ty + 8*i) * ldo + r0 + tx] = tile[tx][ty + 8*i];
}

// -------- batched 32x32 tiled transpose, bf16 -> bf16 (small plan) --------
__global__ void tr_b_v6(const bf16_t* __restrict__ in, bf16_t* __restrict__ out,
                        int ldi, int ldo, int bdiv,
                        long si_hi, long si_lo, long so_hi, long so_lo)
{
  __shared__ bf16_t tile[32][34];
  const int z = blockIdx.z;
  in  += (long)(z / bdiv) * si_hi + (long)(z % bdiv) * si_lo;
  out += (long)(z / bdiv) * so_hi + (long)(z % bdiv) * so_lo;
  const int c0 = blockIdx.x * 32, r0 = blockIdx.y * 32;
  const int tx = threadIdx.x, ty = threadIdx.y;
#pragma unroll
  for (int i = 0; i < 4; ++i)
    tile[ty + 8*i][tx] = in[(long)(r0 + ty + 8*i) * ldi + c0 + tx];
  __syncthreads();
#pragma unroll
  for (int i = 0; i < 4; ++i)
    out[(long)(c0 + ty + 8*i) * ldo + r0 + tx] = tile[tx][ty + 8*i];
}

// -------- per-head weight transposes (small plan) --------
__global__ void tr_wh_v6(const float* __restrict__ Wq, const float* __restrict__ Wk,
                         const float* __restrict__ Wv, const float* __restrict__ Wu,
                         bf16_t* __restrict__ WhT, bf16_t* __restrict__ WuTh, int h)
{
  __shared__ bf16_t tile[32][34];
  const int z = blockIdx.z;
  const float* in; bf16_t* out; int ldi;
  if (z < 3) {
    const float* W = (z == 0) ? Wq : (z == 1) ? Wk : Wv;
    in  = W + (long)h * DMODEL;
    ldi = DH;
    out = WhT + (long)z * DMODEL * DMODEL;
  } else {
    in  = Wu + (long)h * DMODEL * DMODEL;
    ldi = DMODEL;
    out = WuTh;
  }
  const int c0 = blockIdx.x * 32, r0 = blockIdx.y * 32;
  const int tx = threadIdx.x, ty = threadIdx.y;
#pragma unroll
  for (int i = 0; i < 4; ++i)
    tile[ty + 8*i][tx] = (bf16_t)in[(long)(r0 + ty + 8*i) * ldi + c0 + tx];
  __syncthreads();
#pragma unroll
  for (int i = 0; i < 4; ++i)
    out[(long)(c0 + ty + 8*i) * DMODEL + r0 + tx] = tile[tx][ty + 8*i];
}

// -------- cast-only fp32 -> bf16, 3 matrices of DMODEL*DH --------
__global__ void cast3_v6(const float* __restrict__ a, const float* __restrict__ b,
                         const float* __restrict__ c,
                         bf16_t* __restrict__ oa, bf16_t* __restrict__ ob,
                         bf16_t* __restrict__ oc)
{
  const float* src = (blockIdx.z == 0) ? a : (blockIdx.z == 1) ? b : c;
  bf16_t* dst      = (blockIdx.z == 0) ? oa : (blockIdx.z == 1) ? ob : oc;
  const long i = ((long)blockIdx.x * 256 + threadIdx.x) * 4;
  float4 v = *(const float4*)(src + i);
  bf16x4 o;
  o[0] = (bf16_t)v.x; o[1] = (bf16_t)v.y; o[2] = (bf16_t)v.z; o[3] = (bf16_t)v.w;
  *(bf16x4*)(dst + i) = o;
}

// -------- cast-only fp32 -> bf16, one DMODEL*DH matrix --------
__global__ void cast1_v6(const float* __restrict__ src, bf16_t* __restrict__ dst)
{
  const long i = ((long)blockIdx.x * 256 + threadIdx.x) * 4;
  float4 v = *(const float4*)(src + i);
  bf16x4 o;
  o[0] = (bf16_t)v.x; o[1] = (bf16_t)v.y; o[2] = (bf16_t)v.z; o[3] = (bf16_t)v.w;
  *(bf16x4*)(dst + i) = o;
}

// ---------------- LayerNorm over last dim (768): fp32 in -> bf16 out ----------------
__global__ void ln_v6(const float* __restrict__ x, const float* __restrict__ g,
                      const float* __restrict__ b, bf16_t* __restrict__ y)
{
  const long row = blockIdx.x;
  const int tid = threadIdx.x;
  const float* xr = x + row * DMODEL;
  float v0 = xr[tid], v1 = xr[tid + 256], v2 = xr[tid + 512];
  float s  = v0 + v1 + v2;
  float ss = v0*v0 + v1*v1 + v2*v2;
  for (int o = 32; o; o >>= 1) { s += __shfl_down(s, o); ss += __shfl_down(ss, o); }
  __shared__ float rs[4], rss[4];
  const int wave = tid >> 6, lane = tid & 63;
  if (lane == 0) { rs[wave] = s; rss[wave] = ss; }
  __syncthreads();
  s  = rs[0] + rs[1] + rs[2] + rs[3];
  ss = rss[0] + rss[1] + rss[2] + rss[3];
  const float inv = 1.0f / (float)DMODEL;
  const float mean = s * inv;
  const float var  = ss * inv - mean * mean;
  const float rstd = rsqrtf(var + 1e-5f);
  bf16_t* yr = y + row * DMODEL;
  yr[tid]       = (bf16_t)(((v0 - mean) * rstd) * g[tid]       + b[tid]);
  yr[tid + 256] = (bf16_t)(((v1 - mean) * rstd) * g[tid + 256] + b[tid + 256]);
  yr[tid + 512] = (bf16_t)(((v2 - mean) * rstd) * g[tid + 512] + b[tid + 512]);
}

// ---------------- softmax over rows of 1024, in place, bf16 ----------------
__global__ void softmax_v6(bf16_t* __restrict__ S)
{
  const long row = blockIdx.x;
  const int tid = threadIdx.x;
  bf16_t* p = S + row * SEQ + tid * 4;
  bf16x4 v = *(const bf16x4*)p;
  float f0 = (float)v[0], f1 = (float)v[1], f2 = (float)v[2], f3 = (float)v[3];
  float m = fmaxf(fmaxf(f0, f1), fmaxf(f2, f3));
  for (int o = 32; o; o >>= 1) m = fmaxf(m, __shfl_down(m, o));
  __shared__ float rm[4], rsum[4];
  const int wave = tid >> 6, lane = tid & 63;
  if (lane == 0) rm[wave] = m;
  __syncthreads();
  m = fmaxf(fmaxf(rm[0], rm[1]), fmaxf(rm[2], rm[3]));
  float e0 = __expf(f0 - m), e1 = __expf(f1 - m), e2 = __expf(f2 - m), e3 = __expf(f3 - m);
  float s = e0 + e1 + e2 + e3;
  for (int o = 32; o; o >>= 1) s += __shfl_down(s, o);
  if (lane == 0) rsum[wave] = s;
  __syncthreads();
  s = rsum[0] + rsum[1] + rsum[2] + rsum[3];
  const float invs = 1.0f / s;
  bf16x4 o4;
  o4[0] = (bf16_t)(e0 * invs); o4[1] = (bf16_t)(e1 * invs);
  o4[2] = (bf16_t)(e2 * invs); o4[3] = (bf16_t)(e3 * invs);
  *(bf16x4*)p = o4;
}

// ---------------- finalize: o = acc + bias[col] + add ----------------
__global__ void finalize_v6(const float* __restrict__ acc, const float* __restrict__ add,
                            const float* __restrict__ bias, float* __restrict__ o)
{
  const long i = (long)blockIdx.x * 256 + threadIdx.x;
  const int c = (int)(i % DMODEL);
  o[i] = acc[i] + bias[c] + add[i];
}

// ------- split-K reduce: o = sum_{n<NP} p[n*plane] + bias[col] + add (float4) -------
template<int NP>
__global__ void reduce_v6(const float* __restrict__ p, const float* __restrict__ add,
                          const float* __restrict__ bias, float* __restrict__ o,
                          long plane)
{
  const long i = ((long)blockIdx.x * 256 + threadIdx.x) * 4;
  float4 s = *(const float4*)(p + i);
#pragma unroll
  for (int n = 1; n < NP; ++n) {
    float4 v = *(const float4*)(p + i + (long)n * plane);
    s.x += v.x; s.y += v.y; s.z += v.z; s.w += v.w;
  }
  const int c = (int)(i % DMODEL);
  float4 bv = *(const float4*)(bias + c);
  float4 av = *(const float4*)(add + i);
  float4 r;
  r.x = s.x + bv.x + av.x; r.y = s.y + bv.y + av.y;
  r.z = s.z + bv.z + av.z; r.w = s.w + bv.w + av.w;
  *(float4*)(o + i) = r;
}

// ---------------------------------------------------------------------------
extern "C" void kernel_launch(void* const* d_in, const int* in_sizes, int n_in,
                              void* d_out, int out_size, void* d_ws, size_t ws_size,
                              hipStream_t stream)
{
  (void)in_sizes; (void)n_in; (void)out_size;
  const float* x    = (const float*)d_in[0];
  const float* Wq   = (const float*)d_in[1];
  const float* Wk   = (const float*)d_in[2];
  const float* Wv   = (const float*)d_in[3];
  const float* Wu   = (const float*)d_in[4];
  const float* bu   = (const float*)d_in[5];
  const float* ln1g = (const float*)d_in[6];
  const float* ln1b = (const float*)d_in[7];
  const float* ln2g = (const float*)d_in[8];
  const float* ln2b = (const float*)d_in[9];
  const float* W1   = (const float*)d_in[10];
  const float* b1   = (const float*)d_in[11];
  const float* W2   = (const float*)d_in[12];
  const float* b2   = (const float*)d_in[13];
  float* out = (float*)d_out;

  char* ws = (char*)d_ws;
  size_t off = 0;
  auto alloc = [&](size_t bytes) -> void* {
    void* p = (void*)(ws + off);
    off += (bytes + 255) & ~(size_t)255;
    return p;
  };

  const float qk_alpha = 1.0f / sqrtf((float)DMODEL);
  dim3 tb(32, 8);

  const size_t SZ_W   = (size_t)DMODEL * DH * 2;         // 14,155,776
  const size_t SZ_MT  = (size_t)NHEAD * DMODEL * DMODEL * 2;
  const size_t SZ_Y   = (size_t)ROWS * DMODEL * 2;       // 6,291,456
  const size_t SZ_X2  = (size_t)ROWS * DMODEL * 4;       // 12,582,912

  if (ws_size >= (size_t)299e6) {
    // ===== PLAN A: full-batch folded (~298.9 MB) — attention in 6 dispatches =====
    bf16_t* MT   = (bf16_t*)alloc(SZ_MT);
    bf16_t* PhT  = (bf16_t*)alloc(SZ_MT);
    bf16_t* y    = (bf16_t*)alloc(SZ_Y);
    float*  x2f  = (float* )alloc(SZ_X2);
    bf16_t* T    = (bf16_t*)alloc((size_t)NBATCH * NHEAD * SEQ * DMODEL * 2); // 75.5 MB
    bf16_t* S    = (bf16_t*)alloc((size_t)NBATCH * SEQ * NHEAD * SEQ * 2);    // 100.7 MB
    bf16_t* Zt   = (bf16_t*)alloc((size_t)NBATCH * DMODEL * NHEAD * SEQ * 2); // 75.5 MB
    // aliases (lifetime-disjoint):
    bf16_t* Wqb  = (bf16_t*)T;                     // staging, dead before T written
    bf16_t* Wkb  = (bf16_t*)((char*)T + SZ_W);
    bf16_t* Wvb  = (bf16_t*)((char*)T + 2*SZ_W);
    bf16_t* WuT  = (bf16_t*)((char*)T + 3*SZ_W);
    float*  part = (float*)T;                      // 6 x 12.58 MB = 75.5 (T dead after S)
    bf16_t* W1T  = (bf16_t*)S;                     // MLP phase (S dead after out-gemm)
    bf16_t* W2T  = (bf16_t*)((char*)S + 4718592);
    bf16_t* t    = (bf16_t*)((char*)S + 9437184);  // 25.2 MB
    float*  partM= (float* )((char*)S + 34603008); // 2 x 12.58 MB
    bf16_t* y2   = (bf16_t*)Zt;                    // Zt dead after out-gemm

    // ---- weight folds ----
    cast3_v6<<<dim3(6912, 1, 3), 256, 0, stream>>>(Wq, Wk, Wv, Wqb, Wkb, Wvb);
    tr_f2b_v6<<<dim3(DMODEL/32, DH/32), tb, 0, stream>>>(Wu, WuT, DMODEL, DH);
    gemm_v6<false,false,false,0><<<dim3(6, 6, NHEAD), 256, 0, stream>>>(
        Wkb, Wqb, MT, DMODEL, DH, DH, DMODEL, NHEAD,
        0, DMODEL, 0, DMODEL, 0, (long)DMODEL*DMODEL, nullptr, nullptr, 0, 1.0f);
    gemm_v6<false,false,false,0><<<dim3(6, 6, NHEAD), 256, 0, stream>>>(
        WuT, Wvb, PhT, DMODEL, DH, DH, DMODEL, NHEAD,
        0, DMODEL, 0, DMODEL, 0, (long)DMODEL*DMODEL, nullptr, nullptr, 0, 1.0f);

    // ---- attention, all batches per dispatch (z = b*NHEAD + h) ----
    ln_v6<<<ROWS, 256, 0, stream>>>(x, ln1g, ln1b, y);
    // T[b][h][i][g] = y_b @ M_h
    gemm_v6<false,false,false,0><<<dim3(6, 8, NBATCH*NHEAD), 256, 0, stream>>>(
        y, MT, T, DMODEL, DMODEL, DMODEL, DMODEL, NHEAD,
        (long)SEQ*DMODEL, 0, 0, (long)DMODEL*DMODEL,
        (long)NHEAD*SEQ*DMODEL, (long)SEQ*DMODEL, nullptr, nullptr, 0, 1.0f);
    // S[b][i][h*1024+j] = (T_bh @ y_b^T) * alpha
    gemm_v6<false,false,false,0><<<dim3(8, 8, NBATCH*NHEAD), 256, 0, stream>>>(
        T, y, S, DMODEL, DMODEL, DMODEL, NHEAD*SEQ, NHEAD,
        (long)NHEAD*SEQ*DMODEL, (long)SEQ*DMODEL, (long)SEQ*DMODEL, 0,
        (long)SEQ*NHEAD*SEQ, (long)SEQ, nullptr, nullptr, 0, qk_alpha);
    softmax_v6<<<NBATCH*SEQ*NHEAD, 256, 0, stream>>>(S);
    // Zt[b][d][h*1024+j] = PhT_h @ y_b^T
    gemm_v6<false,false,false,0><<<dim3(8, 6, NBATCH*NHEAD), 256, 0, stream>>>(
        PhT, y, Zt, DMODEL, DMODEL, DMODEL, NHEAD*SEQ, NHEAD,
        0, (long)DMODEL*DMODEL, (long)SEQ*DMODEL, 0,
        (long)DMODEL*NHEAD*SEQ, (long)SEQ, nullptr, nullptr, 0, 1.0f);
    // out_b = S_b(1024x12288) @ Zt_b^T, split-K 6: z = kc*NBATCH + b
    gemm_v6<false,false,false,1><<<dim3(6, 8, 24), 256, 0, stream>>>(
        S, Zt, part, NHEAD*SEQ/6, NHEAD*SEQ, NHEAD*SEQ, DMODEL, NBATCH,
        (long)(NHEAD*SEQ/6), (long)SEQ*NHEAD*SEQ,
        (long)(NHEAD*SEQ/6), (long)DMODEL*NHEAD*SEQ,
        (long)ROWS*DMODEL, (long)SEQ*DMODEL, nullptr, nullptr, 0, 1.0f);
    reduce_v6<6><<<(ROWS*DMODEL)/1024, 256, 0, stream>>>(
        part, x, bu, x2f, (long)ROWS*DMODEL);

    // ---- MLP ----
    tr_f2b_v6<<<dim3(DFF/32, DMODEL/32), tb, 0, stream>>>(W1, W1T, DFF, DMODEL);
    tr_f2b_v6<<<dim3(DMODEL/32, DFF/32), tb, 0, stream>>>(W2, W2T, DMODEL, DFF);
    ln_v6<<<ROWS, 256, 0, stream>>>(x2f, ln2g, ln2b, y2);
    gemm_v6<true,false,true,0><<<dim3(DFF/128, ROWS/128, 1), 256, 0, stream>>>(
        y2, W1T, t, DMODEL, DMODEL, DMODEL, DFF, 1, 0,0,0,0,0,0, b1, nullptr, 0, 1.0f);
    gemm_v6<false,false,false,1><<<dim3(6, ROWS/128, 2), 256, 0, stream>>>(
        t, W2T, partM, DFF/2, DFF, DFF, DMODEL, 2,
        0, (long)(DFF/2), 0, (long)(DFF/2), 0, (long)ROWS*DMODEL,
        nullptr, nullptr, 0, 1.0f);
    reduce_v6<2><<<(ROWS*DMODEL)/1024, 256, 0, stream>>>(
        partM, x2f, b2, out, (long)ROWS*DMODEL);
  } else if (ws_size >= (size_t)112e6) {
    // ===== PLAN B: batch-looped folded (~110.1 MB) =====
    bf16_t* MT  = (bf16_t*)alloc(SZ_MT);
    bf16_t* PhT = (bf16_t*)alloc(SZ_MT);
    bf16_t* y   = (bf16_t*)alloc(SZ_Y);
    float*  x2f = (float* )alloc(SZ_X2);
    char*   BIG = (char*  )alloc((size_t)62914560);
    bf16_t* T_b  = (bf16_t*)(BIG);                 // 18,874,368
    bf16_t* S_b  = (bf16_t*)(BIG + 18874368);      // 25,165,824
    bf16_t* Zt_b = (bf16_t*)(BIG + 44040192);      // 18,874,368
    float*  part = (float* )(BIG);                 // 6 x 3,145,728
    bf16_t* Wqb = (bf16_t*)(BIG);
    bf16_t* Wkb = (bf16_t*)(BIG + SZ_W);
    bf16_t* Wvb = (bf16_t*)(BIG + 2*SZ_W);
    bf16_t* WuT = (bf16_t*)(BIG + 3*SZ_W);
    bf16_t* W1T   = (bf16_t*)(BIG);
    bf16_t* W2T   = (bf16_t*)(BIG + 4718592);
    bf16_t* t     = (bf16_t*)(BIG + 9437184);
    float*  partM = (float* )(BIG + 34603008);
    bf16_t* y2    = y;

    cast3_v6<<<dim3(6912, 1, 3), 256, 0, stream>>>(Wq, Wk, Wv, Wqb, Wkb, Wvb);
    tr_f2b_v6<<<dim3(DMODEL/32, DH/32), tb, 0, stream>>>(Wu, WuT, DMODEL, DH);
    gemm_v6<false,false,false,0><<<dim3(6, 6, NHEAD), 256, 0, stream>>>(
        Wkb, Wqb, MT, DMODEL, DH, DH, DMODEL, NHEAD,
        0, DMODEL, 0, DMODEL, 0, (long)DMODEL*DMODEL, nullptr, nullptr, 0, 1.0f);
    gemm_v6<false,false,false,0><<<dim3(6, 6, NHEAD), 256, 0, stream>>>(
        WuT, Wvb, PhT, DMODEL, DH, DH, DMODEL, NHEAD,
        0, DMODEL, 0, DMODEL, 0, (long)DMODEL*DMODEL, nullptr, nullptr, 0, 1.0f);

    ln_v6<<<ROWS, 256, 0, stream>>>(x, ln1g, ln1b, y);
    for (int b = 0; b < NBATCH; ++b) {
      const bf16_t* yb = y + (long)b * SEQ * DMODEL;
      gemm_v6<false,false,false,0><<<dim3(6, 8, NHEAD), 256, 0, stream>>>(
          yb, MT, T_b, DMODEL, DMODEL, DMODEL, DMODEL, NHEAD,
          0, 0, 0, (long)DMODEL*DMODEL, 0, (long)SEQ*DMODEL,
          nullptr, nullptr, 0, 1.0f);
      gemm_v6<false,false,false,0><<<dim3(8, 8, NHEAD), 256, 0, stream>>>(
          T_b, yb, S_b, DMODEL, DMODEL, DMODEL, NHEAD*SEQ, NHEAD,
          0, (long)SEQ*DMODEL, 0, 0, 0, (long)SEQ,
          nullptr, nullptr, 0, qk_alpha);
      softmax_v6<<<NHEAD*SEQ, 256, 0, stream>>>(S_b);
      gemm_v6<false,false,false,0><<<dim3(8, 6, NHEAD), 256, 0, stream>>>(
          PhT, yb, Zt_b, DMODEL, DMODEL, DMODEL, NHEAD*SEQ, NHEAD,
          0, (long)DMODEL*DMODEL, 0, 0, 0, (long)SEQ,
          nullptr, nullptr, 0, 1.0f);
      gemm_v6<false,false,false,1><<<dim3(6, 8, 6), 256, 0, stream>>>(
          S_b, Zt_b, part, NHEAD*SEQ/6, NHEAD*SEQ, NHEAD*SEQ, DMODEL, 6,
          0, (long)(NHEAD*SEQ/6), 0, (long)(NHEAD*SEQ/6), 0, (long)SEQ*DMODEL,
          nullptr, nullptr, 0, 1.0f);
      reduce_v6<6><<<(SEQ*DMODEL)/1024, 256, 0, stream>>>(
          part, x + (long)b*SEQ*DMODEL, bu, x2f + (long)b*SEQ*DMODEL,
          (long)SEQ*DMODEL);
    }

    tr_f2b_v6<<<dim3(DFF/32, DMODEL/32), tb, 0, stream>>>(W1, W1T, DFF, DMODEL);
    tr_f2b_v6<<<dim3(DMODEL/32, DFF/32), tb, 0, stream>>>(W2, W2T, DMODEL, DFF);
    ln_v6<<<ROWS, 256, 0, stream>>>(x2f, ln2g, ln2b, y2);
    gemm_v6<true,false,true,0><<<dim3(DFF/128, ROWS/128, 1), 256, 0, stream>>>(
        y2, W1T, t, DMODEL, DMODEL, DMODEL, DFF, 1, 0,0,0,0,0,0, b1, nullptr, 0, 1.0f);
    gemm_v6<false,false,false,1><<<dim3(6, ROWS/128, 2), 256, 0, stream>>>(
        t, W2T, partM, DFF/2, DFF, DFF, DMODEL, 2,
        0, (long)(DFF/2), 0, (long)(DFF/2), 0, (long)ROWS*DMODEL,
        nullptr, nullptr, 0, 1.0f);
    reduce_v6<2><<<(ROWS*DMODEL)/1024, 256, 0, stream>>>(
        partM, x2f, b2, out, (long)ROWS*DMODEL);
  } else if (ws_size >= (size_t)70e6) {
    // ===== PLAN C: head-looped folded (~68.2 MB) =====
    bf16_t* MT  = (bf16_t*)alloc(SZ_MT);
    bf16_t* PhT = (bf16_t*)alloc(SZ_MT);
    bf16_t* y   = (bf16_t*)alloc(SZ_Y);
    char*   R   = (char*  )alloc((size_t)33554432);
    bf16_t* WAb = (bf16_t*)(R);
    bf16_t* WBb = (bf16_t*)(R + SZ_W);
    float*  x2f = (float* )(R);
    bf16_t* T_h = (bf16_t*)(R + 12582912);
    bf16_t* S_h = (bf16_t*)(R + 18874368);
    bf16_t* Z_h = (bf16_t*)(R + 27262976);
    bf16_t* W1T = (bf16_t*)(R + 12582912);
    bf16_t* W2T = (bf16_t*)(R + 17301504);
    bf16_t* t   = (bf16_t*)MT;
    bf16_t* y2  = y;

    cast1_v6<<<6912, 256, 0, stream>>>(Wq, WAb);
    cast1_v6<<<6912, 256, 0, stream>>>(Wk, WBb);
    gemm_v6<false,false,false,0><<<dim3(6, 6, NHEAD), 256, 0, stream>>>(
        WBb, WAb, MT, DMODEL, DH, DH, DMODEL, NHEAD,
        0, DMODEL, 0, DMODEL, 0, (long)DMODEL*DMODEL, nullptr, nullptr, 0, 1.0f);
    cast1_v6<<<6912, 256, 0, stream>>>(Wv, WAb);
    tr_f2b_v6<<<dim3(DMODEL/32, DH/32), tb, 0, stream>>>(Wu, WBb, DMODEL, DH);
    gemm_v6<false,false,false,0><<<dim3(6, 6, NHEAD), 256, 0, stream>>>(
        WBb, WAb, PhT, DMODEL, DH, DH, DMODEL, NHEAD,
        0, DMODEL, 0, DMODEL, 0, (long)DMODEL*DMODEL, nullptr, nullptr, 0, 1.0f);

    ln_v6<<<ROWS, 256, 0, stream>>>(x, ln1g, ln1b, y);
    for (int h = 0; h < NHEAD; ++h) {
      const bf16_t* MTh  = MT  + (long)h * DMODEL * DMODEL;
      const bf16_t* PhTh = PhT + (long)h * DMODEL * DMODEL;
      gemm_v6<false,false,false,0><<<dim3(6, ROWS/128, 1), 256, 0, stream>>>(
          y, MTh, T_h, DMODEL, DMODEL, DMODEL, DMODEL, 1,
          0,0,0,0,0,0, nullptr, nullptr, 0, 1.0f);
      gemm_v6<false,false,false,0><<<dim3(8, 8, NBATCH), 256, 0, stream>>>(
          T_h, y, S_h, DMODEL, DMODEL, DMODEL, SEQ, NBATCH,
          0, (long)SEQ*DMODEL, 0, (long)SEQ*DMODEL, 0, (long)SEQ*SEQ,
          nullptr, nullptr, 0, qk_alpha);
      softmax_v6<<<ROWS, 256, 0, stream>>>(S_h);
      gemm_v6<false,false,false,0><<<dim3(8, 6, NBATCH), 256, 0, stream>>>(
          PhTh, y, Z_h, DMODEL, DMODEL, DMODEL, SEQ, NBATCH,
          0, 0, 0, (long)SEQ*DMODEL, 0, (long)DMODEL*SEQ,
          nullptr, nullptr, 0, 1.0f);
      if (h == 0)
        gemm_v6<false,false,false,1><<<dim3(6, 8, NBATCH), 256, 0, stream>>>(
            S_h, Z_h, x2f, SEQ, SEQ, SEQ, DMODEL, NBATCH,
            0, (long)SEQ*SEQ, 0, (long)DMODEL*SEQ, 0, (long)SEQ*DMODEL,
            nullptr, nullptr, 0, 1.0f);
      else
        gemm_v6<false,false,false,2><<<dim3(6, 8, NBATCH), 256, 0, stream>>>(
            S_h, Z_h, x2f, SEQ, SEQ, SEQ, DMODEL, NBATCH,
            0, (long)SEQ*SEQ, 0, (long)DMODEL*SEQ, 0, (long)SEQ*DMODEL,
            nullptr, nullptr, 0, 1.0f);
    }
    finalize_v6<<<(ROWS*DMODEL)/256, 256, 0, stream>>>(x2f, x, bu, x2f);

    tr_f2b_v6<<<dim3(DFF/32, DMODEL/32), tb, 0, stream>>>(W1, W1T, DFF, DMODEL);
    tr_f2b_v6<<<dim3(DMODEL/32, DFF/32), tb, 0, stream>>>(W2, W2T, DMODEL, DFF);
    ln_v6<<<ROWS, 256, 0, stream>>>(x2f, ln2g, ln2b, y2);
    gemm_v6<true,false,true,0><<<dim3(DFF/128, ROWS/128, 1), 256, 0, stream>>>(
        y2, W1T, t, DMODEL, DMODEL, DMODEL, DFF, 1, 0,0,0,0,0,0, b1, nullptr, 0, 1.0f);
    gemm_v6<true,true,false,1><<<dim3(6, ROWS/128, 1), 256, 0, stream>>>(
        t, W2T, out, DFF/2, DFF, DFF, DMODEL, 1, 0,0,0,0,0,0,
        b2, x2f, DMODEL, 1.0f);
    gemm_v6<false,false,false,2><<<dim3(6, ROWS/128, 1), 256, 0, stream>>>(
        t + DFF/2, W2T + DFF/2, out, DFF/2, DFF, DFF, DMODEL, 1, 0,0,0,0,0,0,
        nullptr, nullptr, 0, 1.0f);
  } else {
    // ===== legacy SMALL PLAN (~43 MB) =====
    bf16_t* W1T   = (bf16_t*)alloc((size_t)DMODEL * DFF * 2);
    bf16_t* W2T   = (bf16_t*)alloc((size_t)DMODEL * DFF * 2);
    bf16_t* y     = (bf16_t*)alloc(SZ_Y);
    float*  x2f   = (float* )alloc(SZ_X2);
    char*   reg1  = (char*)alloc((size_t)3*DMODEL*DMODEL*2 + (size_t)DMODEL*DMODEL*2 + (size_t)SEQ*DMODEL*2);
    bf16_t* WhT   = (bf16_t*)reg1;
    bf16_t* WuTh  = (bf16_t*)(reg1 + (size_t)3*DMODEL*DMODEL*2);
    bf16_t* attb  = (bf16_t*)(reg1 + (size_t)4*DMODEL*DMODEL*2);
    bf16_t* y2    = (bf16_t*)reg1;
    char*   reg2  = (char*)alloc((size_t)SEQ*3*DMODEL*2 + (size_t)DMODEL*SEQ*2 + (size_t)SEQ*SEQ*2);
    bf16_t* QKVb  = (bf16_t*)reg2;
    bf16_t* Vtb   = (bf16_t*)(reg2 + (size_t)SEQ*3*DMODEL*2);
    bf16_t* Sb    = (bf16_t*)(reg2 + (size_t)SEQ*3*DMODEL*2 + (size_t)DMODEL*SEQ*2);
    bf16_t* tslab = (bf16_t*)reg2;

    tr_f2b_v6<<<dim3(DFF/32, DMODEL/32), tb, 0, stream>>>(W1, W1T, DFF, DMODEL);
    tr_f2b_v6<<<dim3(DMODEL/32, DFF/32), tb, 0, stream>>>(W2, W2T, DMODEL, DFF);
    ln_v6<<<ROWS, 256, 0, stream>>>(x, ln1g, ln1b, y);

    const int N3 = 3 * DMODEL;
    for (int h = 0; h < NHEAD; ++h) {
      tr_wh_v6<<<dim3(24, 24, 4), tb, 0, stream>>>(Wq, Wk, Wv, Wu, WhT, WuTh, h);
      for (int b = 0; b < NBATCH; ++b) {
        const bf16_t* yb = y + (size_t)b * SEQ * DMODEL;
        gemm_v6<false,false,false,0><<<dim3(N3/128, SEQ/128, 1), 256, 0, stream>>>(
            yb, WhT, QKVb, DMODEL, DMODEL, DMODEL, N3, 1, 0,0,0,0,0,0,
            nullptr, nullptr, 0, 1.0f);
        tr_b_v6<<<dim3(DMODEL/32, SEQ/32, 1), tb, 0, stream>>>(
            QKVb + 2*DMODEL, Vtb, N3, SEQ, 1, 0,0,0,0);
        gemm_v6<false,false,false,0><<<dim3(SEQ/128, SEQ/128, 1), 256, 0, stream>>>(
            QKVb, QKVb + DMODEL, Sb, DMODEL, N3, N3, SEQ, 1, 0,0,0,0,0,0,
            nullptr, nullptr, 0, qk_alpha);
        softmax_v6<<<SEQ, 256, 0, stream>>>(Sb);
        gemm_v6<false,false,false,0><<<dim3(DMODEL/128, SEQ/128, 1), 256, 0, stream>>>(
            Sb, Vtb, attb, SEQ, SEQ, SEQ, DMODEL, 1, 0,0,0,0,0,0,
            nullptr, nullptr, 0, 1.0f);
        float* x2b = x2f + (size_t)b * SEQ * DMODEL;
        if (h == 0)
          gemm_v6<false,false,false,1><<<dim3(DMODEL/128, SEQ/128, 1), 256, 0, stream>>>(
              attb, WuTh, x2b, DMODEL, DMODEL, DMODEL, DMODEL, 1, 0,0,0,0,0,0,
              nullptr, nullptr, 0, 1.0f);
        else
          gemm_v6<false,false,false,2><<<dim3(DMODEL/128, SEQ/128, 1), 256, 0, stream>>>(
              attb, WuTh, x2b, DMODEL, DMODEL, DMODEL, DMODEL, 1, 0,0,0,0,0,0,
              nullptr, nullptr, 0, 1.0f);
      }
    }
    finalize_v6<<<(ROWS*DMODEL)/256, 256, 0, stream>>>(x2f, x, bu, x2f);
    ln_v6<<<ROWS, 256, 0, stream>>>(x2f, ln2g, ln2b, y2);
    for (int kb = 0; kb < 4; ++kb) {
      gemm_v6<true,false,true,0><<<dim3(DMODEL/128, ROWS/128, 1), 256, 0, stream>>>(
          y2, W1T + (size_t)kb*DMODEL*DMODEL, tslab, DMODEL, DMODEL, DMODEL, DMODEL, 1,
          0,0,0,0,0,0, b1 + kb*DMODEL, nullptr, 0, 1.0f);
      if (kb == 0)
        gemm_v6<true,true,false,1><<<dim3(DMODEL/128, ROWS/128, 1), 256, 0, stream>>>(
            tslab, W2T + (size_t)kb*DMODEL, out, DMODEL, DMODEL, DFF, DMODEL, 1,
            0,0,0,0,0,0, b2, x2f, DMODEL, 1.0f);
      else
        gemm_v6<false,false,false,2><<<dim3(DMODEL/128, ROWS/128, 1), 256, 0, stream>>>(
            tslab, W2T + (size_t)kb*DMODEL, out, DMODEL, DMODEL, DFF, DMODEL, 1,
            0,0,0,0,0,0, nullptr, nullptr, 0, 1.0f);
    }
  }
}

// Round 7
// 1047.145 us; speedup vs baseline: 1.2497x; 1.1171x over previous
//
#include <hip/hip_runtime.h>
#include <cstdint>
#include <cmath>

// v7: BK=64 GEMM (as v6). Plan A2 (>=262e6, fits 256MiB): full-batch folded plan
//     with per-batch T/S staging; softmax/Zt/out/reduce are single dispatches.
//     Plan B (>=112e6): batch-looped (identical to v6). Plan C / small below.

typedef __bf16 bf16_t;
typedef __bf16 bf16x8 __attribute__((ext_vector_type(8)));
typedef __bf16 bf16x4 __attribute__((ext_vector_type(4)));
typedef float floatx4 __attribute__((ext_vector_type(4)));

#define DMODEL 768
#define NHEAD  12
#define SEQ    1024
#define NBATCH 4
#define ROWS   (NBATCH*SEQ)   // 4096
#define DH     (DMODEL*NHEAD) // 9216
#define DFF    (4*DMODEL)     // 3072

// ---------------------------------------------------------------------------
// GEMM: C = alpha*(A @ B^T) [+bias[col]] [relu] [+res]   (fp32 bias/res/out)
// A: M x K (lda) bf16, BT: N x K (ldb) bf16, C: M x N (ldc). fp32 accum.
// OMODE: 0 = bf16 store, 1 = f32 store, 2 = f32 accumulate
// Batched via blockIdx.z: off = (z/bdiv)*hi + (z%bdiv)*lo  (element offsets)
// 128x128 tile, BK=64 (two frag-ordered 128x32 panels), 4 waves x (4x4) MFMA.
// Requires K % 64 == 0.
// ---------------------------------------------------------------------------
template<bool BIAS, bool RES, bool RELU, int OMODE>
__global__ __launch_bounds__(256)
void gemm_v7(const bf16_t* __restrict__ A, const bf16_t* __restrict__ BT,
             void* __restrict__ Cv, int K, int lda, int ldb, int ldc,
             int bdiv, long sa_hi, long sa_lo, long sb_hi, long sb_lo,
             long sc_hi, long sc_lo,
             const float* __restrict__ bias, const float* __restrict__ res,
             int ldres, float alpha)
{
  __shared__ __align__(16) bf16_t As[128*64];   // panel p at p*4096 elems
  __shared__ __align__(16) bf16_t Bs[128*64];

  const int tid  = threadIdx.x;
  const int wave = tid >> 6;
  const int lane = tid & 63;
  const int r    = lane & 15;   // row within 16-tile
  const int q    = lane >> 4;   // k-chunk (8 elems each)

  const int z = blockIdx.z;
  A  += (long)(z / bdiv) * sa_hi + (long)(z % bdiv) * sa_lo;
  BT += (long)(z / bdiv) * sb_hi + (long)(z % bdiv) * sb_lo;
  const long coff = (long)(z / bdiv) * sc_hi + (long)(z % bdiv) * sc_lo;

  const int bm = blockIdx.y * 128;
  const int bn = blockIdx.x * 128;
  const int wm = (wave & 1) * 64;
  const int wn = (wave >> 1) * 64;

  const int blk0 = 2*wave, blk1 = 2*wave + 1;
  const bf16_t* a_src0 = A  + (long)(bm + blk0*16 + r) * lda + q*8;
  const bf16_t* a_src1 = A  + (long)(bm + blk1*16 + r) * lda + q*8;
  const bf16_t* b_src0 = BT + (long)(bn + blk0*16 + r) * ldb + q*8;
  const bf16_t* b_src1 = BT + (long)(bn + blk1*16 + r) * ldb + q*8;
  const int da0 = blk0*512 + lane*8;
  const int da1 = blk1*512 + lane*8;

  const int am = (wave & 1) * 4;
  const int bb = (wave >> 1) * 4;

  floatx4 acc[4][4] = {};

  for (int k0 = 0; k0 < K; k0 += 64) {
    bf16x8 a00 = *(const bf16x8*)(a_src0 + k0);
    bf16x8 a01 = *(const bf16x8*)(a_src0 + k0 + 32);
    bf16x8 a10 = *(const bf16x8*)(a_src1 + k0);
    bf16x8 a11 = *(const bf16x8*)(a_src1 + k0 + 32);
    bf16x8 b00 = *(const bf16x8*)(b_src0 + k0);
    bf16x8 b01 = *(const bf16x8*)(b_src0 + k0 + 32);
    bf16x8 b10 = *(const bf16x8*)(b_src1 + k0);
    bf16x8 b11 = *(const bf16x8*)(b_src1 + k0 + 32);
    *(bf16x8*)(As + da0)        = a00;
    *(bf16x8*)(As + 4096 + da0) = a01;
    *(bf16x8*)(As + da1)        = a10;
    *(bf16x8*)(As + 4096 + da1) = a11;
    *(bf16x8*)(Bs + da0)        = b00;
    *(bf16x8*)(Bs + 4096 + da0) = b01;
    *(bf16x8*)(Bs + da1)        = b10;
    *(bf16x8*)(Bs + 4096 + da1) = b11;
    __syncthreads();
#pragma unroll
    for (int p = 0; p < 2; ++p) {
      bf16x8 afrag[4], bfrag[4];
#pragma unroll
      for (int t = 0; t < 4; ++t) {
        afrag[t] = *(const bf16x8*)(As + p*4096 + (am + t)*512 + lane*8);
        bfrag[t] = *(const bf16x8*)(Bs + p*4096 + (bb + t)*512 + lane*8);
      }
#pragma unroll
      for (int mt = 0; mt < 4; ++mt)
#pragma unroll
        for (int nt = 0; nt < 4; ++nt)
          acc[mt][nt] = __builtin_amdgcn_mfma_f32_16x16x32_bf16(
              afrag[mt], bfrag[nt], acc[mt][nt], 0, 0, 0);
    }
    __syncthreads();
  }

  // epilogue: C/D layout col=lane&15, row=(lane>>4)*4+e
  const int row0 = bm + wm + q*4;
  const int col0 = bn + wn + r;
#pragma unroll
  for (int nt = 0; nt < 4; ++nt) {
    const int col = col0 + nt*16;
    float bv = 0.f;
    if (BIAS) bv = bias[col];
#pragma unroll
    for (int mt = 0; mt < 4; ++mt) {
#pragma unroll
      for (int e = 0; e < 4; ++e) {
        const int rowi = row0 + mt*16 + e;
        float v = acc[mt][nt][e] * alpha;
        if (BIAS) v += bv;
        if (RELU) v = fmaxf(v, 0.f);
        if (RES)  v += res[(long)rowi * ldres + col];
        const long idx = coff + (long)rowi * ldc + col;
        if (OMODE == 0)      ((bf16_t*)Cv)[idx] = (bf16_t)v;
        else if (OMODE == 1) ((float*)Cv)[idx] = v;
        else                 ((float*)Cv)[idx] += v;
      }
    }
  }
}

// -------- 32x32 tiled transpose, fp32 in -> bf16 out --------
__global__ void tr_f2b_v7(const float* __restrict__ in, bf16_t* __restrict__ out,
                          int ldi, int ldo)
{
  __shared__ bf16_t tile[32][34];
  const int c0 = blockIdx.x * 32, r0 = blockIdx.y * 32;
  const int tx = threadIdx.x, ty = threadIdx.y;
#pragma unroll
  for (int i = 0; i < 4; ++i)
    tile[ty + 8*i][tx] = (bf16_t)in[(long)(r0 + ty + 8*i) * ldi + c0 + tx];
  __syncthreads();
#pragma unroll
  for (int i = 0; i < 4; ++i)
    out[(long)(c0 + ty + 8*i) * ldo + r0 + tx] = tile[tx][ty + 8*i];
}

// -------- batched 32x32 tiled transpose, bf16 -> bf16 (small plan) --------
__global__ void tr_b_v7(const bf16_t* __restrict__ in, bf16_t* __restrict__ out,
                        int ldi, int ldo, int bdiv,
                        long si_hi, long si_lo, long so_hi, long so_lo)
{
  __shared__ bf16_t tile[32][34];
  const int z = blockIdx.z;
  in  += (long)(z / bdiv) * si_hi + (long)(z % bdiv) * si_lo;
  out += (long)(z / bdiv) * so_hi + (long)(z % bdiv) * so_lo;
  const int c0 = blockIdx.x * 32, r0 = blockIdx.y * 32;
  const int tx = threadIdx.x, ty = threadIdx.y;
#pragma unroll
  for (int i = 0; i < 4; ++i)
    tile[ty + 8*i][tx] = in[(long)(r0 + ty + 8*i) * ldi + c0 + tx];
  __syncthreads();
#pragma unroll
  for (int i = 0; i < 4; ++i)
    out[(long)(c0 + ty + 8*i) * ldo + r0 + tx] = tile[tx][ty + 8*i];
}

// -------- per-head weight transposes (small plan) --------
__global__ void tr_wh_v7(const float* __restrict__ Wq, const float* __restrict__ Wk,
                         const float* __restrict__ Wv, const float* __restrict__ Wu,
                         bf16_t* __restrict__ WhT, bf16_t* __restrict__ WuTh, int h)
{
  __shared__ bf16_t tile[32][34];
  const int z = blockIdx.z;
  const float* in; bf16_t* out; int ldi;
  if (z < 3) {
    const float* W = (z == 0) ? Wq : (z == 1) ? Wk : Wv;
    in  = W + (long)h * DMODEL;
    ldi = DH;
    out = WhT + (long)z * DMODEL * DMODEL;
  } else {
    in  = Wu + (long)h * DMODEL * DMODEL;
    ldi = DMODEL;
    out = WuTh;
  }
  const int c0 = blockIdx.x * 32, r0 = blockIdx.y * 32;
  const int tx = threadIdx.x, ty = threadIdx.y;
#pragma unroll
  for (int i = 0; i < 4; ++i)
    tile[ty + 8*i][tx] = (bf16_t)in[(long)(r0 + ty + 8*i) * ldi + c0 + tx];
  __syncthreads();
#pragma unroll
  for (int i = 0; i < 4; ++i)
    out[(long)(c0 + ty + 8*i) * DMODEL + r0 + tx] = tile[tx][ty + 8*i];
}

// -------- cast-only fp32 -> bf16, 3 matrices of DMODEL*DH --------
__global__ void cast3_v7(const float* __restrict__ a, const float* __restrict__ b,
                         const float* __restrict__ c,
                         bf16_t* __restrict__ oa, bf16_t* __restrict__ ob,
                         bf16_t* __restrict__ oc)
{
  const float* src = (blockIdx.z == 0) ? a : (blockIdx.z == 1) ? b : c;
  bf16_t* dst      = (blockIdx.z == 0) ? oa : (blockIdx.z == 1) ? ob : oc;
  const long i = ((long)blockIdx.x * 256 + threadIdx.x) * 4;
  float4 v = *(const float4*)(src + i);
  bf16x4 o;
  o[0] = (bf16_t)v.x; o[1] = (bf16_t)v.y; o[2] = (bf16_t)v.z; o[3] = (bf16_t)v.w;
  *(bf16x4*)(dst + i) = o;
}

// -------- cast-only fp32 -> bf16, one DMODEL*DH matrix --------
__global__ void cast1_v7(const float* __restrict__ src, bf16_t* __restrict__ dst)
{
  const long i = ((long)blockIdx.x * 256 + threadIdx.x) * 4;
  float4 v = *(const float4*)(src + i);
  bf16x4 o;
  o[0] = (bf16_t)v.x; o[1] = (bf16_t)v.y; o[2] = (bf16_t)v.z; o[3] = (bf16_t)v.w;
  *(bf16x4*)(dst + i) = o;
}

// ---------------- LayerNorm over last dim (768): fp32 in -> bf16 out ----------------
__global__ void ln_v7(const float* __restrict__ x, const float* __restrict__ g,
                      const float* __restrict__ b, bf16_t* __restrict__ y)
{
  const long row = blockIdx.x;
  const int tid = threadIdx.x;
  const float* xr = x + row * DMODEL;
  float v0 = xr[tid], v1 = xr[tid + 256], v2 = xr[tid + 512];
  float s  = v0 + v1 + v2;
  float ss = v0*v0 + v1*v1 + v2*v2;
  for (int o = 32; o; o >>= 1) { s += __shfl_down(s, o); ss += __shfl_down(ss, o); }
  __shared__ float rs[4], rss[4];
  const int wave = tid >> 6, lane = tid & 63;
  if (lane == 0) { rs[wave] = s; rss[wave] = ss; }
  __syncthreads();
  s  = rs[0] + rs[1] + rs[2] + rs[3];
  ss = rss[0] + rss[1] + rss[2] + rss[3];
  const float inv = 1.0f / (float)DMODEL;
  const float mean = s * inv;
  const float var  = ss * inv - mean * mean;
  const float rstd = rsqrtf(var + 1e-5f);
  bf16_t* yr = y + row * DMODEL;
  yr[tid]       = (bf16_t)(((v0 - mean) * rstd) * g[tid]       + b[tid]);
  yr[tid + 256] = (bf16_t)(((v1 - mean) * rstd) * g[tid + 256] + b[tid + 256]);
  yr[tid + 512] = (bf16_t)(((v2 - mean) * rstd) * g[tid + 512] + b[tid + 512]);
}

// ---------------- softmax over rows of 1024, in place, bf16 ----------------
__global__ void softmax_v7(bf16_t* __restrict__ S)
{
  const long row = blockIdx.x;
  const int tid = threadIdx.x;
  bf16_t* p = S + row * SEQ + tid * 4;
  bf16x4 v = *(const bf16x4*)p;
  float f0 = (float)v[0], f1 = (float)v[1], f2 = (float)v[2], f3 = (float)v[3];
  float m = fmaxf(fmaxf(f0, f1), fmaxf(f2, f3));
  for (int o = 32; o; o >>= 1) m = fmaxf(m, __shfl_down(m, o));
  __shared__ float rm[4], rsum[4];
  const int wave = tid >> 6, lane = tid & 63;
  if (lane == 0) rm[wave] = m;
  __syncthreads();
  m = fmaxf(fmaxf(rm[0], rm[1]), fmaxf(rm[2], rm[3]));
  float e0 = __expf(f0 - m), e1 = __expf(f1 - m), e2 = __expf(f2 - m), e3 = __expf(f3 - m);
  float s = e0 + e1 + e2 + e3;
  for (int o = 32; o; o >>= 1) s += __shfl_down(s, o);
  if (lane == 0) rsum[wave] = s;
  __syncthreads();
  s = rsum[0] + rsum[1] + rsum[2] + rsum[3];
  const float invs = 1.0f / s;
  bf16x4 o4;
  o4[0] = (bf16_t)(e0 * invs); o4[1] = (bf16_t)(e1 * invs);
  o4[2] = (bf16_t)(e2 * invs); o4[3] = (bf16_t)(e3 * invs);
  *(bf16x4*)p = o4;
}

// ---------------- finalize: o = acc + bias[col] + add ----------------
__global__ void finalize_v7(const float* __restrict__ acc, const float* __restrict__ add,
                            const float* __restrict__ bias, float* __restrict__ o)
{
  const long i = (long)blockIdx.x * 256 + threadIdx.x;
  const int c = (int)(i % DMODEL);
  o[i] = acc[i] + bias[c] + add[i];
}

// ------- split-K reduce: o = sum_{n<NP} p[n*plane] + bias[col] + add (float4) -------
template<int NP>
__global__ void reduce_v7(const float* __restrict__ p, const float* __restrict__ add,
                          const float* __restrict__ bias, float* __restrict__ o,
                          long plane)
{
  const long i = ((long)blockIdx.x * 256 + threadIdx.x) * 4;
  float4 s = *(const float4*)(p + i);
#pragma unroll
  for (int n = 1; n < NP; ++n) {
    float4 v = *(const float4*)(p + i + (long)n * plane);
    s.x += v.x; s.y += v.y; s.z += v.z; s.w += v.w;
  }
  const int c = (int)(i % DMODEL);
  float4 bv = *(const float4*)(bias + c);
  float4 av = *(const float4*)(add + i);
  float4 r;
  r.x = s.x + bv.x + av.x; r.y = s.y + bv.y + av.y;
  r.z = s.z + bv.z + av.z; r.w = s.w + bv.w + av.w;
  *(float4*)(o + i) = r;
}

// ---------------------------------------------------------------------------
extern "C" void kernel_launch(void* const* d_in, const int* in_sizes, int n_in,
                              void* d_out, int out_size, void* d_ws, size_t ws_size,
                              hipStream_t stream)
{
  (void)in_sizes; (void)n_in; (void)out_size;
  const float* x    = (const float*)d_in[0];
  const float* Wq   = (const float*)d_in[1];
  const float* Wk   = (const float*)d_in[2];
  const float* Wv   = (const float*)d_in[3];
  const float* Wu   = (const float*)d_in[4];
  const float* bu   = (const float*)d_in[5];
  const float* ln1g = (const float*)d_in[6];
  const float* ln1b = (const float*)d_in[7];
  const float* ln2g = (const float*)d_in[8];
  const float* ln2b = (const float*)d_in[9];
  const float* W1   = (const float*)d_in[10];
  const float* b1   = (const float*)d_in[11];
  const float* W2   = (const float*)d_in[12];
  const float* b2   = (const float*)d_in[13];
  float* out = (float*)d_out;

  char* ws = (char*)d_ws;
  size_t off = 0;
  auto alloc = [&](size_t bytes) -> void* {
    void* p = (void*)(ws + off);
    off += (bytes + 255) & ~(size_t)255;
    return p;
  };

  const float qk_alpha = 1.0f / sqrtf((float)DMODEL);
  dim3 tb(32, 8);

  const size_t SZ_W   = (size_t)DMODEL * DH * 2;         // 14,155,776
  const size_t SZ_MT  = (size_t)NHEAD * DMODEL * DMODEL * 2;
  const size_t SZ_Y   = (size_t)ROWS * DMODEL * 2;       // 6,291,456
  const size_t SZ_X2  = (size_t)ROWS * DMODEL * 4;       // 12,582,912

  if (ws_size >= (size_t)262e6) {
    // ===== PLAN A2: full-batch folded, ~261.2 MB (fits a 256 MiB workspace) =====
    // Per-batch T staging (T_b aliased into split-K part region, lifetimes disjoint);
    // softmax / Zt / out-gemm / reduce / MLP are full-batch single dispatches.
    bf16_t* MT   = (bf16_t*)alloc(SZ_MT);                       // 14.2 MB
    bf16_t* PhT  = (bf16_t*)alloc(SZ_MT);                       // 14.2 MB
    bf16_t* y    = (bf16_t*)alloc(SZ_Y);                        //  6.3 MB
    float*  x2f  = (float* )alloc(SZ_X2);                       // 12.6 MB
    float*  part = (float* )alloc((size_t)3 * ROWS * DMODEL * 4); // 37.7 MB (kc=3)
    bf16_t* S    = (bf16_t*)alloc((size_t)NBATCH * SEQ * NHEAD * SEQ * 2);    // 100.7 MB
    bf16_t* Zt   = (bf16_t*)alloc((size_t)NBATCH * DMODEL * NHEAD * SEQ * 2); // 75.5 MB
    // aliases (lifetime-disjoint):
    bf16_t* T_b  = (bf16_t*)part;                  // 18.9 MB, dead before out-gemm
    bf16_t* Wqb  = (bf16_t*)S;                     // weight staging in S (dead early)
    bf16_t* Wkb  = (bf16_t*)((char*)S + SZ_W);
    bf16_t* Wvb  = (bf16_t*)((char*)S + 2*SZ_W);
    bf16_t* WuT  = (bf16_t*)((char*)S + 3*SZ_W);
    bf16_t* W1T  = (bf16_t*)S;                     // MLP phase (S dead after out-gemm)
    bf16_t* W2T  = (bf16_t*)((char*)S + 4718592);
    bf16_t* t    = (bf16_t*)((char*)S + 9437184);  // 25.2 MB
    float*  partM= (float* )((char*)S + 34603008); // 4 x 12.58 MB
    bf16_t* y2   = (bf16_t*)Zt;                    // Zt dead after out-gemm

    // ---- weight folds ----
    cast3_v7<<<dim3(6912, 1, 3), 256, 0, stream>>>(Wq, Wk, Wv, Wqb, Wkb, Wvb);
    tr_f2b_v7<<<dim3(DMODEL/32, DH/32), tb, 0, stream>>>(Wu, WuT, DMODEL, DH);
    gemm_v7<false,false,false,0><<<dim3(6, 6, NHEAD), 256, 0, stream>>>(
        Wkb, Wqb, MT, DMODEL, DH, DH, DMODEL, NHEAD,
        0, DMODEL, 0, DMODEL, 0, (long)DMODEL*DMODEL, nullptr, nullptr, 0, 1.0f);
    gemm_v7<false,false,false,0><<<dim3(6, 6, NHEAD), 256, 0, stream>>>(
        WuT, Wvb, PhT, DMODEL, DH, DH, DMODEL, NHEAD,
        0, DMODEL, 0, DMODEL, 0, (long)DMODEL*DMODEL, nullptr, nullptr, 0, 1.0f);

    // ---- attention ----
    ln_v7<<<ROWS, 256, 0, stream>>>(x, ln1g, ln1b, y);
    // per-batch: T_b = y_b @ M_h ; S[b] = T_bh @ y_b^T (T_b buffer reused)
    for (int b = 0; b < NBATCH; ++b) {
      const bf16_t* yb = y + (long)b * SEQ * DMODEL;
      gemm_v7<false,false,false,0><<<dim3(6, 8, NHEAD), 256, 0, stream>>>(
          yb, MT, T_b, DMODEL, DMODEL, DMODEL, DMODEL, NHEAD,
          0, 0, 0, (long)DMODEL*DMODEL, 0, (long)SEQ*DMODEL,
          nullptr, nullptr, 0, 1.0f);
      gemm_v7<false,false,false,0><<<dim3(8, 8, NHEAD), 256, 0, stream>>>(
          T_b, yb, S + (long)b*SEQ*NHEAD*SEQ, DMODEL, DMODEL, DMODEL, NHEAD*SEQ, NHEAD,
          0, (long)SEQ*DMODEL, 0, 0, 0, (long)SEQ,
          nullptr, nullptr, 0, qk_alpha);
    }
    softmax_v7<<<NBATCH*SEQ*NHEAD, 256, 0, stream>>>(S);
    // Zt[b][d][h*1024+j] = PhT_h @ y_b^T   (z = b*NHEAD + h)
    gemm_v7<false,false,false,0><<<dim3(8, 6, NBATCH*NHEAD), 256, 0, stream>>>(
        PhT, y, Zt, DMODEL, DMODEL, DMODEL, NHEAD*SEQ, NHEAD,
        0, (long)DMODEL*DMODEL, (long)SEQ*DMODEL, 0,
        (long)DMODEL*NHEAD*SEQ, (long)SEQ, nullptr, nullptr, 0, 1.0f);
    // out_b = S_b(1024x12288) @ Zt_b^T, split-K 3: z = kc*NBATCH + b
    gemm_v7<false,false,false,1><<<dim3(6, 8, 12), 256, 0, stream>>>(
        S, Zt, part, NHEAD*SEQ/3, NHEAD*SEQ, NHEAD*SEQ, DMODEL, NBATCH,
        (long)(NHEAD*SEQ/3), (long)SEQ*NHEAD*SEQ,
        (long)(NHEAD*SEQ/3), (long)DMODEL*NHEAD*SEQ,
        (long)ROWS*DMODEL, (long)SEQ*DMODEL, nullptr, nullptr, 0, 1.0f);
    reduce_v7<3><<<(ROWS*DMODEL)/1024, 256, 0, stream>>>(
        part, x, bu, x2f, (long)ROWS*DMODEL);

    // ---- MLP ----
    tr_f2b_v7<<<dim3(DFF/32, DMODEL/32), tb, 0, stream>>>(W1, W1T, DFF, DMODEL);
    tr_f2b_v7<<<dim3(DMODEL/32, DFF/32), tb, 0, stream>>>(W2, W2T, DMODEL, DFF);
    ln_v7<<<ROWS, 256, 0, stream>>>(x2f, ln2g, ln2b, y2);
    gemm_v7<true,false,true,0><<<dim3(DFF/128, ROWS/128, 1), 256, 0, stream>>>(
        y2, W1T, t, DMODEL, DMODEL, DMODEL, DFF, 1, 0,0,0,0,0,0, b1, nullptr, 0, 1.0f);
    // MLP2 split-K 4: z = kc (bdiv=4 -> lo strides select the K-slice)
    gemm_v7<false,false,false,1><<<dim3(6, ROWS/128, 4), 256, 0, stream>>>(
        t, W2T, partM, DFF/4, DFF, DFF, DMODEL, 4,
        0, (long)(DFF/4), 0, (long)(DFF/4), 0, (long)ROWS*DMODEL,
        nullptr, nullptr, 0, 1.0f);
    reduce_v7<4><<<(ROWS*DMODEL)/1024, 256, 0, stream>>>(
        partM, x2f, b2, out, (long)ROWS*DMODEL);
  } else if (ws_size >= (size_t)112e6) {
    // ===== PLAN B: batch-looped folded (~110.1 MB, identical to v6) =====
    bf16_t* MT  = (bf16_t*)alloc(SZ_MT);
    bf16_t* PhT = (bf16_t*)alloc(SZ_MT);
    bf16_t* y   = (bf16_t*)alloc(SZ_Y);
    float*  x2f = (float* )alloc(SZ_X2);
    char*   BIG = (char*  )alloc((size_t)62914560);
    bf16_t* T_b  = (bf16_t*)(BIG);                 // 18,874,368
    bf16_t* S_b  = (bf16_t*)(BIG + 18874368);      // 25,165,824
    bf16_t* Zt_b = (bf16_t*)(BIG + 44040192);      // 18,874,368
    float*  part = (float* )(BIG);                 // 6 x 3,145,728
    bf16_t* Wqb = (bf16_t*)(BIG);
    bf16_t* Wkb = (bf16_t*)(BIG + SZ_W);
    bf16_t* Wvb = (bf16_t*)(BIG + 2*SZ_W);
    bf16_t* WuT = (bf16_t*)(BIG + 3*SZ_W);
    bf16_t* W1T   = (bf16_t*)(BIG);
    bf16_t* W2T   = (bf16_t*)(BIG + 4718592);
    bf16_t* t     = (bf16_t*)(BIG + 9437184);
    float*  partM = (float* )(BIG + 34603008);
    bf16_t* y2    = y;

    cast3_v7<<<dim3(6912, 1, 3), 256, 0, stream>>>(Wq, Wk, Wv, Wqb, Wkb, Wvb);
    tr_f2b_v7<<<dim3(DMODEL/32, DH/32), tb, 0, stream>>>(Wu, WuT, DMODEL, DH);
    gemm_v7<false,false,false,0><<<dim3(6, 6, NHEAD), 256, 0, stream>>>(
        Wkb, Wqb, MT, DMODEL, DH, DH, DMODEL, NHEAD,
        0, DMODEL, 0, DMODEL, 0, (long)DMODEL*DMODEL, nullptr, nullptr, 0, 1.0f);
    gemm_v7<false,false,false,0><<<dim3(6, 6, NHEAD), 256, 0, stream>>>(
        WuT, Wvb, PhT, DMODEL, DH, DH, DMODEL, NHEAD,
        0, DMODEL, 0, DMODEL, 0, (long)DMODEL*DMODEL, nullptr, nullptr, 0, 1.0f);

    ln_v7<<<ROWS, 256, 0, stream>>>(x, ln1g, ln1b, y);
    for (int b = 0; b < NBATCH; ++b) {
      const bf16_t* yb = y + (long)b * SEQ * DMODEL;
      gemm_v7<false,false,false,0><<<dim3(6, 8, NHEAD), 256, 0, stream>>>(
          yb, MT, T_b, DMODEL, DMODEL, DMODEL, DMODEL, NHEAD,
          0, 0, 0, (long)DMODEL*DMODEL, 0, (long)SEQ*DMODEL,
          nullptr, nullptr, 0, 1.0f);
      gemm_v7<false,false,false,0><<<dim3(8, 8, NHEAD), 256, 0, stream>>>(
          T_b, yb, S_b, DMODEL, DMODEL, DMODEL, NHEAD*SEQ, NHEAD,
          0, (long)SEQ*DMODEL, 0, 0, 0, (long)SEQ,
          nullptr, nullptr, 0, qk_alpha);
      softmax_v7<<<NHEAD*SEQ, 256, 0, stream>>>(S_b);
      gemm_v7<false,false,false,0><<<dim3(8, 6, NHEAD), 256, 0, stream>>>(
          PhT, yb, Zt_b, DMODEL, DMODEL, DMODEL, NHEAD*SEQ, NHEAD,
          0, (long)DMODEL*DMODEL, 0, 0, 0, (long)SEQ,
          nullptr, nullptr, 0, 1.0f);
      gemm_v7<false,false,false,1><<<dim3(6, 8, 6), 256, 0, stream>>>(
          S_b, Zt_b, part, NHEAD*SEQ/6, NHEAD*SEQ, NHEAD*SEQ, DMODEL, 6,
          0, (long)(NHEAD*SEQ/6), 0, (long)(NHEAD*SEQ/6), 0, (long)SEQ*DMODEL,
          nullptr, nullptr, 0, 1.0f);
      reduce_v7<6><<<(SEQ*DMODEL)/1024, 256, 0, stream>>>(
          part, x + (long)b*SEQ*DMODEL, bu, x2f + (long)b*SEQ*DMODEL,
          (long)SEQ*DMODEL);
    }

    tr_f2b_v7<<<dim3(DFF/32, DMODEL/32), tb, 0, stream>>>(W1, W1T, DFF, DMODEL);
    tr_f2b_v7<<<dim3(DMODEL/32, DFF/32), tb, 0, stream>>>(W2, W2T, DMODEL, DFF);
    ln_v7<<<ROWS, 256, 0, stream>>>(x2f, ln2g, ln2b, y2);
    gemm_v7<true,false,true,0><<<dim3(DFF/128, ROWS/128, 1), 256, 0, stream>>>(
        y2, W1T, t, DMODEL, DMODEL, DMODEL, DFF, 1, 0,0,0,0,0,0, b1, nullptr, 0, 1.0f);
    gemm_v7<false,false,false,1><<<dim3(6, ROWS/128, 2), 256, 0, stream>>>(
        t, W2T, partM, DFF/2, DFF, DFF, DMODEL, 2,
        0, (long)(DFF/2), 0, (long)(DFF/2), 0, (long)ROWS*DMODEL,
        nullptr, nullptr, 0, 1.0f);
    reduce_v7<2><<<(ROWS*DMODEL)/1024, 256, 0, stream>>>(
        partM, x2f, b2, out, (long)ROWS*DMODEL);
  } else if (ws_size >= (size_t)70e6) {
    // ===== PLAN C: head-looped folded (~68.2 MB) =====
    bf16_t* MT  = (bf16_t*)alloc(SZ_MT);
    bf16_t* PhT = (bf16_t*)alloc(SZ_MT);
    bf16_t* y   = (bf16_t*)alloc(SZ_Y);
    char*   R   = (char*  )alloc((size_t)33554432);
    bf16_t* WAb = (bf16_t*)(R);
    bf16_t* WBb = (bf16_t*)(R + SZ_W);
    float*  x2f = (float* )(R);
    bf16_t* T_h = (bf16_t*)(R + 12582912);
    bf16_t* S_h = (bf16_t*)(R + 18874368);
    bf16_t* Z_h = (bf16_t*)(R + 27262976);
    bf16_t* W1T = (bf16_t*)(R + 12582912);
    bf16_t* W2T = (bf16_t*)(R + 17301504);
    bf16_t* t   = (bf16_t*)MT;
    bf16_t* y2  = y;

    cast1_v7<<<6912, 256, 0, stream>>>(Wq, WAb);
    cast1_v7<<<6912, 256, 0, stream>>>(Wk, WBb);
    gemm_v7<false,false,false,0><<<dim3(6, 6, NHEAD), 256, 0, stream>>>(
        WBb, WAb, MT, DMODEL, DH, DH, DMODEL, NHEAD,
        0, DMODEL, 0, DMODEL, 0, (long)DMODEL*DMODEL, nullptr, nullptr, 0, 1.0f);
    cast1_v7<<<6912, 256, 0, stream>>>(Wv, WAb);
    tr_f2b_v7<<<dim3(DMODEL/32, DH/32), tb, 0, stream>>>(Wu, WBb, DMODEL, DH);
    gemm_v7<false,false,false,0><<<dim3(6, 6, NHEAD), 256, 0, stream>>>(
        WBb, WAb, PhT, DMODEL, DH, DH, DMODEL, NHEAD,
        0, DMODEL, 0, DMODEL, 0, (long)DMODEL*DMODEL, nullptr, nullptr, 0, 1.0f);

    ln_v7<<<ROWS, 256, 0, stream>>>(x, ln1g, ln1b, y);
    for (int h = 0; h < NHEAD; ++h) {
      const bf16_t* MTh  = MT  + (long)h * DMODEL * DMODEL;
      const bf16_t* PhTh = PhT + (long)h * DMODEL * DMODEL;
      gemm_v7<false,false,false,0><<<dim3(6, ROWS/128, 1), 256, 0, stream>>>(
          y, MTh, T_h, DMODEL, DMODEL, DMODEL, DMODEL, 1,
          0,0,0,0,0,0, nullptr, nullptr, 0, 1.0f);
      gemm_v7<false,false,false,0><<<dim3(8, 8, NBATCH), 256, 0, stream>>>(
          T_h, y, S_h, DMODEL, DMODEL, DMODEL, SEQ, NBATCH,
          0, (long)SEQ*DMODEL, 0, (long)SEQ*DMODEL, 0, (long)SEQ*SEQ,
          nullptr, nullptr, 0, qk_alpha);
      softmax_v7<<<ROWS, 256, 0, stream>>>(S_h);
      gemm_v7<false,false,false,0><<<dim3(8, 6, NBATCH), 256, 0, stream>>>(
          PhTh, y, Z_h, DMODEL, DMODEL, DMODEL, SEQ, NBATCH,
          0, 0, 0, (long)SEQ*DMODEL, 0, (long)DMODEL*SEQ,
          nullptr, nullptr, 0, 1.0f);
      if (h == 0)
        gemm_v7<false,false,false,1><<<dim3(6, 8, NBATCH), 256, 0, stream>>>(
            S_h, Z_h, x2f, SEQ, SEQ, SEQ, DMODEL, NBATCH,
            0, (long)SEQ*SEQ, 0, (long)DMODEL*SEQ, 0, (long)SEQ*DMODEL,
            nullptr, nullptr, 0, 1.0f);
      else
        gemm_v7<false,false,false,2><<<dim3(6, 8, NBATCH), 256, 0, stream>>>(
            S_h, Z_h, x2f, SEQ, SEQ, SEQ, DMODEL, NBATCH,
            0, (long)SEQ*SEQ, 0, (long)DMODEL*SEQ, 0, (long)SEQ*DMODEL,
            nullptr, nullptr, 0, 1.0f);
    }
    finalize_v7<<<(ROWS*DMODEL)/256, 256, 0, stream>>>(x2f, x, bu, x2f);

    tr_f2b_v7<<<dim3(DFF/32, DMODEL/32), tb, 0, stream>>>(W1, W1T, DFF, DMODEL);
    tr_f2b_v7<<<dim3(DMODEL/32, DFF/32), tb, 0, stream>>>(W2, W2T, DMODEL, DFF);
    ln_v7<<<ROWS, 256, 0, stream>>>(x2f, ln2g, ln2b, y2);
    gemm_v7<true,false,true,0><<<dim3(DFF/128, ROWS/128, 1), 256, 0, stream>>>(
        y2, W1T, t, DMODEL, DMODEL, DMODEL, DFF, 1, 0,0,0,0,0,0, b1, nullptr, 0, 1.0f);
    gemm_v7<true,true,false,1><<<dim3(6, ROWS/128, 1), 256, 0, stream>>>(
        t, W2T, out, DFF/2, DFF, DFF, DMODEL, 1, 0,0,0,0,0,0,
        b2, x2f, DMODEL, 1.0f);
    gemm_v7<false,false,false,2><<<dim3(6, ROWS/128, 1), 256, 0, stream>>>(
        t + DFF/2, W2T + DFF/2, out, DFF/2, DFF, DFF, DMODEL, 1, 0,0,0,0,0,0,
        nullptr, nullptr, 0, 1.0f);
  } else {
    // ===== legacy SMALL PLAN (~43 MB) =====
    bf16_t* W1T   = (bf16_t*)alloc((size_t)DMODEL * DFF * 2);
    bf16_t* W2T   = (bf16_t*)alloc((size_t)DMODEL * DFF * 2);
    bf16_t* y     = (bf16_t*)alloc(SZ_Y);
    float*  x2f   = (float* )alloc(SZ_X2);
    char*   reg1  = (char*)alloc((size_t)3*DMODEL*DMODEL*2 + (size_t)DMODEL*DMODEL*2 + (size_t)SEQ*DMODEL*2);
    bf16_t* WhT   = (bf16_t*)reg1;
    bf16_t* WuTh  = (bf16_t*)(reg1 + (size_t)3*DMODEL*DMODEL*2);
    bf16_t* attb  = (bf16_t*)(reg1 + (size_t)4*DMODEL*DMODEL*2);
    bf16_t* y2    = (bf16_t*)reg1;
    char*   reg2  = (char*)alloc((size_t)SEQ*3*DMODEL*2 + (size_t)DMODEL*SEQ*2 + (size_t)SEQ*SEQ*2);
    bf16_t* QKVb  = (bf16_t*)reg2;
    bf16_t* Vtb   = (bf16_t*)(reg2 + (size_t)SEQ*3*DMODEL*2);
    bf16_t* Sb    = (bf16_t*)(reg2 + (size_t)SEQ*3*DMODEL*2 + (size_t)DMODEL*SEQ*2);
    bf16_t* tslab = (bf16_t*)reg2;

    tr_f2b_v7<<<dim3(DFF/32, DMODEL/32), tb, 0, stream>>>(W1, W1T, DFF, DMODEL);
    tr_f2b_v7<<<dim3(DMODEL/32, DFF/32), tb, 0, stream>>>(W2, W2T, DMODEL, DFF);
    ln_v7<<<ROWS, 256, 0, stream>>>(x, ln1g, ln1b, y);

    const int N3 = 3 * DMODEL;
    for (int h = 0; h < NHEAD; ++h) {
      tr_wh_v7<<<dim3(24, 24, 4), tb, 0, stream>>>(Wq, Wk, Wv, Wu, WhT, WuTh, h);
      for (int b = 0; b < NBATCH; ++b) {
        const bf16_t* yb = y + (size_t)b * SEQ * DMODEL;
        gemm_v7<false,false,false,0><<<dim3(N3/128, SEQ/128, 1), 256, 0, stream>>>(
            yb, WhT, QKVb, DMODEL, DMODEL, DMODEL, N3, 1, 0,0,0,0,0,0,
            nullptr, nullptr, 0, 1.0f);
        tr_b_v7<<<dim3(DMODEL/32, SEQ/32, 1), tb, 0, stream>>>(
            QKVb + 2*DMODEL, Vtb, N3, SEQ, 1, 0,0,0,0);
        gemm_v7<false,false,false,0><<<dim3(SEQ/128, SEQ/128, 1), 256, 0, stream>>>(
            QKVb, QKVb + DMODEL, Sb, DMODEL, N3, N3, SEQ, 1, 0,0,0,0,0,0,
            nullptr, nullptr, 0, qk_alpha);
        softmax_v7<<<SEQ, 256, 0, stream>>>(Sb);
        gemm_v7<false,false,false,0><<<dim3(DMODEL/128, SEQ/128, 1), 256, 0, stream>>>(
            Sb, Vtb, attb, SEQ, SEQ, SEQ, DMODEL, 1, 0,0,0,0,0,0,
            nullptr, nullptr, 0, 1.0f);
        float* x2b = x2f + (size_t)b * SEQ * DMODEL;
        if (h == 0)
          gemm_v7<false,false,false,1><<<dim3(DMODEL/128, SEQ/128, 1), 256, 0, stream>>>(
              attb, WuTh, x2b, DMODEL, DMODEL, DMODEL, DMODEL, 1, 0,0,0,0,0,0,
              nullptr, nullptr, 0, 1.0f);
        else
          gemm_v7<false,false,false,2><<<dim3(DMODEL/128, SEQ/128, 1), 256, 0, stream>>>(
              attb, WuTh, x2b, DMODEL, DMODEL, DMODEL, DMODEL, 1, 0,0,0,0,0,0,
              nullptr, nullptr, 0, 1.0f);
      }
    }
    finalize_v7<<<(ROWS*DMODEL)/256, 256, 0, stream>>>(x2f, x, bu, x2f);
    ln_v7<<<ROWS, 256, 0, stream>>>(x2f, ln2g, ln2b, y2);
    for (int kb = 0; kb < 4; ++kb) {
      gemm_v7<true,false,true,0><<<dim3(DMODEL/128, ROWS/128, 1), 256, 0, stream>>>(
          y2, W1T + (size_t)kb*DMODEL*DMODEL, tslab, DMODEL, DMODEL, DMODEL, DMODEL, 1,
          0,0,0,0,0,0, b1 + kb*DMODEL, nullptr, 0, 1.0f);
      if (kb == 0)
        gemm_v7<true,true,false,1><<<dim3(DMODEL/128, ROWS/128, 1), 256, 0, stream>>>(
            tslab, W2T + (size_t)kb*DMODEL, out, DMODEL, DMODEL, DFF, DMODEL, 1,
            0,0,0,0,0,0, b2, x2f, DMODEL, 1.0f);
      else
        gemm_v7<false,false,false,2><<<dim3(DMODEL/128, ROWS/128, 1), 256, 0, stream>>>(
            tslab, W2T + (size_t)kb*DMODEL, out, DMODEL, DMODEL, DFF, DMODEL, 1,
            0,0,0,0,0,0, nullptr, nullptr, 0, 1.0f);
    }
  }
}

// Round 8
// 994.263 us; speedup vs baseline: 1.3162x; 1.0532x over previous
//
#include <hip/hip_runtime.h>
#include <cstdint>
#include <cmath>

// v8: gemm uses (1) async global_load_lds width-16 staging (no register round-trip),
//     (2) XCD-aware bijective block swizzle (m204). Plan A2' adds 2-batch T/scores
//     grouping. Thresholds unchanged: A2'>=262e6, B>=112e6, C>=70e6.

typedef __bf16 bf16_t;
typedef __bf16 bf16x8 __attribute__((ext_vector_type(8)));
typedef __bf16 bf16x4 __attribute__((ext_vector_type(4)));
typedef float floatx4 __attribute__((ext_vector_type(4)));

#define DMODEL 768
#define NHEAD  12
#define SEQ    1024
#define NBATCH 4
#define ROWS   (NBATCH*SEQ)   // 4096
#define DH     (DMODEL*NHEAD) // 9216
#define DFF    (4*DMODEL)     // 3072

// ---- async 16B global->LDS (gfx950). LDS dest = wave-uniform base + lane*16B. ----
__device__ __forceinline__ void gload16(const bf16_t* g, bf16_t* l)
{
  __builtin_amdgcn_global_load_lds(
      (const __attribute__((address_space(1))) void*)g,
      (__attribute__((address_space(3))) void*)l,
      16, 0, 0);
}

// ---------------------------------------------------------------------------
// GEMM: C = alpha*(A @ B^T) [+bias[col]] [relu] [+res]   (fp32 bias/res/out)
// A: M x K (lda) bf16, BT: N x K (ldb) bf16, C: M x N (ldc). fp32 accum.
// OMODE: 0 = bf16 store, 1 = f32 store, 2 = f32 accumulate
// Batched via z: off = (z/bdiv)*hi + (z%bdiv)*lo (element offsets)
// 128x128 tile, BK=64 (two frag-ordered 128x32 panels), 4 waves x (4x4) MFMA.
// global_load_lds staging: per wave, lane i deposits 16B at panel_base+i*16,
// reading per-lane global addr (row bm+blk*16+(lane&15), col (lane>>4)*8).
// XCD swizzle: consecutive flattened block ids (panel sharers) -> same XCD.
// Requires K % 64 == 0.
// ---------------------------------------------------------------------------
template<bool BIAS, bool RES, bool RELU, int OMODE>
__global__ __launch_bounds__(256)
void gemm_v8(const bf16_t* __restrict__ A, const bf16_t* __restrict__ BT,
             void* __restrict__ Cv, int K, int lda, int ldb, int ldc,
             int bdiv, long sa_hi, long sa_lo, long sb_hi, long sb_lo,
             long sc_hi, long sc_lo,
             const float* __restrict__ bias, const float* __restrict__ res,
             int ldres, float alpha)
{
  __shared__ __align__(16) bf16_t As[128*64];   // panel p at p*4096 elems
  __shared__ __align__(16) bf16_t Bs[128*64];

  // ---- XCD-aware bijective swizzle (m204): chunk consecutive ids per XCD ----
  const long nwg  = (long)gridDim.x * gridDim.y * gridDim.z;
  const long orig = blockIdx.x + (long)gridDim.x * (blockIdx.y + (long)gridDim.y * blockIdx.z);
  const long q8 = nwg >> 3, r8 = nwg & 7;
  const long xcd = orig & 7, loc = orig >> 3;
  const long swz = (xcd < r8 ? xcd*(q8+1) : r8*(q8+1) + (xcd - r8)*q8) + loc;
  const int  bix = (int)(swz % (long)gridDim.x);
  const long rem = swz / (long)gridDim.x;
  const int  biy = (int)(rem % (long)gridDim.y);
  const int  biz = (int)(rem / (long)gridDim.y);

  const int tid  = threadIdx.x;
  const int wave = tid >> 6;
  const int lane = tid & 63;
  const int r    = lane & 15;   // row within 16-tile
  const int q    = lane >> 4;   // k-chunk (8 elems each)

  A  += (long)(biz / bdiv) * sa_hi + (long)(biz % bdiv) * sa_lo;
  BT += (long)(biz / bdiv) * sb_hi + (long)(biz % bdiv) * sb_lo;
  const long coff = (long)(biz / bdiv) * sc_hi + (long)(biz % bdiv) * sc_lo;

  const int bm = biy * 128;
  const int bn = bix * 128;
  const int wm = (wave & 1) * 64;
  const int wn = (wave >> 1) * 64;

  const int blk0 = 2*wave, blk1 = 2*wave + 1;
  const bf16_t* a_src0 = A  + (long)(bm + blk0*16 + r) * lda + q*8;
  const bf16_t* a_src1 = A  + (long)(bm + blk1*16 + r) * lda + q*8;
  const bf16_t* b_src0 = BT + (long)(bn + blk0*16 + r) * ldb + q*8;
  const bf16_t* b_src1 = BT + (long)(bn + blk1*16 + r) * ldb + q*8;
  bf16_t* a_dst0 = As + blk0*512;   // wave-uniform bases; HW adds lane*16B
  bf16_t* a_dst1 = As + blk1*512;
  bf16_t* b_dst0 = Bs + blk0*512;
  bf16_t* b_dst1 = Bs + blk1*512;

  const int am = (wave & 1) * 4;
  const int bb = (wave >> 1) * 4;

  floatx4 acc[4][4] = {};

  for (int k0 = 0; k0 < K; k0 += 64) {
    gload16(a_src0 + k0,      a_dst0);
    gload16(a_src1 + k0,      a_dst1);
    gload16(b_src0 + k0,      b_dst0);
    gload16(b_src1 + k0,      b_dst1);
    gload16(a_src0 + k0 + 32, a_dst0 + 4096);
    gload16(a_src1 + k0 + 32, a_dst1 + 4096);
    gload16(b_src0 + k0 + 32, b_dst0 + 4096);
    gload16(b_src1 + k0 + 32, b_dst1 + 4096);
    __syncthreads();
#pragma unroll
    for (int p = 0; p < 2; ++p) {
      bf16x8 afrag[4], bfrag[4];
#pragma unroll
      for (int t = 0; t < 4; ++t) {
        afrag[t] = *(const bf16x8*)(As + p*4096 + (am + t)*512 + lane*8);
        bfrag[t] = *(const bf16x8*)(Bs + p*4096 + (bb + t)*512 + lane*8);
      }
#pragma unroll
      for (int mt = 0; mt < 4; ++mt)
#pragma unroll
        for (int nt = 0; nt < 4; ++nt)
          acc[mt][nt] = __builtin_amdgcn_mfma_f32_16x16x32_bf16(
              afrag[mt], bfrag[nt], acc[mt][nt], 0, 0, 0);
    }
    __syncthreads();
  }

  // epilogue: C/D layout col=lane&15, row=(lane>>4)*4+e
  const int row0 = bm + wm + q*4;
  const int col0 = bn + wn + r;
#pragma unroll
  for (int nt = 0; nt < 4; ++nt) {
    const int col = col0 + nt*16;
    float bv = 0.f;
    if (BIAS) bv = bias[col];
#pragma unroll
    for (int mt = 0; mt < 4; ++mt) {
#pragma unroll
      for (int e = 0; e < 4; ++e) {
        const int rowi = row0 + mt*16 + e;
        float v = acc[mt][nt][e] * alpha;
        if (BIAS) v += bv;
        if (RELU) v = fmaxf(v, 0.f);
        if (RES)  v += res[(long)rowi * ldres + col];
        const long idx = coff + (long)rowi * ldc + col;
        if (OMODE == 0)      ((bf16_t*)Cv)[idx] = (bf16_t)v;
        else if (OMODE == 1) ((float*)Cv)[idx] = v;
        else                 ((float*)Cv)[idx] += v;
      }
    }
  }
}

// -------- 32x32 tiled transpose, fp32 in -> bf16 out --------
__global__ void tr_f2b_v8(const float* __restrict__ in, bf16_t* __restrict__ out,
                          int ldi, int ldo)
{
  __shared__ bf16_t tile[32][34];
  const int c0 = blockIdx.x * 32, r0 = blockIdx.y * 32;
  const int tx = threadIdx.x, ty = threadIdx.y;
#pragma unroll
  for (int i = 0; i < 4; ++i)
    tile[ty + 8*i][tx] = (bf16_t)in[(long)(r0 + ty + 8*i) * ldi + c0 + tx];
  __syncthreads();
#pragma unroll
  for (int i = 0; i < 4; ++i)
    out[(long)(c0 + ty + 8*i) * ldo + r0 + tx] = tile[tx][ty + 8*i];
}

// -------- batched 32x32 tiled transpose, bf16 -> bf16 (small plan) --------
__global__ void tr_b_v8(const bf16_t* __restrict__ in, bf16_t* __restrict__ out,
                        int ldi, int ldo, int bdiv,
                        long si_hi, long si_lo, long so_hi, long so_lo)
{
  __shared__ bf16_t tile[32][34];
  const int z = blockIdx.z;
  in  += (long)(z / bdiv) * si_hi + (long)(z % bdiv) * si_lo;
  out += (long)(z / bdiv) * so_hi + (long)(z % bdiv) * so_lo;
  const int c0 = blockIdx.x * 32, r0 = blockIdx.y * 32;
  const int tx = threadIdx.x, ty = threadIdx.y;
#pragma unroll
  for (int i = 0; i < 4; ++i)
    tile[ty + 8*i][tx] = in[(long)(r0 + ty + 8*i) * ldi + c0 + tx];
  __syncthreads();
#pragma unroll
  for (int i = 0; i < 4; ++i)
    out[(long)(c0 + ty + 8*i) * ldo + r0 + tx] = tile[tx][ty + 8*i];
}

// -------- per-head weight transposes (small plan) --------
__global__ void tr_wh_v8(const float* __restrict__ Wq, const float* __restrict__ Wk,
                         const float* __restrict__ Wv, const float* __restrict__ Wu,
                         bf16_t* __restrict__ WhT, bf16_t* __restrict__ WuTh, int h)
{
  __shared__ bf16_t tile[32][34];
  const int z = blockIdx.z;
  const float* in; bf16_t* out; int ldi;
  if (z < 3) {
    const float* W = (z == 0) ? Wq : (z == 1) ? Wk : Wv;
    in  = W + (long)h * DMODEL;
    ldi = DH;
    out = WhT + (long)z * DMODEL * DMODEL;
  } else {
    in  = Wu + (long)h * DMODEL * DMODEL;
    ldi = DMODEL;
    out = WuTh;
  }
  const int c0 = blockIdx.x * 32, r0 = blockIdx.y * 32;
  const int tx = threadIdx.x, ty = threadIdx.y;
#pragma unroll
  for (int i = 0; i < 4; ++i)
    tile[ty + 8*i][tx] = (bf16_t)in[(long)(r0 + ty + 8*i) * ldi + c0 + tx];
  __syncthreads();
#pragma unroll
  for (int i = 0; i < 4; ++i)
    out[(long)(c0 + ty + 8*i) * DMODEL + r0 + tx] = tile[tx][ty + 8*i];
}

// -------- cast-only fp32 -> bf16, 3 matrices of DMODEL*DH --------
__global__ void cast3_v8(const float* __restrict__ a, const float* __restrict__ b,
                         const float* __restrict__ c,
                         bf16_t* __restrict__ oa, bf16_t* __restrict__ ob,
                         bf16_t* __restrict__ oc)
{
  const float* src = (blockIdx.z == 0) ? a : (blockIdx.z == 1) ? b : c;
  bf16_t* dst      = (blockIdx.z == 0) ? oa : (blockIdx.z == 1) ? ob : oc;
  const long i = ((long)blockIdx.x * 256 + threadIdx.x) * 4;
  float4 v = *(const float4*)(src + i);
  bf16x4 o;
  o[0] = (bf16_t)v.x; o[1] = (bf16_t)v.y; o[2] = (bf16_t)v.z; o[3] = (bf16_t)v.w;
  *(bf16x4*)(dst + i) = o;
}

// -------- cast-only fp32 -> bf16, one DMODEL*DH matrix --------
__global__ void cast1_v8(const float* __restrict__ src, bf16_t* __restrict__ dst)
{
  const long i = ((long)blockIdx.x * 256 + threadIdx.x) * 4;
  float4 v = *(const float4*)(src + i);
  bf16x4 o;
  o[0] = (bf16_t)v.x; o[1] = (bf16_t)v.y; o[2] = (bf16_t)v.z; o[3] = (bf16_t)v.w;
  *(bf16x4*)(dst + i) = o;
}

// ---------------- LayerNorm over last dim (768): fp32 in -> bf16 out ----------------
__global__ void ln_v8(const float* __restrict__ x, const float* __restrict__ g,
                      const float* __restrict__ b, bf16_t* __restrict__ y)
{
  const long row = blockIdx.x;
  const int tid = threadIdx.x;
  const float* xr = x + row * DMODEL;
  float v0 = xr[tid], v1 = xr[tid + 256], v2 = xr[tid + 512];
  float s  = v0 + v1 + v2;
  float ss = v0*v0 + v1*v1 + v2*v2;
  for (int o = 32; o; o >>= 1) { s += __shfl_down(s, o); ss += __shfl_down(ss, o); }
  __shared__ float rs[4], rss[4];
  const int wave = tid >> 6, lane = tid & 63;
  if (lane == 0) { rs[wave] = s; rss[wave] = ss; }
  __syncthreads();
  s  = rs[0] + rs[1] + rs[2] + rs[3];
  ss = rss[0] + rss[1] + rss[2] + rss[3];
  const float inv = 1.0f / (float)DMODEL;
  const float mean = s * inv;
  const float var  = ss * inv - mean * mean;
  const float rstd = rsqrtf(var + 1e-5f);
  bf16_t* yr = y + row * DMODEL;
  yr[tid]       = (bf16_t)(((v0 - mean) * rstd) * g[tid]       + b[tid]);
  yr[tid + 256] = (bf16_t)(((v1 - mean) * rstd) * g[tid + 256] + b[tid + 256]);
  yr[tid + 512] = (bf16_t)(((v2 - mean) * rstd) * g[tid + 512] + b[tid + 512]);
}

// ---------------- softmax over rows of 1024, in place, bf16 ----------------
__global__ void softmax_v8(bf16_t* __restrict__ S)
{
  const long row = blockIdx.x;
  const int tid = threadIdx.x;
  bf16_t* p = S + row * SEQ + tid * 4;
  bf16x4 v = *(const bf16x4*)p;
  float f0 = (float)v[0], f1 = (float)v[1], f2 = (float)v[2], f3 = (float)v[3];
  float m = fmaxf(fmaxf(f0, f1), fmaxf(f2, f3));
  for (int o = 32; o; o >>= 1) m = fmaxf(m, __shfl_down(m, o));
  __shared__ float rm[4], rsum[4];
  const int wave = tid >> 6, lane = tid & 63;
  if (lane == 0) rm[wave] = m;
  __syncthreads();
  m = fmaxf(fmaxf(rm[0], rm[1]), fmaxf(rm[2], rm[3]));
  float e0 = __expf(f0 - m), e1 = __expf(f1 - m), e2 = __expf(f2 - m), e3 = __expf(f3 - m);
  float s = e0 + e1 + e2 + e3;
  for (int o = 32; o; o >>= 1) s += __shfl_down(s, o);
  if (lane == 0) rsum[wave] = s;
  __syncthreads();
  s = rsum[0] + rsum[1] + rsum[2] + rsum[3];
  const float invs = 1.0f / s;
  bf16x4 o4;
  o4[0] = (bf16_t)(e0 * invs); o4[1] = (bf16_t)(e1 * invs);
  o4[2] = (bf16_t)(e2 * invs); o4[3] = (bf16_t)(e3 * invs);
  *(bf16x4*)p = o4;
}

// ---------------- finalize: o = acc + bias[col] + add ----------------
__global__ void finalize_v8(const float* __restrict__ acc, const float* __restrict__ add,
                            const float* __restrict__ bias, float* __restrict__ o)
{
  const long i = (long)blockIdx.x * 256 + threadIdx.x;
  const int c = (int)(i % DMODEL);
  o[i] = acc[i] + bias[c] + add[i];
}

// ------- split-K reduce: o = sum_{n<NP} p[n*plane] + bias[col] + add (float4) -------
template<int NP>
__global__ void reduce_v8(const float* __restrict__ p, const float* __restrict__ add,
                          const float* __restrict__ bias, float* __restrict__ o,
                          long plane)
{
  const long i = ((long)blockIdx.x * 256 + threadIdx.x) * 4;
  float4 s = *(const float4*)(p + i);
#pragma unroll
  for (int n = 1; n < NP; ++n) {
    float4 v = *(const float4*)(p + i + (long)n * plane);
    s.x += v.x; s.y += v.y; s.z += v.z; s.w += v.w;
  }
  const int c = (int)(i % DMODEL);
  float4 bv = *(const float4*)(bias + c);
  float4 av = *(const float4*)(add + i);
  float4 r;
  r.x = s.x + bv.x + av.x; r.y = s.y + bv.y + av.y;
  r.z = s.z + bv.z + av.z; r.w = s.w + bv.w + av.w;
  *(float4*)(o + i) = r;
}

// ---------------------------------------------------------------------------
extern "C" void kernel_launch(void* const* d_in, const int* in_sizes, int n_in,
                              void* d_out, int out_size, void* d_ws, size_t ws_size,
                              hipStream_t stream)
{
  (void)in_sizes; (void)n_in; (void)out_size;
  const float* x    = (const float*)d_in[0];
  const float* Wq   = (const float*)d_in[1];
  const float* Wk   = (const float*)d_in[2];
  const float* Wv   = (const float*)d_in[3];
  const float* Wu   = (const float*)d_in[4];
  const float* bu   = (const float*)d_in[5];
  const float* ln1g = (const float*)d_in[6];
  const float* ln1b = (const float*)d_in[7];
  const float* ln2g = (const float*)d_in[8];
  const float* ln2b = (const float*)d_in[9];
  const float* W1   = (const float*)d_in[10];
  const float* b1   = (const float*)d_in[11];
  const float* W2   = (const float*)d_in[12];
  const float* b2   = (const float*)d_in[13];
  float* out = (float*)d_out;

  char* ws = (char*)d_ws;
  size_t off = 0;
  auto alloc = [&](size_t bytes) -> void* {
    void* p = (void*)(ws + off);
    off += (bytes + 255) & ~(size_t)255;
    return p;
  };

  const float qk_alpha = 1.0f / sqrtf((float)DMODEL);
  dim3 tb(32, 8);

  const size_t SZ_W   = (size_t)DMODEL * DH * 2;         // 14,155,776
  const size_t SZ_MT  = (size_t)NHEAD * DMODEL * DMODEL * 2;
  const size_t SZ_Y   = (size_t)ROWS * DMODEL * 2;       // 6,291,456
  const size_t SZ_X2  = (size_t)ROWS * DMODEL * 4;       // 12,582,912

  if (ws_size >= (size_t)262e6) {
    // ===== PLAN A2': full-batch folded, ~261.2 MB; 2-batch T/scores grouping =====
    bf16_t* MT   = (bf16_t*)alloc(SZ_MT);                       // 14.2 MB
    bf16_t* PhT  = (bf16_t*)alloc(SZ_MT);                       // 14.2 MB
    bf16_t* y    = (bf16_t*)alloc(SZ_Y);                        //  6.3 MB
    float*  x2f  = (float* )alloc(SZ_X2);                       // 12.6 MB
    float*  part = (float* )alloc((size_t)3 * ROWS * DMODEL * 4); // 37.7 MB
    bf16_t* S    = (bf16_t*)alloc((size_t)NBATCH * SEQ * NHEAD * SEQ * 2);    // 100.7 MB
    bf16_t* Zt   = (bf16_t*)alloc((size_t)NBATCH * DMODEL * NHEAD * SEQ * 2); // 75.5 MB
    // aliases (lifetime-disjoint):
    bf16_t* T2   = (bf16_t*)part;                  // 2-batch T (37.7 MB, exact fit)
    bf16_t* Wqb  = (bf16_t*)S;                     // weight staging in S (dead early)
    bf16_t* Wkb  = (bf16_t*)((char*)S + SZ_W);
    bf16_t* Wvb  = (bf16_t*)((char*)S + 2*SZ_W);
    bf16_t* WuT  = (bf16_t*)((char*)S + 3*SZ_W);
    bf16_t* W1T  = (bf16_t*)S;                     // MLP phase (S dead after out-gemm)
    bf16_t* W2T  = (bf16_t*)((char*)S + 4718592);
    bf16_t* t    = (bf16_t*)((char*)S + 9437184);  // 25.2 MB
    float*  partM= (float* )((char*)S + 34603008); // 4 x 12.58 MB
    bf16_t* y2   = (bf16_t*)Zt;                    // Zt dead after out-gemm

    // ---- weight folds ----
    cast3_v8<<<dim3(6912, 1, 3), 256, 0, stream>>>(Wq, Wk, Wv, Wqb, Wkb, Wvb);
    tr_f2b_v8<<<dim3(DMODEL/32, DH/32), tb, 0, stream>>>(Wu, WuT, DMODEL, DH);
    gemm_v8<false,false,false,0><<<dim3(6, 6, NHEAD), 256, 0, stream>>>(
        Wkb, Wqb, MT, DMODEL, DH, DH, DMODEL, NHEAD,
        0, DMODEL, 0, DMODEL, 0, (long)DMODEL*DMODEL, nullptr, nullptr, 0, 1.0f);
    gemm_v8<false,false,false,0><<<dim3(6, 6, NHEAD), 256, 0, stream>>>(
        WuT, Wvb, PhT, DMODEL, DH, DH, DMODEL, NHEAD,
        0, DMODEL, 0, DMODEL, 0, (long)DMODEL*DMODEL, nullptr, nullptr, 0, 1.0f);

    // ---- attention ----
    ln_v8<<<ROWS, 256, 0, stream>>>(x, ln1g, ln1b, y);
    // 2-batch pairs: T2[p][h][i][g] = y_{b0+p} @ M_h ; S[b0+p] = T2_ph @ y_{b0+p}^T
    for (int b0 = 0; b0 < NBATCH; b0 += 2) {
      const bf16_t* yb = y + (long)b0 * SEQ * DMODEL;
      gemm_v8<false,false,false,0><<<dim3(6, 8, 2*NHEAD), 256, 0, stream>>>(
          yb, MT, T2, DMODEL, DMODEL, DMODEL, DMODEL, NHEAD,
          (long)SEQ*DMODEL, 0, 0, (long)DMODEL*DMODEL,
          (long)NHEAD*SEQ*DMODEL, (long)SEQ*DMODEL,
          nullptr, nullptr, 0, 1.0f);
      gemm_v8<false,false,false,0><<<dim3(8, 8, 2*NHEAD), 256, 0, stream>>>(
          T2, yb, S + (long)b0*SEQ*NHEAD*SEQ, DMODEL, DMODEL, DMODEL, NHEAD*SEQ, NHEAD,
          (long)NHEAD*SEQ*DMODEL, (long)SEQ*DMODEL,
          (long)SEQ*DMODEL, 0,
          (long)SEQ*NHEAD*SEQ, (long)SEQ,
          nullptr, nullptr, 0, qk_alpha);
    }
    softmax_v8<<<NBATCH*SEQ*NHEAD, 256, 0, stream>>>(S);
    // Zt[b][d][h*1024+j] = PhT_h @ y_b^T   (z = b*NHEAD + h)
    gemm_v8<false,false,false,0><<<dim3(8, 6, NBATCH*NHEAD), 256, 0, stream>>>(
        PhT, y, Zt, DMODEL, DMODEL, DMODEL, NHEAD*SEQ, NHEAD,
        0, (long)DMODEL*DMODEL, (long)SEQ*DMODEL, 0,
        (long)DMODEL*NHEAD*SEQ, (long)SEQ, nullptr, nullptr, 0, 1.0f);
    // out_b = S_b(1024x12288) @ Zt_b^T, split-K 3: z = kc*NBATCH + b
    gemm_v8<false,false,false,1><<<dim3(6, 8, 12), 256, 0, stream>>>(
        S, Zt, part, NHEAD*SEQ/3, NHEAD*SEQ, NHEAD*SEQ, DMODEL, NBATCH,
        (long)(NHEAD*SEQ/3), (long)SEQ*NHEAD*SEQ,
        (long)(NHEAD*SEQ/3), (long)DMODEL*NHEAD*SEQ,
        (long)ROWS*DMODEL, (long)SEQ*DMODEL, nullptr, nullptr, 0, 1.0f);
    reduce_v8<3><<<(ROWS*DMODEL)/1024, 256, 0, stream>>>(
        part, x, bu, x2f, (long)ROWS*DMODEL);

    // ---- MLP ----
    tr_f2b_v8<<<dim3(DFF/32, DMODEL/32), tb, 0, stream>>>(W1, W1T, DFF, DMODEL);
    tr_f2b_v8<<<dim3(DMODEL/32, DFF/32), tb, 0, stream>>>(W2, W2T, DMODEL, DFF);
    ln_v8<<<ROWS, 256, 0, stream>>>(x2f, ln2g, ln2b, y2);
    gemm_v8<true,false,true,0><<<dim3(DFF/128, ROWS/128, 1), 256, 0, stream>>>(
        y2, W1T, t, DMODEL, DMODEL, DMODEL, DFF, 1, 0,0,0,0,0,0, b1, nullptr, 0, 1.0f);
    gemm_v8<false,false,false,1><<<dim3(6, ROWS/128, 4), 256, 0, stream>>>(
        t, W2T, partM, DFF/4, DFF, DFF, DMODEL, 4,
        0, (long)(DFF/4), 0, (long)(DFF/4), 0, (long)ROWS*DMODEL,
        nullptr, nullptr, 0, 1.0f);
    reduce_v8<4><<<(ROWS*DMODEL)/1024, 256, 0, stream>>>(
        partM, x2f, b2, out, (long)ROWS*DMODEL);
  } else if (ws_size >= (size_t)112e6) {
    // ===== PLAN B: batch-looped folded (~110.1 MB) =====
    bf16_t* MT  = (bf16_t*)alloc(SZ_MT);
    bf16_t* PhT = (bf16_t*)alloc(SZ_MT);
    bf16_t* y   = (bf16_t*)alloc(SZ_Y);
    float*  x2f = (float* )alloc(SZ_X2);
    char*   BIG = (char*  )alloc((size_t)62914560);
    bf16_t* T_b  = (bf16_t*)(BIG);
    bf16_t* S_b  = (bf16_t*)(BIG + 18874368);
    bf16_t* Zt_b = (bf16_t*)(BIG + 44040192);
    float*  part = (float* )(BIG);
    bf16_t* Wqb = (bf16_t*)(BIG);
    bf16_t* Wkb = (bf16_t*)(BIG + SZ_W);
    bf16_t* Wvb = (bf16_t*)(BIG + 2*SZ_W);
    bf16_t* WuT = (bf16_t*)(BIG + 3*SZ_W);
    bf16_t* W1T   = (bf16_t*)(BIG);
    bf16_t* W2T   = (bf16_t*)(BIG + 4718592);
    bf16_t* t     = (bf16_t*)(BIG + 9437184);
    float*  partM = (float* )(BIG + 34603008);
    bf16_t* y2    = y;

    cast3_v8<<<dim3(6912, 1, 3), 256, 0, stream>>>(Wq, Wk, Wv, Wqb, Wkb, Wvb);
    tr_f2b_v8<<<dim3(DMODEL/32, DH/32), tb, 0, stream>>>(Wu, WuT, DMODEL, DH);
    gemm_v8<false,false,false,0><<<dim3(6, 6, NHEAD), 256, 0, stream>>>(
        Wkb, Wqb, MT, DMODEL, DH, DH, DMODEL, NHEAD,
        0, DMODEL, 0, DMODEL, 0, (long)DMODEL*DMODEL, nullptr, nullptr, 0, 1.0f);
    gemm_v8<false,false,false,0><<<dim3(6, 6, NHEAD), 256, 0, stream>>>(
        WuT, Wvb, PhT, DMODEL, DH, DH, DMODEL, NHEAD,
        0, DMODEL, 0, DMODEL, 0, (long)DMODEL*DMODEL, nullptr, nullptr, 0, 1.0f);

    ln_v8<<<ROWS, 256, 0, stream>>>(x, ln1g, ln1b, y);
    for (int b = 0; b < NBATCH; ++b) {
      const bf16_t* yb = y + (long)b * SEQ * DMODEL;
      gemm_v8<false,false,false,0><<<dim3(6, 8, NHEAD), 256, 0, stream>>>(
          yb, MT, T_b, DMODEL, DMODEL, DMODEL, DMODEL, NHEAD,
          0, 0, 0, (long)DMODEL*DMODEL, 0, (long)SEQ*DMODEL,
          nullptr, nullptr, 0, 1.0f);
      gemm_v8<false,false,false,0><<<dim3(8, 8, NHEAD), 256, 0, stream>>>(
          T_b, yb, S_b, DMODEL, DMODEL, DMODEL, NHEAD*SEQ, NHEAD,
          0, (long)SEQ*DMODEL, 0, 0, 0, (long)SEQ,
          nullptr, nullptr, 0, qk_alpha);
      softmax_v8<<<NHEAD*SEQ, 256, 0, stream>>>(S_b);
      gemm_v8<false,false,false,0><<<dim3(8, 6, NHEAD), 256, 0, stream>>>(
          PhT, yb, Zt_b, DMODEL, DMODEL, DMODEL, NHEAD*SEQ, NHEAD,
          0, (long)DMODEL*DMODEL, 0, 0, 0, (long)SEQ,
          nullptr, nullptr, 0, 1.0f);
      gemm_v8<false,false,false,1><<<dim3(6, 8, 6), 256, 0, stream>>>(
          S_b, Zt_b, part, NHEAD*SEQ/6, NHEAD*SEQ, NHEAD*SEQ, DMODEL, 6,
          0, (long)(NHEAD*SEQ/6), 0, (long)(NHEAD*SEQ/6), 0, (long)SEQ*DMODEL,
          nullptr, nullptr, 0, 1.0f);
      reduce_v8<6><<<(SEQ*DMODEL)/1024, 256, 0, stream>>>(
          part, x + (long)b*SEQ*DMODEL, bu, x2f + (long)b*SEQ*DMODEL,
          (long)SEQ*DMODEL);
    }

    tr_f2b_v8<<<dim3(DFF/32, DMODEL/32), tb, 0, stream>>>(W1, W1T, DFF, DMODEL);
    tr_f2b_v8<<<dim3(DMODEL/32, DFF/32), tb, 0, stream>>>(W2, W2T, DMODEL, DFF);
    ln_v8<<<ROWS, 256, 0, stream>>>(x2f, ln2g, ln2b, y2);
    gemm_v8<true,false,true,0><<<dim3(DFF/128, ROWS/128, 1), 256, 0, stream>>>(
        y2, W1T, t, DMODEL, DMODEL, DMODEL, DFF, 1, 0,0,0,0,0,0, b1, nullptr, 0, 1.0f);
    gemm_v8<false,false,false,1><<<dim3(6, ROWS/128, 2), 256, 0, stream>>>(
        t, W2T, partM, DFF/2, DFF, DFF, DMODEL, 2,
        0, (long)(DFF/2), 0, (long)(DFF/2), 0, (long)ROWS*DMODEL,
        nullptr, nullptr, 0, 1.0f);
    reduce_v8<2><<<(ROWS*DMODEL)/1024, 256, 0, stream>>>(
        partM, x2f, b2, out, (long)ROWS*DMODEL);
  } else if (ws_size >= (size_t)70e6) {
    // ===== PLAN C: head-looped folded (~68.2 MB) =====
    bf16_t* MT  = (bf16_t*)alloc(SZ_MT);
    bf16_t* PhT = (bf16_t*)alloc(SZ_MT);
    bf16_t* y   = (bf16_t*)alloc(SZ_Y);
    char*   R   = (char*  )alloc((size_t)33554432);
    bf16_t* WAb = (bf16_t*)(R);
    bf16_t* WBb = (bf16_t*)(R + SZ_W);
    float*  x2f = (float* )(R);
    bf16_t* T_h = (bf16_t*)(R + 12582912);
    bf16_t* S_h = (bf16_t*)(R + 18874368);
    bf16_t* Z_h = (bf16_t*)(R + 27262976);
    bf16_t* W1T = (bf16_t*)(R + 12582912);
    bf16_t* W2T = (bf16_t*)(R + 17301504);
    bf16_t* t   = (bf16_t*)MT;
    bf16_t* y2  = y;

    cast1_v8<<<6912, 256, 0, stream>>>(Wq, WAb);
    cast1_v8<<<6912, 256, 0, stream>>>(Wk, WBb);
    gemm_v8<false,false,false,0><<<dim3(6, 6, NHEAD), 256, 0, stream>>>(
        WBb, WAb, MT, DMODEL, DH, DH, DMODEL, NHEAD,
        0, DMODEL, 0, DMODEL, 0, (long)DMODEL*DMODEL, nullptr, nullptr, 0, 1.0f);
    cast1_v8<<<6912, 256, 0, stream>>>(Wv, WAb);
    tr_f2b_v8<<<dim3(DMODEL/32, DH/32), tb, 0, stream>>>(Wu, WBb, DMODEL, DH);
    gemm_v8<false,false,false,0><<<dim3(6, 6, NHEAD), 256, 0, stream>>>(
        WBb, WAb, PhT, DMODEL, DH, DH, DMODEL, NHEAD,
        0, DMODEL, 0, DMODEL, 0, (long)DMODEL*DMODEL, nullptr, nullptr, 0, 1.0f);

    ln_v8<<<ROWS, 256, 0, stream>>>(x, ln1g, ln1b, y);
    for (int h = 0; h < NHEAD; ++h) {
      const bf16_t* MTh  = MT  + (long)h * DMODEL * DMODEL;
      const bf16_t* PhTh = PhT + (long)h * DMODEL * DMODEL;
      gemm_v8<false,false,false,0><<<dim3(6, ROWS/128, 1), 256, 0, stream>>>(
          y, MTh, T_h, DMODEL, DMODEL, DMODEL, DMODEL, 1,
          0,0,0,0,0,0, nullptr, nullptr, 0, 1.0f);
      gemm_v8<false,false,false,0><<<dim3(8, 8, NBATCH), 256, 0, stream>>>(
          T_h, y, S_h, DMODEL, DMODEL, DMODEL, SEQ, NBATCH,
          0, (long)SEQ*DMODEL, 0, (long)SEQ*DMODEL, 0, (long)SEQ*SEQ,
          nullptr, nullptr, 0, qk_alpha);
      softmax_v8<<<ROWS, 256, 0, stream>>>(S_h);
      gemm_v8<false,false,false,0><<<dim3(8, 6, NBATCH), 256, 0, stream>>>(
          PhTh, y, Z_h, DMODEL, DMODEL, DMODEL, SEQ, NBATCH,
          0, 0, 0, (long)SEQ*DMODEL, 0, (long)DMODEL*SEQ,
          nullptr, nullptr, 0, 1.0f);
      if (h == 0)
        gemm_v8<false,false,false,1><<<dim3(6, 8, NBATCH), 256, 0, stream>>>(
            S_h, Z_h, x2f, SEQ, SEQ, SEQ, DMODEL, NBATCH,
            0, (long)SEQ*SEQ, 0, (long)DMODEL*SEQ, 0, (long)SEQ*DMODEL,
            nullptr, nullptr, 0, 1.0f);
      else
        gemm_v8<false,false,false,2><<<dim3(6, 8, NBATCH), 256, 0, stream>>>(
            S_h, Z_h, x2f, SEQ, SEQ, SEQ, DMODEL, NBATCH,
            0, (long)SEQ*SEQ, 0, (long)DMODEL*SEQ, 0, (long)SEQ*DMODEL,
            nullptr, nullptr, 0, 1.0f);
    }
    finalize_v8<<<(ROWS*DMODEL)/256, 256, 0, stream>>>(x2f, x, bu, x2f);

    tr_f2b_v8<<<dim3(DFF/32, DMODEL/32), tb, 0, stream>>>(W1, W1T, DFF, DMODEL);
    tr_f2b_v8<<<dim3(DMODEL/32, DFF/32), tb, 0, stream>>>(W2, W2T, DMODEL, DFF);
    ln_v8<<<ROWS, 256, 0, stream>>>(x2f, ln2g, ln2b, y2);
    gemm_v8<true,false,true,0><<<dim3(DFF/128, ROWS/128, 1), 256, 0, stream>>>(
        y2, W1T, t, DMODEL, DMODEL, DMODEL, DFF, 1, 0,0,0,0,0,0, b1, nullptr, 0, 1.0f);
    gemm_v8<true,true,false,1><<<dim3(6, ROWS/128, 1), 256, 0, stream>>>(
        t, W2T, out, DFF/2, DFF, DFF, DMODEL, 1, 0,0,0,0,0,0,
        b2, x2f, DMODEL, 1.0f);
    gemm_v8<false,false,false,2><<<dim3(6, ROWS/128, 1), 256, 0, stream>>>(
        t + DFF/2, W2T + DFF/2, out, DFF/2, DFF, DFF, DMODEL, 1, 0,0,0,0,0,0,
        nullptr, nullptr, 0, 1.0f);
  } else {
    // ===== legacy SMALL PLAN (~43 MB) =====
    bf16_t* W1T   = (bf16_t*)alloc((size_t)DMODEL * DFF * 2);
    bf16_t* W2T   = (bf16_t*)alloc((size_t)DMODEL * DFF * 2);
    bf16_t* y     = (bf16_t*)alloc(SZ_Y);
    float*  x2f   = (float* )alloc(SZ_X2);
    char*   reg1  = (char*)alloc((size_t)3*DMODEL*DMODEL*2 + (size_t)DMODEL*DMODEL*2 + (size_t)SEQ*DMODEL*2);
    bf16_t* WhT   = (bf16_t*)reg1;
    bf16_t* WuTh  = (bf16_t*)(reg1 + (size_t)3*DMODEL*DMODEL*2);
    bf16_t* attb  = (bf16_t*)(reg1 + (size_t)4*DMODEL*DMODEL*2);
    bf16_t* y2    = (bf16_t*)reg1;
    char*   reg2  = (char*)alloc((size_t)SEQ*3*DMODEL*2 + (size_t)DMODEL*SEQ*2 + (size_t)SEQ*SEQ*2);
    bf16_t* QKVb  = (bf16_t*)reg2;
    bf16_t* Vtb   = (bf16_t*)(reg2 + (size_t)SEQ*3*DMODEL*2);
    bf16_t* Sb    = (bf16_t*)(reg2 + (size_t)SEQ*3*DMODEL*2 + (size_t)DMODEL*SEQ*2);
    bf16_t* tslab = (bf16_t*)reg2;

    tr_f2b_v8<<<dim3(DFF/32, DMODEL/32), tb, 0, stream>>>(W1, W1T, DFF, DMODEL);
    tr_f2b_v8<<<dim3(DMODEL/32, DFF/32), tb, 0, stream>>>(W2, W2T, DMODEL, DFF);
    ln_v8<<<ROWS, 256, 0, stream>>>(x, ln1g, ln1b, y);

    const int N3 = 3 * DMODEL;
    for (int h = 0; h < NHEAD; ++h) {
      tr_wh_v8<<<dim3(24, 24, 4), tb, 0, stream>>>(Wq, Wk, Wv, Wu, WhT, WuTh, h);
      for (int b = 0; b < NBATCH; ++b) {
        const bf16_t* yb = y + (size_t)b * SEQ * DMODEL;
        gemm_v8<false,false,false,0><<<dim3(N3/128, SEQ/128, 1), 256, 0, stream>>>(
            yb, WhT, QKVb, DMODEL, DMODEL, DMODEL, N3, 1, 0,0,0,0,0,0,
            nullptr, nullptr, 0, 1.0f);
        tr_b_v8<<<dim3(DMODEL/32, SEQ/32, 1), tb, 0, stream>>>(
            QKVb + 2*DMODEL, Vtb, N3, SEQ, 1, 0,0,0,0);
        gemm_v8<false,false,false,0><<<dim3(SEQ/128, SEQ/128, 1), 256, 0, stream>>>(
            QKVb, QKVb + DMODEL, Sb, DMODEL, N3, N3, SEQ, 1, 0,0,0,0,0,0,
            nullptr, nullptr, 0, qk_alpha);
        softmax_v8<<<SEQ, 256, 0, stream>>>(Sb);
        gemm_v8<false,false,false,0><<<dim3(DMODEL/128, SEQ/128, 1), 256, 0, stream>>>(
            Sb, Vtb, attb, SEQ, SEQ, SEQ, DMODEL, 1, 0,0,0,0,0,0,
            nullptr, nullptr, 0, 1.0f);
        float* x2b = x2f + (size_t)b * SEQ * DMODEL;
        if (h == 0)
          gemm_v8<false,false,false,1><<<dim3(DMODEL/128, SEQ/128, 1), 256, 0, stream>>>(
              attb, WuTh, x2b, DMODEL, DMODEL, DMODEL, DMODEL, 1, 0,0,0,0,0,0,
              nullptr, nullptr, 0, 1.0f);
        else
          gemm_v8<false,false,false,2><<<dim3(DMODEL/128, SEQ/128, 1), 256, 0, stream>>>(
              attb, WuTh, x2b, DMODEL, DMODEL, DMODEL, DMODEL, 1, 0,0,0,0,0,0,
              nullptr, nullptr, 0, 1.0f);
      }
    }
    finalize_v8<<<(ROWS*DMODEL)/256, 256, 0, stream>>>(x2f, x, bu, x2f);
    ln_v8<<<ROWS, 256, 0, stream>>>(x2f, ln2g, ln2b, y2);
    for (int kb = 0; kb < 4; ++kb) {
      gemm_v8<true,false,true,0><<<dim3(DMODEL/128, ROWS/128, 1), 256, 0, stream>>>(
          y2, W1T + (size_t)kb*DMODEL*DMODEL, tslab, DMODEL, DMODEL, DMODEL, DMODEL, 1,
          0,0,0,0,0,0, b1 + kb*DMODEL, nullptr, 0, 1.0f);
      if (kb == 0)
        gemm_v8<true,true,false,1><<<dim3(DMODEL/128, ROWS/128, 1), 256, 0, stream>>>(
            tslab, W2T + (size_t)kb*DMODEL, out, DMODEL, DMODEL, DFF, DMODEL, 1,
            0,0,0,0,0,0, b2, x2f, DMODEL, 1.0f);
      else
        gemm_v8<false,false,false,2><<<dim3(DMODEL/128, ROWS/128, 1), 256, 0, stream>>>(
            tslab, W2T + (size_t)kb*DMODEL, out, DMODEL, DMODEL, DFF, DMODEL, 1,
            0,0,0,0,0,0, nullptr, nullptr, 0, 1.0f);
    }
  }
}

// Round 9
// 958.407 us; speedup vs baseline: 1.3655x; 1.0374x over previous
//
#include <hip/hip_runtime.h>
#include <cstdint>
#include <cmath>

// v9: OMODE=3 atomic-fp32 split-K (unsafeAtomicAdd) for the latency-bound
//     long-K GEMMs. Plan A3 (>=230e6, 223.5 MB): full-batch everything;
//     out-GEMM split-K 8 (1536 blocks), MLP2 split-K 4. gload_lds + XCD
//     swizzle retained. Plan B (>=112e6) / C / small unchanged fallbacks.

typedef __bf16 bf16_t;
typedef __bf16 bf16x8 __attribute__((ext_vector_type(8)));
typedef __bf16 bf16x4 __attribute__((ext_vector_type(4)));
typedef float floatx4 __attribute__((ext_vector_type(4)));

#define DMODEL 768
#define NHEAD  12
#define SEQ    1024
#define NBATCH 4
#define ROWS   (NBATCH*SEQ)   // 4096
#define DH     (DMODEL*NHEAD) // 9216
#define DFF    (4*DMODEL)     // 3072

// ---- async 16B global->LDS (gfx950). LDS dest = wave-uniform base + lane*16B. ----
__device__ __forceinline__ void gload16(const bf16_t* g, bf16_t* l)
{
  __builtin_amdgcn_global_load_lds(
      (const __attribute__((address_space(1))) void*)g,
      (__attribute__((address_space(3))) void*)l,
      16, 0, 0);
}

// ---------------------------------------------------------------------------
// GEMM: C = alpha*(A @ B^T) [+bias[col]] [relu] [+res]
// OMODE: 0 = bf16 store, 1 = f32 store, 2 = f32 accumulate (non-atomic),
//        3 = f32 atomicAdd (HW fadd) into pre-initialized target
// Batched via z: off = (z/bdiv)*hi + (z%bdiv)*lo (element offsets)
// 128x128 tile, BK=64, gload_lds w16 staging, XCD-bijective block swizzle.
// Requires K % 64 == 0.
// ---------------------------------------------------------------------------
template<bool BIAS, bool RES, bool RELU, int OMODE>
__global__ __launch_bounds__(256)
void gemm_v9(const bf16_t* __restrict__ A, const bf16_t* __restrict__ BT,
             void* __restrict__ Cv, int K, int lda, int ldb, int ldc,
             int bdiv, long sa_hi, long sa_lo, long sb_hi, long sb_lo,
             long sc_hi, long sc_lo,
             const float* __restrict__ bias, const float* __restrict__ res,
             int ldres, float alpha)
{
  __shared__ __align__(16) bf16_t As[128*64];   // panel p at p*4096 elems
  __shared__ __align__(16) bf16_t Bs[128*64];

  // ---- XCD-aware bijective swizzle (m204) ----
  const long nwg  = (long)gridDim.x * gridDim.y * gridDim.z;
  const long orig = blockIdx.x + (long)gridDim.x * (blockIdx.y + (long)gridDim.y * blockIdx.z);
  const long q8 = nwg >> 3, r8 = nwg & 7;
  const long xcd = orig & 7, loc = orig >> 3;
  const long swz = (xcd < r8 ? xcd*(q8+1) : r8*(q8+1) + (xcd - r8)*q8) + loc;
  const int  bix = (int)(swz % (long)gridDim.x);
  const long rem = swz / (long)gridDim.x;
  const int  biy = (int)(rem % (long)gridDim.y);
  const int  biz = (int)(rem / (long)gridDim.y);

  const int tid  = threadIdx.x;
  const int wave = tid >> 6;
  const int lane = tid & 63;
  const int r    = lane & 15;
  const int q    = lane >> 4;

  A  += (long)(biz / bdiv) * sa_hi + (long)(biz % bdiv) * sa_lo;
  BT += (long)(biz / bdiv) * sb_hi + (long)(biz % bdiv) * sb_lo;
  const long coff = (long)(biz / bdiv) * sc_hi + (long)(biz % bdiv) * sc_lo;

  const int bm = biy * 128;
  const int bn = bix * 128;
  const int wm = (wave & 1) * 64;
  const int wn = (wave >> 1) * 64;

  const int blk0 = 2*wave, blk1 = 2*wave + 1;
  const bf16_t* a_src0 = A  + (long)(bm + blk0*16 + r) * lda + q*8;
  const bf16_t* a_src1 = A  + (long)(bm + blk1*16 + r) * lda + q*8;
  const bf16_t* b_src0 = BT + (long)(bn + blk0*16 + r) * ldb + q*8;
  const bf16_t* b_src1 = BT + (long)(bn + blk1*16 + r) * ldb + q*8;
  bf16_t* a_dst0 = As + blk0*512;   // wave-uniform; HW adds lane*16B
  bf16_t* a_dst1 = As + blk1*512;
  bf16_t* b_dst0 = Bs + blk0*512;
  bf16_t* b_dst1 = Bs + blk1*512;

  const int am = (wave & 1) * 4;
  const int bb = (wave >> 1) * 4;

  floatx4 acc[4][4] = {};

  for (int k0 = 0; k0 < K; k0 += 64) {
    gload16(a_src0 + k0,      a_dst0);
    gload16(a_src1 + k0,      a_dst1);
    gload16(b_src0 + k0,      b_dst0);
    gload16(b_src1 + k0,      b_dst1);
    gload16(a_src0 + k0 + 32, a_dst0 + 4096);
    gload16(a_src1 + k0 + 32, a_dst1 + 4096);
    gload16(b_src0 + k0 + 32, b_dst0 + 4096);
    gload16(b_src1 + k0 + 32, b_dst1 + 4096);
    __syncthreads();
#pragma unroll
    for (int p = 0; p < 2; ++p) {
      bf16x8 afrag[4], bfrag[4];
#pragma unroll
      for (int t = 0; t < 4; ++t) {
        afrag[t] = *(const bf16x8*)(As + p*4096 + (am + t)*512 + lane*8);
        bfrag[t] = *(const bf16x8*)(Bs + p*4096 + (bb + t)*512 + lane*8);
      }
#pragma unroll
      for (int mt = 0; mt < 4; ++mt)
#pragma unroll
        for (int nt = 0; nt < 4; ++nt)
          acc[mt][nt] = __builtin_amdgcn_mfma_f32_16x16x32_bf16(
              afrag[mt], bfrag[nt], acc[mt][nt], 0, 0, 0);
    }
    __syncthreads();
  }

  // epilogue: C/D layout col=lane&15, row=(lane>>4)*4+e
  const int row0 = bm + wm + q*4;
  const int col0 = bn + wn + r;
#pragma unroll
  for (int nt = 0; nt < 4; ++nt) {
    const int col = col0 + nt*16;
    float bv = 0.f;
    if (BIAS) bv = bias[col];
#pragma unroll
    for (int mt = 0; mt < 4; ++mt) {
#pragma unroll
      for (int e = 0; e < 4; ++e) {
        const int rowi = row0 + mt*16 + e;
        float v = acc[mt][nt][e] * alpha;
        if (BIAS) v += bv;
        if (RELU) v = fmaxf(v, 0.f);
        if (RES)  v += res[(long)rowi * ldres + col];
        const long idx = coff + (long)rowi * ldc + col;
        if (OMODE == 0)      ((bf16_t*)Cv)[idx] = (bf16_t)v;
        else if (OMODE == 1) ((float*)Cv)[idx] = v;
        else if (OMODE == 2) ((float*)Cv)[idx] += v;
        else                 unsafeAtomicAdd(&((float*)Cv)[idx], v);
      }
    }
  }
}

// -------- 32x32 tiled transpose, fp32 in -> bf16 out --------
__global__ void tr_f2b_v9(const float* __restrict__ in, bf16_t* __restrict__ out,
                          int ldi, int ldo)
{
  __shared__ bf16_t tile[32][34];
  const int c0 = blockIdx.x * 32, r0 = blockIdx.y * 32;
  const int tx = threadIdx.x, ty = threadIdx.y;
#pragma unroll
  for (int i = 0; i < 4; ++i)
    tile[ty + 8*i][tx] = (bf16_t)in[(long)(r0 + ty + 8*i) * ldi + c0 + tx];
  __syncthreads();
#pragma unroll
  for (int i = 0; i < 4; ++i)
    out[(long)(c0 + ty + 8*i) * ldo + r0 + tx] = tile[tx][ty + 8*i];
}

// -------- batched 32x32 tiled transpose, bf16 -> bf16 (small plan) --------
__global__ void tr_b_v9(const bf16_t* __restrict__ in, bf16_t* __restrict__ out,
                        int ldi, int ldo, int bdiv,
                        long si_hi, long si_lo, long so_hi, long so_lo)
{
  __shared__ bf16_t tile[32][34];
  const int z = blockIdx.z;
  in  += (long)(z / bdiv) * si_hi + (long)(z % bdiv) * si_lo;
  out += (long)(z / bdiv) * so_hi + (long)(z % bdiv) * so_lo;
  const int c0 = blockIdx.x * 32, r0 = blockIdx.y * 32;
  const int tx = threadIdx.x, ty = threadIdx.y;
#pragma unroll
  for (int i = 0; i < 4; ++i)
    tile[ty + 8*i][tx] = in[(long)(r0 + ty + 8*i) * ldi + c0 + tx];
  __syncthreads();
#pragma unroll
  for (int i = 0; i < 4; ++i)
    out[(long)(c0 + ty + 8*i) * ldo + r0 + tx] = tile[tx][ty + 8*i];
}

// -------- per-head weight transposes (small plan) --------
__global__ void tr_wh_v9(const float* __restrict__ Wq, const float* __restrict__ Wk,
                         const float* __restrict__ Wv, const float* __restrict__ Wu,
                         bf16_t* __restrict__ WhT, bf16_t* __restrict__ WuTh, int h)
{
  __shared__ bf16_t tile[32][34];
  const int z = blockIdx.z;
  const float* in; bf16_t* out; int ldi;
  if (z < 3) {
    const float* W = (z == 0) ? Wq : (z == 1) ? Wk : Wv;
    in  = W + (long)h * DMODEL;
    ldi = DH;
    out = WhT + (long)z * DMODEL * DMODEL;
  } else {
    in  = Wu + (long)h * DMODEL * DMODEL;
    ldi = DMODEL;
    out = WuTh;
  }
  const int c0 = blockIdx.x * 32, r0 = blockIdx.y * 32;
  const int tx = threadIdx.x, ty = threadIdx.y;
#pragma unroll
  for (int i = 0; i < 4; ++i)
    tile[ty + 8*i][tx] = (bf16_t)in[(long)(r0 + ty + 8*i) * ldi + c0 + tx];
  __syncthreads();
#pragma unroll
  for (int i = 0; i < 4; ++i)
    out[(long)(c0 + ty + 8*i) * DMODEL + r0 + tx] = tile[tx][ty + 8*i];
}

// -------- cast-only fp32 -> bf16, 3 matrices of DMODEL*DH --------
__global__ void cast3_v9(const float* __restrict__ a, const float* __restrict__ b,
                         const float* __restrict__ c,
                         bf16_t* __restrict__ oa, bf16_t* __restrict__ ob,
                         bf16_t* __restrict__ oc)
{
  const float* src = (blockIdx.z == 0) ? a : (blockIdx.z == 1) ? b : c;
  bf16_t* dst      = (blockIdx.z == 0) ? oa : (blockIdx.z == 1) ? ob : oc;
  const long i = ((long)blockIdx.x * 256 + threadIdx.x) * 4;
  float4 v = *(const float4*)(src + i);
  bf16x4 o;
  o[0] = (bf16_t)v.x; o[1] = (bf16_t)v.y; o[2] = (bf16_t)v.z; o[3] = (bf16_t)v.w;
  *(bf16x4*)(dst + i) = o;
}

// -------- cast-only fp32 -> bf16, one DMODEL*DH matrix --------
__global__ void cast1_v9(const float* __restrict__ src, bf16_t* __restrict__ dst)
{
  const long i = ((long)blockIdx.x * 256 + threadIdx.x) * 4;
  float4 v = *(const float4*)(src + i);
  bf16x4 o;
  o[0] = (bf16_t)v.x; o[1] = (bf16_t)v.y; o[2] = (bf16_t)v.z; o[3] = (bf16_t)v.w;
  *(bf16x4*)(dst + i) = o;
}

// ---------------- LayerNorm over last dim (768): fp32 in -> bf16 out ----------------
__global__ void ln_v9(const float* __restrict__ x, const float* __restrict__ g,
                      const float* __restrict__ b, bf16_t* __restrict__ y)
{
  const long row = blockIdx.x;
  const int tid = threadIdx.x;
  const float* xr = x + row * DMODEL;
  float v0 = xr[tid], v1 = xr[tid + 256], v2 = xr[tid + 512];
  float s  = v0 + v1 + v2;
  float ss = v0*v0 + v1*v1 + v2*v2;
  for (int o = 32; o; o >>= 1) { s += __shfl_down(s, o); ss += __shfl_down(ss, o); }
  __shared__ float rs[4], rss[4];
  const int wave = tid >> 6, lane = tid & 63;
  if (lane == 0) { rs[wave] = s; rss[wave] = ss; }
  __syncthreads();
  s  = rs[0] + rs[1] + rs[2] + rs[3];
  ss = rss[0] + rss[1] + rss[2] + rss[3];
  const float inv = 1.0f / (float)DMODEL;
  const float mean = s * inv;
  const float var  = ss * inv - mean * mean;
  const float rstd = rsqrtf(var + 1e-5f);
  bf16_t* yr = y + row * DMODEL;
  yr[tid]       = (bf16_t)(((v0 - mean) * rstd) * g[tid]       + b[tid]);
  yr[tid + 256] = (bf16_t)(((v1 - mean) * rstd) * g[tid + 256] + b[tid + 256]);
  yr[tid + 512] = (bf16_t)(((v2 - mean) * rstd) * g[tid + 512] + b[tid + 512]);
}

// ---------------- softmax over rows of 1024, in place, bf16 ----------------
__global__ void softmax_v9(bf16_t* __restrict__ S)
{
  const long row = blockIdx.x;
  const int tid = threadIdx.x;
  bf16_t* p = S + row * SEQ + tid * 4;
  bf16x4 v = *(const bf16x4*)p;
  float f0 = (float)v[0], f1 = (float)v[1], f2 = (float)v[2], f3 = (float)v[3];
  float m = fmaxf(fmaxf(f0, f1), fmaxf(f2, f3));
  for (int o = 32; o; o >>= 1) m = fmaxf(m, __shfl_down(m, o));
  __shared__ float rm[4], rsum[4];
  const int wave = tid >> 6, lane = tid & 63;
  if (lane == 0) rm[wave] = m;
  __syncthreads();
  m = fmaxf(fmaxf(rm[0], rm[1]), fmaxf(rm[2], rm[3]));
  float e0 = __expf(f0 - m), e1 = __expf(f1 - m), e2 = __expf(f2 - m), e3 = __expf(f3 - m);
  float s = e0 + e1 + e2 + e3;
  for (int o = 32; o; o >>= 1) s += __shfl_down(s, o);
  if (lane == 0) rsum[wave] = s;
  __syncthreads();
  s = rsum[0] + rsum[1] + rsum[2] + rsum[3];
  const float invs = 1.0f / s;
  bf16x4 o4;
  o4[0] = (bf16_t)(e0 * invs); o4[1] = (bf16_t)(e1 * invs);
  o4[2] = (bf16_t)(e2 * invs); o4[3] = (bf16_t)(e3 * invs);
  *(bf16x4*)p = o4;
}

// ---------------- finalize: o = acc + bias[col] + add ----------------
__global__ void finalize_v9(const float* __restrict__ acc, const float* __restrict__ add,
                            const float* __restrict__ bias, float* __restrict__ o)
{
  const long i = (long)blockIdx.x * 256 + threadIdx.x;
  const int c = (int)(i % DMODEL);
  o[i] = acc[i] + bias[c] + add[i];
}

// ---------------- init: o = add + bias[col]  (float4) ----------------
__global__ void initb_v9(const float* __restrict__ add, const float* __restrict__ bias,
                         float* __restrict__ o)
{
  const long i = ((long)blockIdx.x * 256 + threadIdx.x) * 4;
  const int c = (int)(i % DMODEL);
  float4 av = *(const float4*)(add + i);
  float4 bv = *(const float4*)(bias + c);
  float4 r;
  r.x = av.x + bv.x; r.y = av.y + bv.y; r.z = av.z + bv.z; r.w = av.w + bv.w;
  *(float4*)(o + i) = r;
}

// ------- split-K reduce: o = sum_{n<NP} p[n*plane] + bias[col] + add (float4) -------
template<int NP>
__global__ void reduce_v9(const float* __restrict__ p, const float* __restrict__ add,
                          const float* __restrict__ bias, float* __restrict__ o,
                          long plane)
{
  const long i = ((long)blockIdx.x * 256 + threadIdx.x) * 4;
  float4 s = *(const float4*)(p + i);
#pragma unroll
  for (int n = 1; n < NP; ++n) {
    float4 v = *(const float4*)(p + i + (long)n * plane);
    s.x += v.x; s.y += v.y; s.z += v.z; s.w += v.w;
  }
  const int c = (int)(i % DMODEL);
  float4 bv = *(const float4*)(bias + c);
  float4 av = *(const float4*)(add + i);
  float4 r;
  r.x = s.x + bv.x + av.x; r.y = s.y + bv.y + av.y;
  r.z = s.z + bv.z + av.z; r.w = s.w + bv.w + av.w;
  *(float4*)(o + i) = r;
}

// ---------------------------------------------------------------------------
extern "C" void kernel_launch(void* const* d_in, const int* in_sizes, int n_in,
                              void* d_out, int out_size, void* d_ws, size_t ws_size,
                              hipStream_t stream)
{
  (void)in_sizes; (void)n_in; (void)out_size;
  const float* x    = (const float*)d_in[0];
  const float* Wq   = (const float*)d_in[1];
  const float* Wk   = (const float*)d_in[2];
  const float* Wv   = (const float*)d_in[3];
  const float* Wu   = (const float*)d_in[4];
  const float* bu   = (const float*)d_in[5];
  const float* ln1g = (const float*)d_in[6];
  const float* ln1b = (const float*)d_in[7];
  const float* ln2g = (const float*)d_in[8];
  const float* ln2b = (const float*)d_in[9];
  const float* W1   = (const float*)d_in[10];
  const float* b1   = (const float*)d_in[11];
  const float* W2   = (const float*)d_in[12];
  const float* b2   = (const float*)d_in[13];
  float* out = (float*)d_out;

  char* ws = (char*)d_ws;
  size_t off = 0;
  auto alloc = [&](size_t bytes) -> void* {
    void* p = (void*)(ws + off);
    off += (bytes + 255) & ~(size_t)255;
    return p;
  };

  const float qk_alpha = 1.0f / sqrtf((float)DMODEL);
  dim3 tb(32, 8);

  const size_t SZ_W   = (size_t)DMODEL * DH * 2;         // 14,155,776
  const size_t SZ_MT  = (size_t)NHEAD * DMODEL * DMODEL * 2;
  const size_t SZ_Y   = (size_t)ROWS * DMODEL * 2;       // 6,291,456
  const size_t SZ_X2  = (size_t)ROWS * DMODEL * 4;       // 12,582,912

  if (ws_size >= (size_t)230e6) {
    // ===== PLAN A3: full-batch folded + atomic split-K (~223.5 MB) =====
    bf16_t* MT   = (bf16_t*)alloc(SZ_MT);                       // 14.2 MB
    bf16_t* PhT  = (bf16_t*)alloc(SZ_MT);                       // 14.2 MB
    bf16_t* y    = (bf16_t*)alloc(SZ_Y);                        //  6.3 MB
    float*  x2f  = (float* )alloc(SZ_X2);                       // 12.6 MB
    bf16_t* S    = (bf16_t*)alloc((size_t)NBATCH * SEQ * NHEAD * SEQ * 2);    // 100.7 MB
    bf16_t* Zt   = (bf16_t*)alloc((size_t)NBATCH * DMODEL * NHEAD * SEQ * 2); // 75.5 MB
    // aliases (lifetime-disjoint):
    bf16_t* T    = (bf16_t*)Zt;                    // full-batch T (75.5 MB exact; dead before Zt-gemm)
    bf16_t* Wqb  = (bf16_t*)S;                     // weight staging in S (dead after folds)
    bf16_t* Wkb  = (bf16_t*)((char*)S + SZ_W);
    bf16_t* Wvb  = (bf16_t*)((char*)S + 2*SZ_W);
    bf16_t* WuT  = (bf16_t*)((char*)S + 3*SZ_W);
    bf16_t* W1T  = (bf16_t*)S;                     // MLP phase (S dead after out-gemm)
    bf16_t* W2T  = (bf16_t*)((char*)S + 4718592);
    bf16_t* t    = (bf16_t*)((char*)S + 9437184);  // 25.2 MB
    bf16_t* y2   = (bf16_t*)Zt;                    // Zt dead after out-gemm

    // ---- weight folds ----
    cast3_v9<<<dim3(6912, 1, 3), 256, 0, stream>>>(Wq, Wk, Wv, Wqb, Wkb, Wvb);
    tr_f2b_v9<<<dim3(DMODEL/32, DH/32), tb, 0, stream>>>(Wu, WuT, DMODEL, DH);
    gemm_v9<false,false,false,0><<<dim3(6, 6, NHEAD), 256, 0, stream>>>(
        Wkb, Wqb, MT, DMODEL, DH, DH, DMODEL, NHEAD,
        0, DMODEL, 0, DMODEL, 0, (long)DMODEL*DMODEL, nullptr, nullptr, 0, 1.0f);
    gemm_v9<false,false,false,0><<<dim3(6, 6, NHEAD), 256, 0, stream>>>(
        WuT, Wvb, PhT, DMODEL, DH, DH, DMODEL, NHEAD,
        0, DMODEL, 0, DMODEL, 0, (long)DMODEL*DMODEL, nullptr, nullptr, 0, 1.0f);

    // ---- attention (all full-batch dispatches) ----
    ln_v9<<<ROWS, 256, 0, stream>>>(x, ln1g, ln1b, y);
    // T[b][h][i][g] = y_b @ M_h   (z = b*NHEAD + h)
    gemm_v9<false,false,false,0><<<dim3(6, 8, NBATCH*NHEAD), 256, 0, stream>>>(
        y, MT, T, DMODEL, DMODEL, DMODEL, DMODEL, NHEAD,
        (long)SEQ*DMODEL, 0, 0, (long)DMODEL*DMODEL,
        (long)NHEAD*SEQ*DMODEL, (long)SEQ*DMODEL, nullptr, nullptr, 0, 1.0f);
    // S[b][i][h*1024+j] = (T_bh @ y_b^T) * alpha
    gemm_v9<false,false,false,0><<<dim3(8, 8, NBATCH*NHEAD), 256, 0, stream>>>(
        T, y, S, DMODEL, DMODEL, DMODEL, NHEAD*SEQ, NHEAD,
        (long)NHEAD*SEQ*DMODEL, (long)SEQ*DMODEL, (long)SEQ*DMODEL, 0,
        (long)SEQ*NHEAD*SEQ, (long)SEQ, nullptr, nullptr, 0, qk_alpha);
    softmax_v9<<<NBATCH*SEQ*NHEAD, 256, 0, stream>>>(S);
    // Zt[b][d][h*1024+j] = PhT_h @ y_b^T  (overwrites T region; T dead)
    gemm_v9<false,false,false,0><<<dim3(8, 6, NBATCH*NHEAD), 256, 0, stream>>>(
        PhT, y, Zt, DMODEL, DMODEL, DMODEL, NHEAD*SEQ, NHEAD,
        0, (long)DMODEL*DMODEL, (long)SEQ*DMODEL, 0,
        (long)DMODEL*NHEAD*SEQ, (long)SEQ, nullptr, nullptr, 0, 1.0f);
    // x2f = x + bu, then atomic split-K 8: x2f += S_b @ Zt_b^T  (z = kc*4 + b)
    initb_v9<<<(ROWS*DMODEL)/1024, 256, 0, stream>>>(x, bu, x2f);
    gemm_v9<false,false,false,3><<<dim3(6, 8, 32), 256, 0, stream>>>(
        S, Zt, x2f, NHEAD*SEQ/8, NHEAD*SEQ, NHEAD*SEQ, DMODEL, NBATCH,
        (long)(NHEAD*SEQ/8), (long)SEQ*NHEAD*SEQ,
        (long)(NHEAD*SEQ/8), (long)DMODEL*NHEAD*SEQ,
        0, (long)SEQ*DMODEL, nullptr, nullptr, 0, 1.0f);

    // ---- MLP ----
    ln_v9<<<ROWS, 256, 0, stream>>>(x2f, ln2g, ln2b, y2);
    tr_f2b_v9<<<dim3(DFF/32, DMODEL/32), tb, 0, stream>>>(W1, W1T, DFF, DMODEL);
    tr_f2b_v9<<<dim3(DMODEL/32, DFF/32), tb, 0, stream>>>(W2, W2T, DMODEL, DFF);
    gemm_v9<true,false,true,0><<<dim3(DFF/128, ROWS/128, 1), 256, 0, stream>>>(
        y2, W1T, t, DMODEL, DMODEL, DMODEL, DFF, 1, 0,0,0,0,0,0, b1, nullptr, 0, 1.0f);
    // out = x2f + b2, then atomic split-K 4: out += t @ W2T  (z = kc)
    initb_v9<<<(ROWS*DMODEL)/1024, 256, 0, stream>>>(x2f, b2, out);
    gemm_v9<false,false,false,3><<<dim3(6, ROWS/128, 4), 256, 0, stream>>>(
        t, W2T, out, DFF/4, DFF, DFF, DMODEL, 4,
        0, (long)(DFF/4), 0, (long)(DFF/4), 0, 0,
        nullptr, nullptr, 0, 1.0f);
  } else if (ws_size >= (size_t)112e6) {
    // ===== PLAN B: batch-looped folded (~110.1 MB) =====
    bf16_t* MT  = (bf16_t*)alloc(SZ_MT);
    bf16_t* PhT = (bf16_t*)alloc(SZ_MT);
    bf16_t* y   = (bf16_t*)alloc(SZ_Y);
    float*  x2f = (float* )alloc(SZ_X2);
    char*   BIG = (char*  )alloc((size_t)62914560);
    bf16_t* T_b  = (bf16_t*)(BIG);
    bf16_t* S_b  = (bf16_t*)(BIG + 18874368);
    bf16_t* Zt_b = (bf16_t*)(BIG + 44040192);
    float*  part = (float* )(BIG);
    bf16_t* Wqb = (bf16_t*)(BIG);
    bf16_t* Wkb = (bf16_t*)(BIG + SZ_W);
    bf16_t* Wvb = (bf16_t*)(BIG + 2*SZ_W);
    bf16_t* WuT = (bf16_t*)(BIG + 3*SZ_W);
    bf16_t* W1T   = (bf16_t*)(BIG);
    bf16_t* W2T   = (bf16_t*)(BIG + 4718592);
    bf16_t* t     = (bf16_t*)(BIG + 9437184);
    float*  partM = (float* )(BIG + 34603008);
    bf16_t* y2    = y;

    cast3_v9<<<dim3(6912, 1, 3), 256, 0, stream>>>(Wq, Wk, Wv, Wqb, Wkb, Wvb);
    tr_f2b_v9<<<dim3(DMODEL/32, DH/32), tb, 0, stream>>>(Wu, WuT, DMODEL, DH);
    gemm_v9<false,false,false,0><<<dim3(6, 6, NHEAD), 256, 0, stream>>>(
        Wkb, Wqb, MT, DMODEL, DH, DH, DMODEL, NHEAD,
        0, DMODEL, 0, DMODEL, 0, (long)DMODEL*DMODEL, nullptr, nullptr, 0, 1.0f);
    gemm_v9<false,false,false,0><<<dim3(6, 6, NHEAD), 256, 0, stream>>>(
        WuT, Wvb, PhT, DMODEL, DH, DH, DMODEL, NHEAD,
        0, DMODEL, 0, DMODEL, 0, (long)DMODEL*DMODEL, nullptr, nullptr, 0, 1.0f);

    ln_v9<<<ROWS, 256, 0, stream>>>(x, ln1g, ln1b, y);
    for (int b = 0; b < NBATCH; ++b) {
      const bf16_t* yb = y + (long)b * SEQ * DMODEL;
      gemm_v9<false,false,false,0><<<dim3(6, 8, NHEAD), 256, 0, stream>>>(
          yb, MT, T_b, DMODEL, DMODEL, DMODEL, DMODEL, NHEAD,
          0, 0, 0, (long)DMODEL*DMODEL, 0, (long)SEQ*DMODEL,
          nullptr, nullptr, 0, 1.0f);
      gemm_v9<false,false,false,0><<<dim3(8, 8, NHEAD), 256, 0, stream>>>(
          T_b, yb, S_b, DMODEL, DMODEL, DMODEL, NHEAD*SEQ, NHEAD,
          0, (long)SEQ*DMODEL, 0, 0, 0, (long)SEQ,
          nullptr, nullptr, 0, qk_alpha);
      softmax_v9<<<NHEAD*SEQ, 256, 0, stream>>>(S_b);
      gemm_v9<false,false,false,0><<<dim3(8, 6, NHEAD), 256, 0, stream>>>(
          PhT, yb, Zt_b, DMODEL, DMODEL, DMODEL, NHEAD*SEQ, NHEAD,
          0, (long)DMODEL*DMODEL, 0, 0, 0, (long)SEQ,
          nullptr, nullptr, 0, 1.0f);
      gemm_v9<false,false,false,1><<<dim3(6, 8, 6), 256, 0, stream>>>(
          S_b, Zt_b, part, NHEAD*SEQ/6, NHEAD*SEQ, NHEAD*SEQ, DMODEL, 6,
          0, (long)(NHEAD*SEQ/6), 0, (long)(NHEAD*SEQ/6), 0, (long)SEQ*DMODEL,
          nullptr, nullptr, 0, 1.0f);
      reduce_v9<6><<<(SEQ*DMODEL)/1024, 256, 0, stream>>>(
          part, x + (long)b*SEQ*DMODEL, bu, x2f + (long)b*SEQ*DMODEL,
          (long)SEQ*DMODEL);
    }

    tr_f2b_v9<<<dim3(DFF/32, DMODEL/32), tb, 0, stream>>>(W1, W1T, DFF, DMODEL);
    tr_f2b_v9<<<dim3(DMODEL/32, DFF/32), tb, 0, stream>>>(W2, W2T, DMODEL, DFF);
    ln_v9<<<ROWS, 256, 0, stream>>>(x2f, ln2g, ln2b, y2);
    gemm_v9<true,false,true,0><<<dim3(DFF/128, ROWS/128, 1), 256, 0, stream>>>(
        y2, W1T, t, DMODEL, DMODEL, DMODEL, DFF, 1, 0,0,0,0,0,0, b1, nullptr, 0, 1.0f);
    gemm_v9<false,false,false,1><<<dim3(6, ROWS/128, 2), 256, 0, stream>>>(
        t, W2T, partM, DFF/2, DFF, DFF, DMODEL, 2,
        0, (long)(DFF/2), 0, (long)(DFF/2), 0, (long)ROWS*DMODEL,
        nullptr, nullptr, 0, 1.0f);
    reduce_v9<2><<<(ROWS*DMODEL)/1024, 256, 0, stream>>>(
        partM, x2f, b2, out, (long)ROWS*DMODEL);
  } else if (ws_size >= (size_t)70e6) {
    // ===== PLAN C: head-looped folded (~68.2 MB) =====
    bf16_t* MT  = (bf16_t*)alloc(SZ_MT);
    bf16_t* PhT = (bf16_t*)alloc(SZ_MT);
    bf16_t* y   = (bf16_t*)alloc(SZ_Y);
    char*   R   = (char*  )alloc((size_t)33554432);
    bf16_t* WAb = (bf16_t*)(R);
    bf16_t* WBb = (bf16_t*)(R + SZ_W);
    float*  x2f = (float* )(R);
    bf16_t* T_h = (bf16_t*)(R + 12582912);
    bf16_t* S_h = (bf16_t*)(R + 18874368);
    bf16_t* Z_h = (bf16_t*)(R + 27262976);
    bf16_t* W1T = (bf16_t*)(R + 12582912);
    bf16_t* W2T = (bf16_t*)(R + 17301504);
    bf16_t* t   = (bf16_t*)MT;
    bf16_t* y2  = y;

    cast1_v9<<<6912, 256, 0, stream>>>(Wq, WAb);
    cast1_v9<<<6912, 256, 0, stream>>>(Wk, WBb);
    gemm_v9<false,false,false,0><<<dim3(6, 6, NHEAD), 256, 0, stream>>>(
        WBb, WAb, MT, DMODEL, DH, DH, DMODEL, NHEAD,
        0, DMODEL, 0, DMODEL, 0, (long)DMODEL*DMODEL, nullptr, nullptr, 0, 1.0f);
    cast1_v9<<<6912, 256, 0, stream>>>(Wv, WAb);
    tr_f2b_v9<<<dim3(DMODEL/32, DH/32), tb, 0, stream>>>(Wu, WBb, DMODEL, DH);
    gemm_v9<false,false,false,0><<<dim3(6, 6, NHEAD), 256, 0, stream>>>(
        WBb, WAb, PhT, DMODEL, DH, DH, DMODEL, NHEAD,
        0, DMODEL, 0, DMODEL, 0, (long)DMODEL*DMODEL, nullptr, nullptr, 0, 1.0f);

    ln_v9<<<ROWS, 256, 0, stream>>>(x, ln1g, ln1b, y);
    for (int h = 0; h < NHEAD; ++h) {
      const bf16_t* MTh  = MT  + (long)h * DMODEL * DMODEL;
      const bf16_t* PhTh = PhT + (long)h * DMODEL * DMODEL;
      gemm_v9<false,false,false,0><<<dim3(6, ROWS/128, 1), 256, 0, stream>>>(
          y, MTh, T_h, DMODEL, DMODEL, DMODEL, DMODEL, 1,
          0,0,0,0,0,0, nullptr, nullptr, 0, 1.0f);
      gemm_v9<false,false,false,0><<<dim3(8, 8, NBATCH), 256, 0, stream>>>(
          T_h, y, S_h, DMODEL, DMODEL, DMODEL, SEQ, NBATCH,
          0, (long)SEQ*DMODEL, 0, (long)SEQ*DMODEL, 0, (long)SEQ*SEQ,
          nullptr, nullptr, 0, qk_alpha);
      softmax_v9<<<ROWS, 256, 0, stream>>>(S_h);
      gemm_v9<false,false,false,0><<<dim3(8, 6, NBATCH), 256, 0, stream>>>(
          PhTh, y, Z_h, DMODEL, DMODEL, DMODEL, SEQ, NBATCH,
          0, 0, 0, (long)SEQ*DMODEL, 0, (long)DMODEL*SEQ,
          nullptr, nullptr, 0, 1.0f);
      if (h == 0)
        gemm_v9<false,false,false,1><<<dim3(6, 8, NBATCH), 256, 0, stream>>>(
            S_h, Z_h, x2f, SEQ, SEQ, SEQ, DMODEL, NBATCH,
            0, (long)SEQ*SEQ, 0, (long)DMODEL*SEQ, 0, (long)SEQ*DMODEL,
            nullptr, nullptr, 0, 1.0f);
      else
        gemm_v9<false,false,false,2><<<dim3(6, 8, NBATCH), 256, 0, stream>>>(
            S_h, Z_h, x2f, SEQ, SEQ, SEQ, DMODEL, NBATCH,
            0, (long)SEQ*SEQ, 0, (long)DMODEL*SEQ, 0, (long)SEQ*DMODEL,
            nullptr, nullptr, 0, 1.0f);
    }
    finalize_v9<<<(ROWS*DMODEL)/256, 256, 0, stream>>>(x2f, x, bu, x2f);

    tr_f2b_v9<<<dim3(DFF/32, DMODEL/32), tb, 0, stream>>>(W1, W1T, DFF, DMODEL);
    tr_f2b_v9<<<dim3(DMODEL/32, DFF/32), tb, 0, stream>>>(W2, W2T, DMODEL, DFF);
    ln_v9<<<ROWS, 256, 0, stream>>>(x2f, ln2g, ln2b, y2);
    gemm_v9<true,false,true,0><<<dim3(DFF/128, ROWS/128, 1), 256, 0, stream>>>(
        y2, W1T, t, DMODEL, DMODEL, DMODEL, DFF, 1, 0,0,0,0,0,0, b1, nullptr, 0, 1.0f);
    gemm_v9<true,true,false,1><<<dim3(6, ROWS/128, 1), 256, 0, stream>>>(
        t, W2T, out, DFF/2, DFF, DFF, DMODEL, 1, 0,0,0,0,0,0,
        b2, x2f, DMODEL, 1.0f);
    gemm_v9<false,false,false,2><<<dim3(6, ROWS/128, 1), 256, 0, stream>>>(
        t + DFF/2, W2T + DFF/2, out, DFF/2, DFF, DFF, DMODEL, 1, 0,0,0,0,0,0,
        nullptr, nullptr, 0, 1.0f);
  } else {
    // ===== legacy SMALL PLAN (~43 MB) =====
    bf16_t* W1T   = (bf16_t*)alloc((size_t)DMODEL * DFF * 2);
    bf16_t* W2T   = (bf16_t*)alloc((size_t)DMODEL * DFF * 2);
    bf16_t* y     = (bf16_t*)alloc(SZ_Y);
    float*  x2f   = (float* )alloc(SZ_X2);
    char*   reg1  = (char*)alloc((size_t)3*DMODEL*DMODEL*2 + (size_t)DMODEL*DMODEL*2 + (size_t)SEQ*DMODEL*2);
    bf16_t* WhT   = (bf16_t*)reg1;
    bf16_t* WuTh  = (bf16_t*)(reg1 + (size_t)3*DMODEL*DMODEL*2);
    bf16_t* attb  = (bf16_t*)(reg1 + (size_t)4*DMODEL*DMODEL*2);
    bf16_t* y2    = (bf16_t*)reg1;
    char*   reg2  = (char*)alloc((size_t)SEQ*3*DMODEL*2 + (size_t)DMODEL*SEQ*2 + (size_t)SEQ*SEQ*2);
    bf16_t* QKVb  = (bf16_t*)reg2;
    bf16_t* Vtb   = (bf16_t*)(reg2 + (size_t)SEQ*3*DMODEL*2);
    bf16_t* Sb    = (bf16_t*)(reg2 + (size_t)SEQ*3*DMODEL*2 + (size_t)DMODEL*SEQ*2);
    bf16_t* tslab = (bf16_t*)reg2;

    tr_f2b_v9<<<dim3(DFF/32, DMODEL/32), tb, 0, stream>>>(W1, W1T, DFF, DMODEL);
    tr_f2b_v9<<<dim3(DMODEL/32, DFF/32), tb, 0, stream>>>(W2, W2T, DMODEL, DFF);
    ln_v9<<<ROWS, 256, 0, stream>>>(x, ln1g, ln1b, y);

    const int N3 = 3 * DMODEL;
    for (int h = 0; h < NHEAD; ++h) {
      tr_wh_v9<<<dim3(24, 24, 4), tb, 0, stream>>>(Wq, Wk, Wv, Wu, WhT, WuTh, h);
      for (int b = 0; b < NBATCH; ++b) {
        const bf16_t* yb = y + (size_t)b * SEQ * DMODEL;
        gemm_v9<false,false,false,0><<<dim3(N3/128, SEQ/128, 1), 256, 0, stream>>>(
            yb, WhT, QKVb, DMODEL, DMODEL, DMODEL, N3, 1, 0,0,0,0,0,0,
            nullptr, nullptr, 0, 1.0f);
        tr_b_v9<<<dim3(DMODEL/32, SEQ/32, 1), tb, 0, stream>>>(
            QKVb + 2*DMODEL, Vtb, N3, SEQ, 1, 0,0,0,0);
        gemm_v9<false,false,false,0><<<dim3(SEQ/128, SEQ/128, 1), 256, 0, stream>>>(
            QKVb, QKVb + DMODEL, Sb, DMODEL, N3, N3, SEQ, 1, 0,0,0,0,0,0,
            nullptr, nullptr, 0, qk_alpha);
        softmax_v9<<<SEQ, 256, 0, stream>>>(Sb);
        gemm_v9<false,false,false,0><<<dim3(DMODEL/128, SEQ/128, 1), 256, 0, stream>>>(
            Sb, Vtb, attb, SEQ, SEQ, SEQ, DMODEL, 1, 0,0,0,0,0,0,
            nullptr, nullptr, 0, 1.0f);
        float* x2b = x2f + (size_t)b * SEQ * DMODEL;
        if (h == 0)
          gemm_v9<false,false,false,1><<<dim3(DMODEL/128, SEQ/128, 1), 256, 0, stream>>>(
              attb, WuTh, x2b, DMODEL, DMODEL, DMODEL, DMODEL, 1, 0,0,0,0,0,0,
              nullptr, nullptr, 0, 1.0f);
        else
          gemm_v9<false,false,false,2><<<dim3(DMODEL/128, SEQ/128, 1), 256, 0, stream>>>(
              attb, WuTh, x2b, DMODEL, DMODEL, DMODEL, DMODEL, 1, 0,0,0,0,0,0,
              nullptr, nullptr, 0, 1.0f);
      }
    }
    finalize_v9<<<(ROWS*DMODEL)/256, 256, 0, stream>>>(x2f, x, bu, x2f);
    ln_v9<<<ROWS, 256, 0, stream>>>(x2f, ln2g, ln2b, y2);
    for (int kb = 0; kb < 4; ++kb) {
      gemm_v9<true,false,true,0><<<dim3(DMODEL/128, ROWS/128, 1), 256, 0, stream>>>(
          y2, W1T + (size_t)kb*DMODEL*DMODEL, tslab, DMODEL, DMODEL, DMODEL, DMODEL, 1,
          0,0,0,0,0,0, b1 + kb*DMODEL, nullptr, 0, 1.0f);
      if (kb == 0)
        gemm_v9<true,true,false,1><<<dim3(DMODEL/128, ROWS/128, 1), 256, 0, stream>>>(
            tslab, W2T + (size_t)kb*DMODEL, out, DMODEL, DMODEL, DFF, DMODEL, 1,
            0,0,0,0,0,0, b2, x2f, DMODEL, 1.0f);
      else
        gemm_v9<false,false,false,2><<<dim3(DMODEL/128, ROWS/128, 1), 256, 0, stream>>>(
            tslab, W2T + (size_t)kb*DMODEL, out, DMODEL, DMODEL, DFF, DMODEL, 1,
            0,0,0,0,0,0, nullptr, nullptr, 0, 1.0f);
    }
  }
}